// Round 8
// baseline (1970.022 us; speedup 1.0000x reference)
//
#include <hip/hip_runtime.h>

#define TPB 256
#define NBMAX 1024     // max coarse buckets
#define CAP 9216       // per-bucket capacity (mean 8184, sigma ~90 -> +11 sigma)
#define EPB 2048       // edges per block in k_bucket (8/thread)

typedef float f32x4 __attribute__((ext_vector_type(4)));
typedef float f32x2 __attribute__((ext_vector_type(2)));

__device__ __forceinline__ float lrelu(float x) { return x > 0.f ? x : 0.2f * x; }

// bf16 helpers (RNE pack)
__device__ __forceinline__ unsigned bfr(float x) {
  unsigned u = __float_as_uint(x);
  return (u + 0x7FFFu + ((u >> 16) & 1u)) >> 16;
}
__device__ __forceinline__ unsigned pk(float a, float b) { return bfr(a) | (bfr(b) << 16); }
__device__ __forceinline__ float ubf(unsigned us) { return __uint_as_float(us << 16); }

// ============================ bucketed binning ==============================
// Combined key space: key=d (dst rows, buckets 0..NBD-1) and key=NPAD+s
// (src rows, buckets NBD..NB-1; NPAD = 256-aligned N). Payload:
// (key&255)<<24 | other_endpoint. Buckets are unordered internally — the
// fused gather kernels don't need intra-bucket sorting.
__global__ void __launch_bounds__(TPB) k_bucket(
    const int* __restrict__ ei, int E, int NPAD,
    int* __restrict__ cursor, unsigned* __restrict__ items)
{
  __shared__ int hist[NBMAX];            // counts -> rank counters
  __shared__ int lofs[NBMAX];            // exclusive scan (stage offsets)
  __shared__ int basem[NBMAX];           // b*CAP + resv - lofs[b]
  __shared__ int scan_s[TPB];
  __shared__ unsigned stage[2 * EPB];    // payload, bucket-major
  __shared__ unsigned short bid[2 * EPB];// bucket id per staged item
  int tid = threadIdx.x;
  for (int i = tid; i < NBMAX; i += TPB) hist[i] = 0;
  int s0 = blockIdx.x * EPB;
  int nE = min(EPB, E - s0);
  int sv[EPB / TPB], dv[EPB / TPB];
  __syncthreads();
#pragma unroll
  for (int k = 0; k < EPB / (TPB * 4); k++) {
    int li = tid * 4 + k * TPB * 4;
    if (li + 3 < nE) {
      int4 s4 = *(const int4*)(ei + s0 + li);
      int4 d4 = *(const int4*)(ei + E + s0 + li);
      sv[k*4+0] = s4.x; sv[k*4+1] = s4.y; sv[k*4+2] = s4.z; sv[k*4+3] = s4.w;
      dv[k*4+0] = d4.x; dv[k*4+1] = d4.y; dv[k*4+2] = d4.z; dv[k*4+3] = d4.w;
#pragma unroll
      for (int j = 0; j < 4; j++) {
        atomicAdd(&hist[dv[k*4+j] >> 8], 1);
        atomicAdd(&hist[(NPAD + sv[k*4+j]) >> 8], 1);
      }
    } else {
      for (int j = 0; j < 4; j++) {
        if (li + j < nE) {
          sv[k*4+j] = ei[s0 + li + j];
          dv[k*4+j] = ei[E + s0 + li + j];
          atomicAdd(&hist[dv[k*4+j] >> 8], 1);
          atomicAdd(&hist[(NPAD + sv[k*4+j]) >> 8], 1);
        }
      }
    }
  }
  __syncthreads();
  // 1024-bin exclusive scan; thread t owns bins 4t..4t+3
  int b0 = tid * 4;
  int c0 = hist[b0], c1 = hist[b0 + 1], c2 = hist[b0 + 2], c3 = hist[b0 + 3];
  int tsum = c0 + c1 + c2 + c3;
  scan_s[tid] = tsum;
  __syncthreads();
#pragma unroll
  for (int o = 1; o < TPB; o <<= 1) {
    int t = (tid >= o) ? scan_s[tid - o] : 0;
    __syncthreads();
    scan_s[tid] += t;
    __syncthreads();
  }
  int run = scan_s[tid] - tsum;
  int cs[4] = {c0, c1, c2, c3};
#pragma unroll
  for (int j = 0; j < 4; j++) {
    int b = b0 + j, c = cs[j];
    lofs[b] = run;
    int resv = c ? atomicAdd(&cursor[b], c) : 0;
    basem[b] = b * CAP + resv - run;
    hist[b] = 0;                     // rank counters for phase 3
    run += c;
  }
  __syncthreads();
  // phase 3: rank-scatter payload + bucket id into LDS (bucket-major)
#pragma unroll
  for (int k = 0; k < EPB / TPB; k++) {
    int li = tid * 4 + (k >> 2) * TPB * 4 + (k & 3);   // matches load indexing
    if (li < nE) {
      int s = sv[k], d = dv[k];
      int b1 = d >> 8;
      int p1 = lofs[b1] + atomicAdd(&hist[b1], 1);
      stage[p1] = ((unsigned)(d & 255) << 24) | (unsigned)s;
      bid[p1] = (unsigned short)b1;
      int k2 = NPAD + s, b2 = k2 >> 8;
      int p2 = lofs[b2] + atomicAdd(&hist[b2], 1);
      stage[p2] = ((unsigned)(s & 255) << 24) | (unsigned)d;
      bid[p2] = (unsigned short)b2;
    }
  }
  __syncthreads();
  // phase 4: ordered write-out — two independent LDS reads, coalesced runs
  int total = 2 * nE;
  for (int idx = tid; idx < total; idx += TPB) {
    unsigned u = stage[idx];
    int b = bid[idx];
    int dest = basem[b] + idx;
    if (dest < (b + 1) * CAP) items[dest] = u;
  }
}

// ============================ dense node kernels ============================

__global__ void __launch_bounds__(TPB) k_score(
    const float* __restrict__ x1, const float* __restrict__ x2,
    const float* __restrict__ Wq, const float* __restrict__ bq,
    const float* __restrict__ Wk, const float* __restrict__ bk,
    float* __restrict__ escore, float* __restrict__ sumexp, int N)
{
  __shared__ float sWq[128], sWk[160], sbq[16], sbk[16];
  for (int i = threadIdx.x; i < 128; i += TPB) sWq[i] = Wq[i];
  for (int i = threadIdx.x; i < 160; i += TPB) sWk[i] = Wk[i];
  if (threadIdx.x < 16) { sbq[threadIdx.x] = bq[threadIdx.x]; sbk[threadIdx.x] = bk[threadIdx.x]; }
  __syncthreads();
  int n = blockIdx.x * TPB + threadIdx.x;
  float e = 0.f;
  if (n < N) {
    float a[8], b[10];
#pragma unroll
    for (int i = 0; i < 8; i++) a[i] = x1[n*8 + i];
#pragma unroll
    for (int i = 0; i < 10; i++) b[i] = x2[n*10 + i];
    float score = 0.f;
#pragma unroll
    for (int j = 0; j < 16; j++) {
      float q = sbq[j], k = sbk[j];
#pragma unroll
      for (int i = 0; i < 8; i++) q += a[i] * sWq[i*16 + j];
#pragma unroll
      for (int i = 0; i < 10; i++) k += b[i] * sWk[i*16 + j];
      score += q * k;
    }
    e = __expf(score);   // |score| small: exp safe without max-subtraction
    escore[n] = e;
  }
  float v = e;
#pragma unroll
  for (int off = 32; off > 0; off >>= 1) v += __shfl_down(v, off);
  __shared__ float red[TPB / 64];
  if ((threadIdx.x & 63) == 0) red[threadIdx.x >> 6] = v;
  __syncthreads();
  if (threadIdx.x == 0) {
    float s = 0.f;
#pragma unroll
    for (int w = 0; w < TPB / 64; w++) s += red[w];
    atomicAdd(sumexp, s);
  }
}

__global__ void __launch_bounds__(TPB) k_A1(
    const float* __restrict__ x1, const float* __restrict__ x2,
    const float* __restrict__ Wv, const float* __restrict__ bv,
    const float* __restrict__ W1, const float* __restrict__ a1s, const float* __restrict__ a1d,
    const float* __restrict__ escore, const float* __restrict__ sumexp,
    unsigned* __restrict__ rec1a, unsigned* __restrict__ rec1b,
    float* __restrict__ ed, int N)
{
  __shared__ float sWv[288], sbv[16], sW1[512], sas[32], sad[32];
  for (int i = threadIdx.x; i < 288; i += TPB) sWv[i] = Wv[i];
  for (int i = threadIdx.x; i < 512; i += TPB) sW1[i] = W1[i];
  if (threadIdx.x < 16) sbv[threadIdx.x] = bv[threadIdx.x];
  if (threadIdx.x < 32) { sas[threadIdx.x] = a1s[threadIdx.x]; sad[threadIdx.x] = a1d[threadIdx.x]; }
  __syncthreads();
  int n = blockIdx.x * TPB + threadIdx.x;
  if (n >= N) return;
  float w = escore[n] / sumexp[0];
  float f[16];
  {
    float a[8], b[10];
#pragma unroll
    for (int i = 0; i < 8; i++) a[i] = x1[n*8 + i];
#pragma unroll
    for (int i = 0; i < 10; i++) b[i] = x2[n*10 + i];
#pragma unroll
    for (int j = 0; j < 16; j++) {
      float v = sbv[j];
#pragma unroll
      for (int i = 0; i < 8; i++) v += a[i] * sWv[i*16 + j];
#pragma unroll
      for (int i = 0; i < 10; i++) v += b[i] * sWv[(8 + i)*16 + j];
      f[j] = w * v;
    }
  }
  float hr[32], esv[8], edv[8];
#pragma unroll
  for (int j = 0; j < 32; j++) {
    float s = 0.f;
#pragma unroll
    for (int i = 0; i < 16; i++) s += f[i] * sW1[i*32 + j];
    hr[j] = s;
  }
#pragma unroll
  for (int hh = 0; hh < 8; hh++) {
    float s = 0.f, d = 0.f;
#pragma unroll
    for (int c = 0; c < 4; c++) { s += hr[hh*4+c]*sas[hh*4+c]; d += hr[hh*4+c]*sad[hh*4+c]; }
    esv[hh] = s; edv[hh] = d;
  }
  unsigned* ra = rec1a + (size_t)n*10;
  unsigned* rb = rec1b + (size_t)n*10;
  ra[0] = pk(esv[0], esv[1]); ra[1] = pk(esv[2], esv[3]);
  rb[0] = pk(esv[4], esv[5]); rb[1] = pk(esv[6], esv[7]);
#pragma unroll
  for (int hh = 0; hh < 4; hh++) {
    ra[2+2*hh] = pk(hr[hh*4+0], hr[hh*4+1]);
    ra[3+2*hh] = pk(hr[hh*4+2], hr[hh*4+3]);
    rb[2+2*hh] = pk(hr[16+hh*4+0], hr[16+hh*4+1]);
    rb[3+2*hh] = pk(hr[16+hh*4+2], hr[16+hh*4+3]);
  }
  f32x4 e0 = {edv[0], edv[1], edv[2], edv[3]};
  f32x4 e1 = {edv[4], edv[5], edv[6], edv[7]};
  *(f32x4*)(ed + n*8)     = e0;
  *(f32x4*)(ed + n*8 + 4) = e1;
}

__global__ void __launch_bounds__(TPB) k_B2(
    const float* __restrict__ W2, const float* __restrict__ a2s, const float* __restrict__ a2d,
    const float* __restrict__ X,
    unsigned* __restrict__ rec2, float* __restrict__ ed, int N)
{
  __shared__ float sW[512], sas[16], sad[16];
  for (int i = threadIdx.x; i < 512; i += TPB) sW[i] = W2[i];
  if (threadIdx.x < 16) { sas[threadIdx.x] = a2s[threadIdx.x]; sad[threadIdx.x] = a2d[threadIdx.x]; }
  __syncthreads();
  int n = blockIdx.x * TPB + threadIdx.x;
  if (n >= N) return;
  float Xr[32];
#pragma unroll
  for (int i = 0; i < 8; i++) {
    f32x4 t = __builtin_nontemporal_load((const f32x4*)(X + n*32) + i);
    Xr[i*4+0] = t.x; Xr[i*4+1] = t.y; Xr[i*4+2] = t.z; Xr[i*4+3] = t.w;
  }
  float hr[16];
#pragma unroll
  for (int j = 0; j < 16; j++) {
    float s = 0.f;
#pragma unroll
    for (int f = 0; f < 32; f++) s += Xr[f] * sW[f*16 + j];
    hr[j] = s;
  }
  float esv[4], edv[4];
#pragma unroll
  for (int hh = 0; hh < 4; hh++) {
    float s = 0.f, d = 0.f;
#pragma unroll
    for (int c = 0; c < 4; c++) { s += hr[hh*4+c]*sas[hh*4+c]; d += hr[hh*4+c]*sad[hh*4+c]; }
    esv[hh] = s; edv[hh] = d;
  }
  unsigned* r = rec2 + (size_t)n*10;
  r[0] = pk(esv[0], esv[1]); r[1] = pk(esv[2], esv[3]);
#pragma unroll
  for (int hh = 0; hh < 4; hh++) {
    r[2+2*hh] = pk(hr[hh*4+0], hr[hh*4+1]);
    r[3+2*hh] = pk(hr[hh*4+2], hr[hh*4+3]);
  }
  f32x4 e0 = {edv[0], edv[1], edv[2], edv[3]};
  *(f32x4*)(ed + n*8) = e0;
}

__global__ void __launch_bounds__(TPB) k_B3(
    const float* __restrict__ W3, const float* __restrict__ a3s, const float* __restrict__ a3d,
    const float* __restrict__ X3,
    float* __restrict__ rec3, float* __restrict__ ed, int N)
{
  __shared__ float sW[128], sas[8], sad[8];
  for (int i = threadIdx.x; i < 128; i += TPB) sW[i] = W3[i];
  if (threadIdx.x < 8) { sas[threadIdx.x] = a3s[threadIdx.x]; sad[threadIdx.x] = a3d[threadIdx.x]; }
  __syncthreads();
  int n = blockIdx.x * TPB + threadIdx.x;
  if (n >= N) return;
  float Xr[16];
#pragma unroll
  for (int i = 0; i < 4; i++) {
    f32x4 t = __builtin_nontemporal_load((const f32x4*)(X3 + n*16) + i);
    Xr[i*4+0] = t.x; Xr[i*4+1] = t.y; Xr[i*4+2] = t.z; Xr[i*4+3] = t.w;
  }
  float hr[8];
#pragma unroll
  for (int j = 0; j < 8; j++) {
    float s = 0.f;
#pragma unroll
    for (int f = 0; f < 16; f++) s += Xr[f] * sW[f*8 + j];
    hr[j] = s;
  }
  float* r = rec3 + (size_t)n*10;
#pragma unroll
  for (int hh = 0; hh < 2; hh++) {
    float s = 0.f, d = 0.f;
#pragma unroll
    for (int c = 0; c < 4; c++) { s += hr[hh*4+c]*sas[hh*4+c]; d += hr[hh*4+c]*sad[hh*4+c]; }
    r[hh] = s;
    ed[n*8 + hh] = d;
  }
#pragma unroll
  for (int hh = 0; hh < 2; hh++) {
    f32x2 a = {hr[hh*4+0], hr[hh*4+1]};
    f32x2 b = {hr[hh*4+2], hr[hh*4+3]};
    *(f32x2*)(r + 2 + hh*4)     = a;
    *(f32x2*)(r + 2 + hh*4 + 2) = b;
  }
}

// ================= fused bucket-gather GAT passes (no CSR) ==================
// One block per 256-row dst bucket. Stream unordered items; accumulate
// z/acc into LDS via ds_add_f32; epilogue adds self-loop, normalizes, +bias.
// H=4 heads/pass; bf16 records (40B, L2-resident).
template<int OS, int HOFF>
__global__ void __launch_bounds__(TPB) k_gatb(
    const int* __restrict__ cursor, const unsigned* __restrict__ items,
    const unsigned* __restrict__ rec, const float* __restrict__ ed,
    const float* __restrict__ bias, float* __restrict__ out, int N)
{
  __shared__ float zacc[256][21];   // [row][h*5 + {z,c0..c3}], pad 21 (odd)
  __shared__ float eds[256][4];
  int tid = threadIdx.x, b = blockIdx.x;
  int base = b << 8;
  {
    int r = base + tid;
    f32x4 e = {0.f, 0.f, 0.f, 0.f};
    if (r < N) e = *(const f32x4*)(ed + (size_t)r*8 + HOFF);
    eds[tid][0] = e.x; eds[tid][1] = e.y; eds[tid][2] = e.z; eds[tid][3] = e.w;
#pragma unroll
    for (int i = 0; i < 21; i++) zacc[tid][i] = 0.f;
  }
  __syncthreads();
  size_t bbase = (size_t)b * CAP;
  int cnt = min(cursor[b], CAP);
  for (int i = tid; i < cnt; i += TPB) {
    unsigned u = __builtin_nontemporal_load(items + bbase + i);
    int row = u >> 24;
    int s = u & 0xFFFFFFu;
    const unsigned* rp = rec + (size_t)s*10;
    uint2 ew  = *(const uint2*)rp;
    uint4 h01 = *(const uint4*)(rp + 2);
    uint4 h23 = *(const uint4*)(rp + 6);
    unsigned hw[8] = {h01.x, h01.y, h01.z, h01.w, h23.x, h23.y, h23.z, h23.w};
    float esv[4] = {ubf(ew.x & 0xFFFFu), ubf(ew.x >> 16),
                    ubf(ew.y & 0xFFFFu), ubf(ew.y >> 16)};
    float* za = &zacc[row][0];
#pragma unroll
    for (int hh = 0; hh < 4; hh++) {
      float w = __expf(lrelu(esv[hh] + eds[row][hh]));
      atomicAdd(&za[hh*5 + 0], w);
      unsigned a = hw[2*hh], c = hw[2*hh + 1];
      atomicAdd(&za[hh*5 + 1], w * ubf(a & 0xFFFFu));
      atomicAdd(&za[hh*5 + 2], w * ubf(a >> 16));
      atomicAdd(&za[hh*5 + 3], w * ubf(c & 0xFFFFu));
      atomicAdd(&za[hh*5 + 4], w * ubf(c >> 16));
    }
  }
  __syncthreads();
  int r = base + tid;
  if (r >= N) return;
  const unsigned* rp = rec + (size_t)r*10;
  uint2 ew  = *(const uint2*)rp;
  uint4 h01 = *(const uint4*)(rp + 2);
  uint4 h23 = *(const uint4*)(rp + 6);
  unsigned hw[8] = {h01.x, h01.y, h01.z, h01.w, h23.x, h23.y, h23.z, h23.w};
  float esv[4] = {ubf(ew.x & 0xFFFFu), ubf(ew.x >> 16),
                  ubf(ew.y & 0xFFFFu), ubf(ew.y >> 16)};
#pragma unroll
  for (int hh = 0; hh < 4; hh++) {
    float w = __expf(lrelu(esv[hh] + eds[tid][hh]));   // self-loop
    float z = zacc[tid][hh*5 + 0] + w;
    unsigned a = hw[2*hh], c = hw[2*hh + 1];
    float inv = 1.f / z;
    const f32x4 bb = *(const f32x4*)(bias + (HOFF + hh)*4);
    f32x4 o = { (zacc[tid][hh*5+1] + w*ubf(a & 0xFFFFu))*inv + bb.x,
                (zacc[tid][hh*5+2] + w*ubf(a >> 16))   *inv + bb.y,
                (zacc[tid][hh*5+3] + w*ubf(c & 0xFFFFu))*inv + bb.z,
                (zacc[tid][hh*5+4] + w*ubf(c >> 16))   *inv + bb.w };
    __builtin_nontemporal_store(o, (f32x4*)(out + (size_t)r*OS + (HOFF + hh)*4));
  }
}

// Layer 3 (H=2, fp32 rec3) fused pass.
__global__ void __launch_bounds__(TPB) k_gat3b(
    const int* __restrict__ cursor, const unsigned* __restrict__ items,
    const float* __restrict__ rec, const float* __restrict__ ed,
    const float* __restrict__ b3, float* __restrict__ x4, int N)
{
  __shared__ float zacc[256][11];   // [row][h*5 + {z,c0..c3}], pad 11 (odd)
  __shared__ float eds[256][2];
  int tid = threadIdx.x, b = blockIdx.x;
  int base = b << 8;
  {
    int r = base + tid;
    f32x2 e = {0.f, 0.f};
    if (r < N) e = *(const f32x2*)(ed + (size_t)r*8);
    eds[tid][0] = e.x; eds[tid][1] = e.y;
#pragma unroll
    for (int i = 0; i < 11; i++) zacc[tid][i] = 0.f;
  }
  __syncthreads();
  size_t bbase = (size_t)b * CAP;
  int cnt = min(cursor[b], CAP);
  for (int i = tid; i < cnt; i += TPB) {
    unsigned u = __builtin_nontemporal_load(items + bbase + i);
    int row = u >> 24;
    int s = u & 0xFFFFFFu;
    const float* rp = rec + (size_t)s*10;
    f32x2 es2 = *(const f32x2*)rp;
    f32x4 h0 = *(const f32x4*)(rp + 2);
    f32x4 h1 = *(const f32x4*)(rp + 6);
    float* za = &zacc[row][0];
    float w0 = __expf(lrelu(es2.x + eds[row][0]));
    atomicAdd(&za[0], w0);
    atomicAdd(&za[1], w0*h0.x); atomicAdd(&za[2], w0*h0.y);
    atomicAdd(&za[3], w0*h0.z); atomicAdd(&za[4], w0*h0.w);
    float w1 = __expf(lrelu(es2.y + eds[row][1]));
    atomicAdd(&za[5], w1);
    atomicAdd(&za[6], w1*h1.x); atomicAdd(&za[7], w1*h1.y);
    atomicAdd(&za[8], w1*h1.z); atomicAdd(&za[9], w1*h1.w);
  }
  __syncthreads();
  int r = base + tid;
  if (r >= N) return;
  const float* rp = rec + (size_t)r*10;
  f32x2 es2 = *(const f32x2*)rp;
  f32x4 h0 = *(const f32x4*)(rp + 2);
  f32x4 h1 = *(const f32x4*)(rp + 6);
  float w0 = __expf(lrelu(es2.x + eds[tid][0]));
  float w1 = __expf(lrelu(es2.y + eds[tid][1]));
  float i0 = 1.f / (zacc[tid][0] + w0);
  float i1 = 1.f / (zacc[tid][5] + w1);
  const f32x4 bb0 = *(const f32x4*)(b3);
  const f32x4 bb1 = *(const f32x4*)(b3 + 4);
  f32x4 o0 = { (zacc[tid][1] + w0*h0.x)*i0 + bb0.x, (zacc[tid][2] + w0*h0.y)*i0 + bb0.y,
               (zacc[tid][3] + w0*h0.z)*i0 + bb0.z, (zacc[tid][4] + w0*h0.w)*i0 + bb0.w };
  f32x4 o1 = { (zacc[tid][6] + w1*h1.x)*i1 + bb1.x, (zacc[tid][7] + w1*h1.y)*i1 + bb1.y,
               (zacc[tid][8] + w1*h1.z)*i1 + bb1.z, (zacc[tid][9] + w1*h1.w)*i1 + bb1.w };
  __builtin_nontemporal_store(o0, (f32x4*)(x4 + (size_t)r*8));
  __builtin_nontemporal_store(o1, (f32x4*)(x4 + (size_t)r*8 + 4));
}

// Fused adjacency + final: one block per 256-row src bucket (buckets NBD..).
// R3acc/deg in LDS; epilogue computes out = dot(x4,R3)+R3@Wl2.
__global__ void __launch_bounds__(TPB) k_adjb(
    const int* __restrict__ cursor, const unsigned* __restrict__ items,
    const float* __restrict__ x4, const float* __restrict__ Wl2,
    float* __restrict__ out, int N, int NBD)
{
  __shared__ float racc[256][9];    // [row][8 acc + count]
  __shared__ float sW[8];
  int tid = threadIdx.x, b = blockIdx.x + NBD;
  int base = blockIdx.x << 8;       // src row base (NPAD-aligned)
  if (tid < 8) sW[tid] = Wl2[tid];
#pragma unroll
  for (int i = 0; i < 9; i++) racc[tid][i] = 0.f;
  __syncthreads();
  size_t bbase = (size_t)b * CAP;
  int cnt = min(cursor[b], CAP);
  for (int i = tid; i < cnt; i += TPB) {
    unsigned u = __builtin_nontemporal_load(items + bbase + i);
    int row = u >> 24;
    int c = u & 0xFFFFFFu;
    f32x4 xv0 = *(const f32x4*)(x4 + (size_t)c*8);
    f32x4 xv1 = *(const f32x4*)(x4 + (size_t)c*8 + 4);
    float* ra = &racc[row][0];
    atomicAdd(&ra[0], xv0.x); atomicAdd(&ra[1], xv0.y);
    atomicAdd(&ra[2], xv0.z); atomicAdd(&ra[3], xv0.w);
    atomicAdd(&ra[4], xv1.x); atomicAdd(&ra[5], xv1.y);
    atomicAdd(&ra[6], xv1.z); atomicAdd(&ra[7], xv1.w);
    atomicAdd(&ra[8], 1.f);
  }
  __syncthreads();
  int r = base + tid;
  if (r >= N) return;
  float deg = racc[tid][8];
  float inv = deg > 0.f ? 1.f / deg : 0.f;
  f32x4 xo0 = *(const f32x4*)(x4 + (size_t)r*8);
  f32x4 xo1 = *(const f32x4*)(x4 + (size_t)r*8 + 4);
  float res = 0.f;
#pragma unroll
  for (int j = 0; j < 4; j++) {
    float R0 = racc[tid][j] * inv;
    float R1 = racc[tid][4 + j] * inv;
    float x0 = (j==0)?xo0.x:(j==1)?xo0.y:(j==2)?xo0.z:xo0.w;
    float x1 = (j==0)?xo1.x:(j==1)?xo1.y:(j==2)?xo1.z:xo1.w;
    res += R0 * (x0 + sW[j]) + R1 * (x1 + sW[4 + j]);
  }
  out[r] = res;
}

// ============================ launch ========================================
extern "C" void kernel_launch(void* const* d_in, const int* in_sizes, int n_in,
                              void* d_out, int out_size, void* d_ws, size_t ws_size,
                              hipStream_t stream)
{
  const float* x1  = (const float*)d_in[0];
  const float* x2  = (const float*)d_in[1];
  const int*   ei  = (const int*)d_in[2];
  const float* Wq  = (const float*)d_in[4];
  const float* bq  = (const float*)d_in[5];
  const float* Wk  = (const float*)d_in[6];
  const float* bk  = (const float*)d_in[7];
  const float* Wv  = (const float*)d_in[8];
  const float* bv  = (const float*)d_in[9];
  const float* W1  = (const float*)d_in[10];
  const float* a1s = (const float*)d_in[11];
  const float* a1d = (const float*)d_in[12];
  const float* b1  = (const float*)d_in[13];
  const float* W2  = (const float*)d_in[14];
  const float* a2s = (const float*)d_in[15];
  const float* a2d = (const float*)d_in[16];
  const float* b2  = (const float*)d_in[17];
  const float* W3  = (const float*)d_in[18];
  const float* a3s = (const float*)d_in[19];
  const float* a3d = (const float*)d_in[20];
  const float* b3  = (const float*)d_in[21];
  const float* Wl2 = (const float*)d_in[22];

  int N = in_sizes[0] / 8;
  int E = in_sizes[2] / 2;
  int NBD  = (N + 255) >> 8;            // dst buckets (391)
  int NPAD = NBD << 8;                  // 256-aligned src key offset
  int NB   = NBD + NBD;                 // total buckets (src span == dst span)

  // ---- workspace (element offsets all multiples of 4 -> 16B aligned) ----
  int* cursor   = (int*)d_ws;                           // 1024 (zeroed)
  float* sumexp = (float*)(cursor + 1024);              // 16 (1 used, zeroed)
  unsigned* items = (unsigned*)(sumexp + 16);           // NB*CAP
  unsigned* rec1a = items + (size_t)NB * CAP;           // 10N (4.0 MB)
  unsigned* rec1b = rec1a + 10ull*N;                    // 10N (later aliased by x4)
  unsigned* rec2  = rec1b + 10ull*N;                    // 10N
  float* rec3     = (float*)(rec2 + 10ull*N);           // 10N
  float* ed       = rec3 + 10ull*N;                     // 8N
  float* escore   = ed + 8ull*N;                        // N
  float* X        = escore + (size_t)N;                 // 32N (X3 aliases, stride 16)
  float* X3 = X;
  float* x4 = (float*)rec1b;                            // 8N (rec1b dead by then)

  int gN  = (N + TPB - 1) / TPB;
  int gB  = (E + EPB - 1) / EPB;

  (void)hipMemsetAsync(d_ws, 0, (1024 + 16) * sizeof(int), stream);  // cursor + sumexp

  // binning (bucket-major items; no intra-bucket sort needed)
  k_bucket<<<gB, TPB, 0, stream>>>(ei, E, NPAD, cursor, items);

  // dense prologue
  k_score<<<gN, TPB, 0, stream>>>(x1, x2, Wq, bq, Wk, bk, escore, sumexp, N);
  k_A1<<<gN, TPB, 0, stream>>>(x1, x2, Wv, bv, W1, a1s, a1d, escore, sumexp, rec1a, rec1b, ed, N);

  // GAT layer 1 (two fused 4-head passes)
  k_gatb<32, 0><<<NBD, TPB, 0, stream>>>(cursor, items, rec1a, ed, b1, X, N);
  k_gatb<32, 4><<<NBD, TPB, 0, stream>>>(cursor, items, rec1b, ed, b1, X, N);
  // GAT layer 2
  k_B2<<<gN, TPB, 0, stream>>>(W2, a2s, a2d, X, rec2, ed, N);
  k_gatb<16, 0><<<NBD, TPB, 0, stream>>>(cursor, items, rec2, ed, b2, X3, N);
  // GAT layer 3
  k_B3<<<gN, TPB, 0, stream>>>(W3, a3s, a3d, X3, rec3, ed, N);
  k_gat3b<<<NBD, TPB, 0, stream>>>(cursor, items, rec3, ed, b3, x4, N);

  // fused adjacency + final (src buckets NBD..2*NBD-1)
  k_adjb<<<NBD, TPB, 0, stream>>>(cursor, items, x4, Wl2, (float*)d_out, N, NBD);
}

// Round 9
// 582.315 us; speedup vs baseline: 3.3831x; 3.3831x over previous
//
#include <hip/hip_runtime.h>

#define TPB 256
#define CAP 9216       // per-bucket capacity (mean 8184, sigma ~90 -> +11 sigma)
#define EPB 4096       // edges per block in k_bucket (16/thread)
#define OFSW 784       // ofs table row stride (>= NB+1, 16-aligned)

typedef float f32x4 __attribute__((ext_vector_type(4)));
typedef float f32x2 __attribute__((ext_vector_type(2)));

__device__ __forceinline__ float lrelu(float x) { return x > 0.f ? x : 0.2f * x; }

// bf16 helpers (RNE pack)
__device__ __forceinline__ unsigned bfr(float x) {
  unsigned u = __float_as_uint(x);
  return (u + 0x7FFFu + ((u >> 16) & 1u)) >> 16;
}
__device__ __forceinline__ unsigned pk(float a, float b) { return bfr(a) | (bfr(b) << 16); }
__device__ __forceinline__ float ubf(unsigned us) { return __uint_as_float(us << 16); }

// ============================ bucketed CSR build ============================
// Pass 1: per-block LDS 1024-bin sort of 2*EPB items; output block-contiguous
// (fully coalesced, NO global atomics, NO scattered writes) + the block's
// bucket-offset row (exclusive scan) to a global ofs table.
__global__ void __launch_bounds__(TPB) k_bucket(
    const int* __restrict__ ei, int E, int N,
    unsigned* __restrict__ items2, int* __restrict__ ofs)
{
  __shared__ int hist[1024];            // counts -> rank counters
  __shared__ int lofs[1024];            // exclusive scan (stage offsets)
  __shared__ int scan_s[TPB];
  __shared__ unsigned stage[2 * EPB];   // 8192 items, bucket-major
  int tid = threadIdx.x;
  for (int i = tid; i < 1024; i += TPB) hist[i] = 0;
  int s0 = blockIdx.x * EPB;
  int nE = min(EPB, E - s0);
  int sv[16], dv[16];
  __syncthreads();
#pragma unroll
  for (int k = 0; k < 4; k++) {
    int li = tid * 4 + k * TPB * 4;
    if (li + 3 < nE) {
      int4 s4 = *(const int4*)(ei + s0 + li);
      int4 d4 = *(const int4*)(ei + E + s0 + li);
      sv[k*4+0] = s4.x; sv[k*4+1] = s4.y; sv[k*4+2] = s4.z; sv[k*4+3] = s4.w;
      dv[k*4+0] = d4.x; dv[k*4+1] = d4.y; dv[k*4+2] = d4.z; dv[k*4+3] = d4.w;
#pragma unroll
      for (int j = 0; j < 4; j++) {
        atomicAdd(&hist[dv[k*4+j] >> 8], 1);
        atomicAdd(&hist[(N + sv[k*4+j]) >> 8], 1);
      }
    } else {
      for (int j = 0; j < 4; j++) {
        if (li + j < nE) {
          sv[k*4+j] = ei[s0 + li + j];
          dv[k*4+j] = ei[E + s0 + li + j];
          atomicAdd(&hist[dv[k*4+j] >> 8], 1);
          atomicAdd(&hist[(N + sv[k*4+j]) >> 8], 1);
        }
      }
    }
  }
  __syncthreads();
  // 1024-bin exclusive scan; thread t owns bins 4t..4t+3
  int b0 = tid * 4;
  int c0 = hist[b0], c1 = hist[b0 + 1], c2 = hist[b0 + 2], c3 = hist[b0 + 3];
  int tsum = c0 + c1 + c2 + c3;
  scan_s[tid] = tsum;
  __syncthreads();
#pragma unroll
  for (int o = 1; o < TPB; o <<= 1) {
    int t = (tid >= o) ? scan_s[tid - o] : 0;
    __syncthreads();
    scan_s[tid] += t;
    __syncthreads();
  }
  int run = scan_s[tid] - tsum;
  int cs[4] = {c0, c1, c2, c3};
#pragma unroll
  for (int j = 0; j < 4; j++) {
    int b = b0 + j;
    lofs[b] = run;
    hist[b] = 0;                     // rank counters for phase 3
    run += cs[j];
  }
  __syncthreads();
  // phase 3: rank-scatter payload into LDS (bucket-major)
#pragma unroll
  for (int k = 0; k < 16; k++) {
    int li = tid * 4 + (k >> 2) * TPB * 4 + (k & 3);   // matches load indexing
    if (li < nE) {
      int s = sv[k], d = dv[k];
      int b1 = d >> 8;
      int p1 = lofs[b1] + atomicAdd(&hist[b1], 1);
      stage[p1] = ((unsigned)(d & 255) << 24) | (unsigned)s;
      int k2 = N + s, b2 = k2 >> 8;
      int p2 = lofs[b2] + atomicAdd(&hist[b2], 1);
      stage[p2] = ((unsigned)(k2 & 255) << 24) | (unsigned)d;
    }
  }
  __syncthreads();
  // phase 4: fully coalesced block-contiguous write-out + ofs row
  int total = 2 * nE;
  size_t obase = (size_t)blockIdx.x * (2 * EPB);
  for (int idx = tid; idx < total; idx += TPB)
    __builtin_nontemporal_store(stage[idx], items2 + obase + idx);
  int orow = blockIdx.x * OFSW;
  for (int i = tid; i < OFSW; i += TPB)
    ofs[orow + i] = lofs[i];         // lofs[b]=2*nE for b>=NB (empty bins)
}

// Pass 2: one block per bucket k — gather the bucket's runs from all block
// segments (scattered READS, high MLP), then 256-bin row-sort into the CSR.
__global__ void __launch_bounds__(TPB) k_csr2(
    const int* __restrict__ ofs, const unsigned* __restrict__ items2, int nB,
    unsigned* __restrict__ items, int* __restrict__ rowptr, int* __restrict__ rowend, int n2)
{
  __shared__ unsigned stage[CAP];
  __shared__ int segdst[OFSW];
  __shared__ int ctr;
  __shared__ int cnt_s[TPB], scan_s[TPB], off_s[TPB];
  int tid = threadIdx.x, k = blockIdx.x;
  if (tid == 0) ctr = 0;
  cnt_s[tid] = 0;
  __syncthreads();
  for (int b = tid; b < nB; b += TPB) {
    int o0 = ofs[b * OFSW + k];
    int o1 = ofs[b * OFSW + k + 1];
    int c = o1 - o0;
    segdst[b] = c ? atomicAdd(&ctr, c) : 0;
  }
  __syncthreads();
  int cnt = min(ctr, CAP);
  for (int b = tid; b < nB; b += TPB) {
    int o0 = ofs[b * OFSW + k];
    int c  = ofs[b * OFSW + k + 1] - o0;
    int dst = segdst[b];
    const unsigned* src = items2 + (size_t)b * (2 * EPB) + o0;
    for (int j = 0; j < c; j++) {
      int p = dst + j;
      if (p < CAP) stage[p] = __builtin_nontemporal_load(src + j);
    }
  }
  __syncthreads();
  for (int i = tid; i < cnt; i += TPB) atomicAdd(&cnt_s[stage[i] >> 24], 1);
  __syncthreads();
  int v = cnt_s[tid];
  scan_s[tid] = v;
  __syncthreads();
#pragma unroll
  for (int o = 1; o < TPB; o <<= 1) {
    int t = (tid >= o) ? scan_s[tid - o] : 0;
    __syncthreads();
    scan_s[tid] += t;
    __syncthreads();
  }
  int excl = scan_s[tid] - v;
  off_s[tid] = excl;
  size_t bbase = (size_t)k * CAP;
  int g = k * 256 + tid;
  if (g < n2) { rowptr[g] = (int)bbase + excl; rowend[g] = (int)bbase + excl + v; }
  cnt_s[tid] = 0;
  __syncthreads();
  for (int i = tid; i < cnt; i += TPB) {
    unsigned u = stage[i];
    int kk = u >> 24;
    int r = atomicAdd(&cnt_s[kk], 1);
    items[bbase + off_s[kk] + r] = u & 0xFFFFFFu;
  }
}

// ============================ dense node kernels ============================

__global__ void __launch_bounds__(TPB) k_score(
    const float* __restrict__ x1, const float* __restrict__ x2,
    const float* __restrict__ Wq, const float* __restrict__ bq,
    const float* __restrict__ Wk, const float* __restrict__ bk,
    float* __restrict__ escore, float* __restrict__ sumexp, int N)
{
  __shared__ float sWq[128], sWk[160], sbq[16], sbk[16];
  for (int i = threadIdx.x; i < 128; i += TPB) sWq[i] = Wq[i];
  for (int i = threadIdx.x; i < 160; i += TPB) sWk[i] = Wk[i];
  if (threadIdx.x < 16) { sbq[threadIdx.x] = bq[threadIdx.x]; sbk[threadIdx.x] = bk[threadIdx.x]; }
  __syncthreads();
  int n = blockIdx.x * TPB + threadIdx.x;
  float e = 0.f;
  if (n < N) {
    float a[8], b[10];
#pragma unroll
    for (int i = 0; i < 8; i++) a[i] = x1[n*8 + i];
#pragma unroll
    for (int i = 0; i < 10; i++) b[i] = x2[n*10 + i];
    float score = 0.f;
#pragma unroll
    for (int j = 0; j < 16; j++) {
      float q = sbq[j], k = sbk[j];
#pragma unroll
      for (int i = 0; i < 8; i++) q += a[i] * sWq[i*16 + j];
#pragma unroll
      for (int i = 0; i < 10; i++) k += b[i] * sWk[i*16 + j];
      score += q * k;
    }
    e = __expf(score);   // |score| small: exp safe without max-subtraction
    escore[n] = e;
  }
  float v = e;
#pragma unroll
  for (int off = 32; off > 0; off >>= 1) v += __shfl_down(v, off);
  __shared__ float red[TPB / 64];
  if ((threadIdx.x & 63) == 0) red[threadIdx.x >> 6] = v;
  __syncthreads();
  if (threadIdx.x == 0) {
    float s = 0.f;
#pragma unroll
    for (int w = 0; w < TPB / 64; w++) s += red[w];
    atomicAdd(sumexp, s);
  }
}

__global__ void __launch_bounds__(TPB) k_A1(
    const float* __restrict__ x1, const float* __restrict__ x2,
    const float* __restrict__ Wv, const float* __restrict__ bv,
    const float* __restrict__ W1, const float* __restrict__ a1s, const float* __restrict__ a1d,
    const float* __restrict__ escore, const float* __restrict__ sumexp,
    unsigned* __restrict__ rec1a, unsigned* __restrict__ rec1b,
    float* __restrict__ ed, int N)
{
  __shared__ float sWv[288], sbv[16], sW1[512], sas[32], sad[32];
  for (int i = threadIdx.x; i < 288; i += TPB) sWv[i] = Wv[i];
  for (int i = threadIdx.x; i < 512; i += TPB) sW1[i] = W1[i];
  if (threadIdx.x < 16) sbv[threadIdx.x] = bv[threadIdx.x];
  if (threadIdx.x < 32) { sas[threadIdx.x] = a1s[threadIdx.x]; sad[threadIdx.x] = a1d[threadIdx.x]; }
  __syncthreads();
  int n = blockIdx.x * TPB + threadIdx.x;
  if (n >= N) return;
  float w = escore[n] / sumexp[0];
  float f[16];
  {
    float a[8], b[10];
#pragma unroll
    for (int i = 0; i < 8; i++) a[i] = x1[n*8 + i];
#pragma unroll
    for (int i = 0; i < 10; i++) b[i] = x2[n*10 + i];
#pragma unroll
    for (int j = 0; j < 16; j++) {
      float v = sbv[j];
#pragma unroll
      for (int i = 0; i < 8; i++) v += a[i] * sWv[i*16 + j];
#pragma unroll
      for (int i = 0; i < 10; i++) v += b[i] * sWv[(8 + i)*16 + j];
      f[j] = w * v;
    }
  }
  float hr[32], esv[8], edv[8];
#pragma unroll
  for (int j = 0; j < 32; j++) {
    float s = 0.f;
#pragma unroll
    for (int i = 0; i < 16; i++) s += f[i] * sW1[i*32 + j];
    hr[j] = s;
  }
#pragma unroll
  for (int hh = 0; hh < 8; hh++) {
    float s = 0.f, d = 0.f;
#pragma unroll
    for (int c = 0; c < 4; c++) { s += hr[hh*4+c]*sas[hh*4+c]; d += hr[hh*4+c]*sad[hh*4+c]; }
    esv[hh] = s; edv[hh] = d;
  }
  unsigned* ra = rec1a + (size_t)n*10;
  unsigned* rb = rec1b + (size_t)n*10;
  ra[0] = pk(esv[0], esv[1]); ra[1] = pk(esv[2], esv[3]);
  rb[0] = pk(esv[4], esv[5]); rb[1] = pk(esv[6], esv[7]);
#pragma unroll
  for (int hh = 0; hh < 4; hh++) {
    ra[2+2*hh] = pk(hr[hh*4+0], hr[hh*4+1]);
    ra[3+2*hh] = pk(hr[hh*4+2], hr[hh*4+3]);
    rb[2+2*hh] = pk(hr[16+hh*4+0], hr[16+hh*4+1]);
    rb[3+2*hh] = pk(hr[16+hh*4+2], hr[16+hh*4+3]);
  }
  f32x4 e0 = {edv[0], edv[1], edv[2], edv[3]};
  f32x4 e1 = {edv[4], edv[5], edv[6], edv[7]};
  *(f32x4*)(ed + n*8)     = e0;
  *(f32x4*)(ed + n*8 + 4) = e1;
}

__global__ void __launch_bounds__(TPB) k_B2(
    const float* __restrict__ W2, const float* __restrict__ a2s, const float* __restrict__ a2d,
    const float* __restrict__ X,
    unsigned* __restrict__ rec2, float* __restrict__ ed, int N)
{
  __shared__ float sW[512], sas[16], sad[16];
  for (int i = threadIdx.x; i < 512; i += TPB) sW[i] = W2[i];
  if (threadIdx.x < 16) { sas[threadIdx.x] = a2s[threadIdx.x]; sad[threadIdx.x] = a2d[threadIdx.x]; }
  __syncthreads();
  int n = blockIdx.x * TPB + threadIdx.x;
  if (n >= N) return;
  float Xr[32];
#pragma unroll
  for (int i = 0; i < 8; i++) {
    f32x4 t = __builtin_nontemporal_load((const f32x4*)(X + n*32) + i);
    Xr[i*4+0] = t.x; Xr[i*4+1] = t.y; Xr[i*4+2] = t.z; Xr[i*4+3] = t.w;
  }
  float hr[16];
#pragma unroll
  for (int j = 0; j < 16; j++) {
    float s = 0.f;
#pragma unroll
    for (int f = 0; f < 32; f++) s += Xr[f] * sW[f*16 + j];
    hr[j] = s;
  }
  float esv[4], edv[4];
#pragma unroll
  for (int hh = 0; hh < 4; hh++) {
    float s = 0.f, d = 0.f;
#pragma unroll
    for (int c = 0; c < 4; c++) { s += hr[hh*4+c]*sas[hh*4+c]; d += hr[hh*4+c]*sad[hh*4+c]; }
    esv[hh] = s; edv[hh] = d;
  }
  unsigned* r = rec2 + (size_t)n*10;
  r[0] = pk(esv[0], esv[1]); r[1] = pk(esv[2], esv[3]);
#pragma unroll
  for (int hh = 0; hh < 4; hh++) {
    r[2+2*hh] = pk(hr[hh*4+0], hr[hh*4+1]);
    r[3+2*hh] = pk(hr[hh*4+2], hr[hh*4+3]);
  }
  f32x4 e0 = {edv[0], edv[1], edv[2], edv[3]};
  *(f32x4*)(ed + n*8) = e0;
}

__global__ void __launch_bounds__(TPB) k_B3(
    const float* __restrict__ W3, const float* __restrict__ a3s, const float* __restrict__ a3d,
    const float* __restrict__ X3,
    float* __restrict__ rec3, float* __restrict__ ed, int N)
{
  __shared__ float sW[128], sas[8], sad[8];
  for (int i = threadIdx.x; i < 128; i += TPB) sW[i] = W3[i];
  if (threadIdx.x < 8) { sas[threadIdx.x] = a3s[threadIdx.x]; sad[threadIdx.x] = a3d[threadIdx.x]; }
  __syncthreads();
  int n = blockIdx.x * TPB + threadIdx.x;
  if (n >= N) return;
  float Xr[16];
#pragma unroll
  for (int i = 0; i < 4; i++) {
    f32x4 t = __builtin_nontemporal_load((const f32x4*)(X3 + n*16) + i);
    Xr[i*4+0] = t.x; Xr[i*4+1] = t.y; Xr[i*4+2] = t.z; Xr[i*4+3] = t.w;
  }
  float hr[8];
#pragma unroll
  for (int j = 0; j < 8; j++) {
    float s = 0.f;
#pragma unroll
    for (int f = 0; f < 16; f++) s += Xr[f] * sW[f*8 + j];
    hr[j] = s;
  }
  float* r = rec3 + (size_t)n*10;
#pragma unroll
  for (int hh = 0; hh < 2; hh++) {
    float s = 0.f, d = 0.f;
#pragma unroll
    for (int c = 0; c < 4; c++) { s += hr[hh*4+c]*sas[hh*4+c]; d += hr[hh*4+c]*sad[hh*4+c]; }
    r[hh] = s;
    ed[n*8 + hh] = d;
  }
#pragma unroll
  for (int hh = 0; hh < 2; hh++) {
    f32x2 a = {hr[hh*4+0], hr[hh*4+1]};
    f32x2 b = {hr[hh*4+2], hr[hh*4+3]};
    *(f32x2*)(r + 2 + hh*4)     = a;
    *(f32x2*)(r + 2 + hh*4 + 2) = b;
  }
}

// ==================== wave-per-row gather passes ============================
template<int OS, int HOFF>
__global__ void __launch_bounds__(TPB) k_gat4(
    const int* __restrict__ rowptr, const int* __restrict__ rowend, const int* __restrict__ col,
    const unsigned* __restrict__ rec, const float* __restrict__ ed,
    const float* __restrict__ bias, float* __restrict__ out, int N)
{
  int wave = (blockIdx.x * TPB + threadIdx.x) >> 6;
  if (wave >= N) return;
  int lane = threadIdx.x & 63;
  int hh = lane & 3, j = lane >> 2;
  int d = wave;
  int e0 = rowptr[d], deg = rowend[d] - e0;
  float edv = ed[d*8 + HOFF + hh];
  float z = 0.f;
  f32x4 acc = {0.f, 0.f, 0.f, 0.f};
  for (int t = j; t <= deg; t += 16) {
    int s = (t == deg) ? d : __builtin_nontemporal_load(col + e0 + t);
    const unsigned* rp = rec + (size_t)s*10;
    unsigned ew = rp[hh >> 1];
    uint2 hv = *(const uint2*)(rp + 2 + 2*hh);
    float esv = ubf((ew >> ((hh & 1) * 16)) & 0xFFFFu);
    float w = __expf(lrelu(esv + edv));
    z += w;
    acc.x += w * ubf(hv.x & 0xFFFFu); acc.y += w * ubf(hv.x >> 16);
    acc.z += w * ubf(hv.y & 0xFFFFu); acc.w += w * ubf(hv.y >> 16);
  }
#pragma unroll
  for (int m = 4; m < 64; m <<= 1) {
    z += __shfl_xor(z, m);
    acc.x += __shfl_xor(acc.x, m); acc.y += __shfl_xor(acc.y, m);
    acc.z += __shfl_xor(acc.z, m); acc.w += __shfl_xor(acc.w, m);
  }
  if (j == 0) {
    float inv = 1.f / z;
    const f32x4 bb = *(const f32x4*)(bias + (HOFF + hh)*4);
    f32x4 o = { acc.x*inv + bb.x, acc.y*inv + bb.y, acc.z*inv + bb.z, acc.w*inv + bb.w };
    __builtin_nontemporal_store(o, (f32x4*)(out + (size_t)d*OS + (HOFF + hh)*4));
  }
}

__global__ void __launch_bounds__(TPB) k_gat3(
    const int* __restrict__ rowptr, const int* __restrict__ rowend, const int* __restrict__ col,
    const float* __restrict__ rec, const float* __restrict__ ed,
    const float* __restrict__ b3, float* __restrict__ x4, int N)
{
  int wave = (blockIdx.x * TPB + threadIdx.x) >> 6;
  if (wave >= N) return;
  int lane = threadIdx.x & 63;
  int hh = lane & 1, j = lane >> 1;
  int d = wave;
  int e0 = rowptr[d], deg = rowend[d] - e0;
  float edv = ed[d*8 + hh];
  float z = 0.f;
  f32x4 acc = {0.f, 0.f, 0.f, 0.f};
  for (int t = j; t <= deg; t += 32) {
    int s = (t == deg) ? d : __builtin_nontemporal_load(col + e0 + t);
    const float* rp = rec + (size_t)s*10;
    float esv = rp[hh];
    f32x2 a = *(const f32x2*)(rp + 2 + hh*4);
    f32x2 b = *(const f32x2*)(rp + 2 + hh*4 + 2);
    float w = __expf(lrelu(esv + edv));
    z += w; acc.x += w*a.x; acc.y += w*a.y; acc.z += w*b.x; acc.w += w*b.y;
  }
#pragma unroll
  for (int m = 2; m < 64; m <<= 1) {
    z += __shfl_xor(z, m);
    acc.x += __shfl_xor(acc.x, m); acc.y += __shfl_xor(acc.y, m);
    acc.z += __shfl_xor(acc.z, m); acc.w += __shfl_xor(acc.w, m);
  }
  if (j == 0) {
    float inv = 1.f / z;
    const f32x4 bb = *(const f32x4*)(b3 + hh*4);
    f32x4 o = { acc.x*inv + bb.x, acc.y*inv + bb.y, acc.z*inv + bb.z, acc.w*inv + bb.w };
    __builtin_nontemporal_store(o, (f32x4*)(x4 + d*8 + hh*4));
  }
}

__global__ void __launch_bounds__(TPB) k_adj_final(
    const int* __restrict__ rowptr, const int* __restrict__ rowend, const int* __restrict__ col,
    const float* __restrict__ x4, const float* __restrict__ Wl2,
    float* __restrict__ out, int N)
{
  __shared__ float sW[8];
  if (threadIdx.x < 8) sW[threadIdx.x] = Wl2[threadIdx.x];
  __syncthreads();
  int wave = (blockIdx.x * TPB + threadIdx.x) >> 6;
  if (wave >= N) return;
  int lane = threadIdx.x & 63;
  int q = lane & 1, j = lane >> 1;
  int r = wave;
  int e0 = rowptr[N + r], deg = rowend[N + r] - e0;
  f32x4 acc = {0.f, 0.f, 0.f, 0.f};
  for (int t = j; t < deg; t += 32) {
    int c = __builtin_nontemporal_load(col + e0 + t);
    f32x4 xv = *(const f32x4*)(x4 + c*8 + q*4);
    acc.x += xv.x; acc.y += xv.y; acc.z += xv.z; acc.w += xv.w;
  }
#pragma unroll
  for (int m = 2; m < 64; m <<= 1) {
    acc.x += __shfl_xor(acc.x, m); acc.y += __shfl_xor(acc.y, m);
    acc.z += __shfl_xor(acc.z, m); acc.w += __shfl_xor(acc.w, m);
  }
  float part = 0.f;
  if (j == 0) {
    float inv = deg > 0 ? 1.f / (float)deg : 0.f;
    f32x4 R = { acc.x*inv, acc.y*inv, acc.z*inv, acc.w*inv };
    f32x4 xo = *(const f32x4*)(x4 + r*8 + q*4);
    part = xo.x*R.x + xo.y*R.y + xo.z*R.z + xo.w*R.w
         + R.x*sW[q*4+0] + R.y*sW[q*4+1] + R.z*sW[q*4+2] + R.w*sW[q*4+3];
  }
  part += __shfl_xor(part, 1);
  if (lane == 0) out[r] = part;
}

// ============================ launch ========================================
extern "C" void kernel_launch(void* const* d_in, const int* in_sizes, int n_in,
                              void* d_out, int out_size, void* d_ws, size_t ws_size,
                              hipStream_t stream)
{
  const float* x1  = (const float*)d_in[0];
  const float* x2  = (const float*)d_in[1];
  const int*   ei  = (const int*)d_in[2];
  const float* Wq  = (const float*)d_in[4];
  const float* bq  = (const float*)d_in[5];
  const float* Wk  = (const float*)d_in[6];
  const float* bk  = (const float*)d_in[7];
  const float* Wv  = (const float*)d_in[8];
  const float* bv  = (const float*)d_in[9];
  const float* W1  = (const float*)d_in[10];
  const float* a1s = (const float*)d_in[11];
  const float* a1d = (const float*)d_in[12];
  const float* b1  = (const float*)d_in[13];
  const float* W2  = (const float*)d_in[14];
  const float* a2s = (const float*)d_in[15];
  const float* a2d = (const float*)d_in[16];
  const float* b2  = (const float*)d_in[17];
  const float* W3  = (const float*)d_in[18];
  const float* a3s = (const float*)d_in[19];
  const float* a3d = (const float*)d_in[20];
  const float* b3  = (const float*)d_in[21];
  const float* Wl2 = (const float*)d_in[22];

  int N = in_sizes[0] / 8;
  int E = in_sizes[2] / 2;
  int n2 = 2 * N;
  int NB = (n2 + 255) >> 8;             // CSR buckets (782)
  int gB = (E + EPB - 1) / EPB;         // k_bucket blocks (782)

  // ---- workspace ----
  float* sumexp = (float*)d_ws;                          // 16 (1 used, zeroed)
  int* rowptr   = (int*)(sumexp + 16);                   // 2N
  int* rowend   = rowptr + (size_t)n2;                   // 2N
  unsigned* itemsCSR = (unsigned*)(rowend + (size_t)n2); // NB*CAP (28.8 MB)
  unsigned* regionA  = itemsCSR + (size_t)NB * CAP;
  // phase 1 (CSR build): items2 + ofs live in regionA
  unsigned* items2 = regionA;                            // gB*8192 (25.6 MB)
  int* ofs = (int*)(items2 + (size_t)gB * (2 * EPB));    // gB*784  (2.45 MB)
  size_t raSize = (size_t)gB * (2 * EPB + OFSW);         // uints
  // phase 2 (dense+gather): recs/ed/escore alias regionA (items2/ofs dead)
  unsigned* rec1a = regionA;                             // 10N
  unsigned* rec1b = rec1a + 10ull*N;                     // 10N (aliased by x4 later)
  unsigned* rec2  = rec1b + 10ull*N;                     // 10N
  float* rec3     = (float*)(rec2 + 10ull*N);            // 10N
  float* ed       = rec3 + 10ull*N;                      // 8N
  float* escore   = ed + 8ull*N;                         // N   (49N total < raSize)
  float* X        = (float*)(regionA + raSize);          // 32N (X3 aliases, stride 16)
  float* X3 = X;
  float* x4 = (float*)rec1b;                             // 8N (rec1b dead by then)

  int gN = (N + TPB - 1) / TPB;
  int g64 = (int)(((long long)N * 64 + TPB - 1) / TPB);  // wave-per-row grids

  (void)hipMemsetAsync(sumexp, 0, 16 * sizeof(float), stream);

  // CSR build: block-sort (coalesced, atomic-free) -> per-bucket gather+sort
  k_bucket<<<gB, TPB, 0, stream>>>(ei, E, N, items2, ofs);
  k_csr2<<<NB, TPB, 0, stream>>>(ofs, items2, gB, itemsCSR, rowptr, rowend, n2);
  int* colv = (int*)itemsCSR;

  // dense prologue
  k_score<<<gN, TPB, 0, stream>>>(x1, x2, Wq, bq, Wk, bk, escore, sumexp, N);
  k_A1<<<gN, TPB, 0, stream>>>(x1, x2, Wv, bv, W1, a1s, a1d, escore, sumexp, rec1a, rec1b, ed, N);

  // GAT layer 1 (two 4-head passes)
  k_gat4<32, 0><<<g64, TPB, 0, stream>>>(rowptr, rowend, colv, rec1a, ed, b1, X, N);
  k_gat4<32, 4><<<g64, TPB, 0, stream>>>(rowptr, rowend, colv, rec1b, ed, b1, X, N);
  // GAT layer 2
  k_B2<<<gN, TPB, 0, stream>>>(W2, a2s, a2d, X, rec2, ed, N);
  k_gat4<16, 0><<<g64, TPB, 0, stream>>>(rowptr, rowend, colv, rec2, ed, b2, X3, N);
  // GAT layer 3
  k_B3<<<gN, TPB, 0, stream>>>(W3, a3s, a3d, X3, rec3, ed, N);
  k_gat3<<<g64, TPB, 0, stream>>>(rowptr, rowend, colv, rec3, ed, b3, x4, N);

  // adjacency readout (src-CSR rows [N,2N))
  k_adj_final<<<g64, TPB, 0, stream>>>(rowptr, rowend, colv, x4, Wl2, (float*)d_out, N);
}

// Round 10
// 526.104 us; speedup vs baseline: 3.7445x; 1.1068x over previous
//
#include <hip/hip_runtime.h>

#define TPB 256
#define CAP 9216       // per-bucket capacity (mean 8184, sigma ~90 -> +11 sigma)
#define EPB 4096       // edges per block in k_bucket (16/thread)
#define OFSW 784       // ofs table row stride (>= NB+1, 16-aligned)

typedef float f32x4 __attribute__((ext_vector_type(4)));
typedef float f32x2 __attribute__((ext_vector_type(2)));

__device__ __forceinline__ float lrelu(float x) { return x > 0.f ? x : 0.2f * x; }

// bf16 helpers (RNE pack)
__device__ __forceinline__ unsigned bfr(float x) {
  unsigned u = __float_as_uint(x);
  return (u + 0x7FFFu + ((u >> 16) & 1u)) >> 16;
}
__device__ __forceinline__ unsigned pk(float a, float b) { return bfr(a) | (bfr(b) << 16); }
__device__ __forceinline__ float ubf(unsigned us) { return __uint_as_float(us << 16); }

// ============================ bucketed CSR build ============================
// Pass 1: per-block LDS 1024-bin sort of 2*EPB items; output block-contiguous
// (fully coalesced, NO global atomics, NO scattered writes) + the block's
// bucket-offset row (exclusive scan) to a global ofs table.
__global__ void __launch_bounds__(TPB) k_bucket(
    const int* __restrict__ ei, int E, int N,
    unsigned* __restrict__ items2, int* __restrict__ ofs)
{
  __shared__ int hist[1024];            // counts -> rank counters
  __shared__ int lofs[1024];            // exclusive scan (stage offsets)
  __shared__ int scan_s[TPB];
  __shared__ unsigned stage[2 * EPB];   // 8192 items, bucket-major
  int tid = threadIdx.x;
  for (int i = tid; i < 1024; i += TPB) hist[i] = 0;
  int s0 = blockIdx.x * EPB;
  int nE = min(EPB, E - s0);
  int sv[16], dv[16];
  __syncthreads();
#pragma unroll
  for (int k = 0; k < 4; k++) {
    int li = tid * 4 + k * TPB * 4;
    if (li + 3 < nE) {
      int4 s4 = *(const int4*)(ei + s0 + li);
      int4 d4 = *(const int4*)(ei + E + s0 + li);
      sv[k*4+0] = s4.x; sv[k*4+1] = s4.y; sv[k*4+2] = s4.z; sv[k*4+3] = s4.w;
      dv[k*4+0] = d4.x; dv[k*4+1] = d4.y; dv[k*4+2] = d4.z; dv[k*4+3] = d4.w;
#pragma unroll
      for (int j = 0; j < 4; j++) {
        atomicAdd(&hist[dv[k*4+j] >> 8], 1);
        atomicAdd(&hist[(N + sv[k*4+j]) >> 8], 1);
      }
    } else {
      for (int j = 0; j < 4; j++) {
        if (li + j < nE) {
          sv[k*4+j] = ei[s0 + li + j];
          dv[k*4+j] = ei[E + s0 + li + j];
          atomicAdd(&hist[dv[k*4+j] >> 8], 1);
          atomicAdd(&hist[(N + sv[k*4+j]) >> 8], 1);
        }
      }
    }
  }
  __syncthreads();
  // 1024-bin exclusive scan; thread t owns bins 4t..4t+3
  int b0 = tid * 4;
  int c0 = hist[b0], c1 = hist[b0 + 1], c2 = hist[b0 + 2], c3 = hist[b0 + 3];
  int tsum = c0 + c1 + c2 + c3;
  scan_s[tid] = tsum;
  __syncthreads();
#pragma unroll
  for (int o = 1; o < TPB; o <<= 1) {
    int t = (tid >= o) ? scan_s[tid - o] : 0;
    __syncthreads();
    scan_s[tid] += t;
    __syncthreads();
  }
  int run = scan_s[tid] - tsum;
  int cs[4] = {c0, c1, c2, c3};
#pragma unroll
  for (int j = 0; j < 4; j++) {
    int b = b0 + j;
    lofs[b] = run;
    hist[b] = 0;                     // rank counters for phase 3
    run += cs[j];
  }
  __syncthreads();
  // phase 3: rank-scatter payload into LDS (bucket-major)
#pragma unroll
  for (int k = 0; k < 16; k++) {
    int li = tid * 4 + (k >> 2) * TPB * 4 + (k & 3);   // matches load indexing
    if (li < nE) {
      int s = sv[k], d = dv[k];
      int b1 = d >> 8;
      int p1 = lofs[b1] + atomicAdd(&hist[b1], 1);
      stage[p1] = ((unsigned)(d & 255) << 24) | (unsigned)s;
      int k2 = N + s, b2 = k2 >> 8;
      int p2 = lofs[b2] + atomicAdd(&hist[b2], 1);
      stage[p2] = ((unsigned)(k2 & 255) << 24) | (unsigned)d;
    }
  }
  __syncthreads();
  // phase 4: fully coalesced block-contiguous write-out + ofs row
  int total = 2 * nE;
  size_t obase = (size_t)blockIdx.x * (2 * EPB);
  for (int idx = tid; idx < total; idx += TPB)
    __builtin_nontemporal_store(stage[idx], items2 + obase + idx);
  int orow = blockIdx.x * OFSW;
  for (int i = tid; i < OFSW; i += TPB)
    ofs[orow + i] = lofs[i];         // lofs[b]=2*nE for b>=NB (empty bins)
}

// Pass 2: one block per bucket k — gather the bucket's runs from all block
// segments (cached reads: each thread re-touches its run's lines ~10x),
// then 256-bin row-sort into the CSR.
__global__ void __launch_bounds__(TPB) k_csr2(
    const int* __restrict__ ofs, const unsigned* __restrict__ items2, int nB,
    unsigned* __restrict__ items, int* __restrict__ rowptr, int* __restrict__ rowend, int n2)
{
  __shared__ unsigned stage[CAP];
  __shared__ int segdst[OFSW];
  __shared__ int ctr;
  __shared__ int cnt_s[TPB], scan_s[TPB], off_s[TPB];
  int tid = threadIdx.x, k = blockIdx.x;
  if (tid == 0) ctr = 0;
  cnt_s[tid] = 0;
  __syncthreads();
  for (int b = tid; b < nB; b += TPB) {
    int o0 = ofs[b * OFSW + k];
    int o1 = ofs[b * OFSW + k + 1];
    int c = o1 - o0;
    segdst[b] = c ? atomicAdd(&ctr, c) : 0;
  }
  __syncthreads();
  int cnt = min(ctr, CAP);
  for (int b = tid; b < nB; b += TPB) {
    int o0 = ofs[b * OFSW + k];
    int c  = ofs[b * OFSW + k + 1] - o0;
    int dst = segdst[b];
    const unsigned* src = items2 + (size_t)b * (2 * EPB) + o0;
    for (int j = 0; j < c; j++) {
      int p = dst + j;
      if (p < CAP) stage[p] = src[j];      // plain load: line reuse in L1/L2
    }
  }
  __syncthreads();
  for (int i = tid; i < cnt; i += TPB) atomicAdd(&cnt_s[stage[i] >> 24], 1);
  __syncthreads();
  int v = cnt_s[tid];
  scan_s[tid] = v;
  __syncthreads();
#pragma unroll
  for (int o = 1; o < TPB; o <<= 1) {
    int t = (tid >= o) ? scan_s[tid - o] : 0;
    __syncthreads();
    scan_s[tid] += t;
    __syncthreads();
  }
  int excl = scan_s[tid] - v;
  off_s[tid] = excl;
  size_t bbase = (size_t)k * CAP;
  int g = k * 256 + tid;
  if (g < n2) { rowptr[g] = (int)bbase + excl; rowend[g] = (int)bbase + excl + v; }
  cnt_s[tid] = 0;
  __syncthreads();
  for (int i = tid; i < cnt; i += TPB) {
    unsigned u = stage[i];
    int kk = u >> 24;
    int r = atomicAdd(&cnt_s[kk], 1);
    items[bbase + off_s[kk] + r] = u & 0xFFFFFFu;
  }
}

// ============================ dense node kernels ============================

__global__ void __launch_bounds__(TPB) k_score(
    const float* __restrict__ x1, const float* __restrict__ x2,
    const float* __restrict__ Wq, const float* __restrict__ bq,
    const float* __restrict__ Wk, const float* __restrict__ bk,
    float* __restrict__ escore, float* __restrict__ sumexp, int N)
{
  __shared__ float sWq[128], sWk[160], sbq[16], sbk[16];
  for (int i = threadIdx.x; i < 128; i += TPB) sWq[i] = Wq[i];
  for (int i = threadIdx.x; i < 160; i += TPB) sWk[i] = Wk[i];
  if (threadIdx.x < 16) { sbq[threadIdx.x] = bq[threadIdx.x]; sbk[threadIdx.x] = bk[threadIdx.x]; }
  __syncthreads();
  int n = blockIdx.x * TPB + threadIdx.x;
  float e = 0.f;
  if (n < N) {
    float a[8], b[10];
#pragma unroll
    for (int i = 0; i < 8; i++) a[i] = x1[n*8 + i];
#pragma unroll
    for (int i = 0; i < 10; i++) b[i] = x2[n*10 + i];
    float score = 0.f;
#pragma unroll
    for (int j = 0; j < 16; j++) {
      float q = sbq[j], k = sbk[j];
#pragma unroll
      for (int i = 0; i < 8; i++) q += a[i] * sWq[i*16 + j];
#pragma unroll
      for (int i = 0; i < 10; i++) k += b[i] * sWk[i*16 + j];
      score += q * k;
    }
    e = __expf(score);   // |score| small: exp safe without max-subtraction
    escore[n] = e;
  }
  float v = e;
#pragma unroll
  for (int off = 32; off > 0; off >>= 1) v += __shfl_down(v, off);
  __shared__ float red[TPB / 64];
  if ((threadIdx.x & 63) == 0) red[threadIdx.x >> 6] = v;
  __syncthreads();
  if (threadIdx.x == 0) {
    float s = 0.f;
#pragma unroll
    for (int w = 0; w < TPB / 64; w++) s += red[w];
    atomicAdd(sumexp, s);
  }
}

__global__ void __launch_bounds__(TPB) k_A1(
    const float* __restrict__ x1, const float* __restrict__ x2,
    const float* __restrict__ Wv, const float* __restrict__ bv,
    const float* __restrict__ W1, const float* __restrict__ a1s, const float* __restrict__ a1d,
    const float* __restrict__ escore, const float* __restrict__ sumexp,
    unsigned* __restrict__ rec1a, unsigned* __restrict__ rec1b,
    float* __restrict__ ed, int N)
{
  __shared__ float sWv[288], sbv[16], sW1[512], sas[32], sad[32];
  for (int i = threadIdx.x; i < 288; i += TPB) sWv[i] = Wv[i];
  for (int i = threadIdx.x; i < 512; i += TPB) sW1[i] = W1[i];
  if (threadIdx.x < 16) sbv[threadIdx.x] = bv[threadIdx.x];
  if (threadIdx.x < 32) { sas[threadIdx.x] = a1s[threadIdx.x]; sad[threadIdx.x] = a1d[threadIdx.x]; }
  __syncthreads();
  int n = blockIdx.x * TPB + threadIdx.x;
  if (n >= N) return;
  float w = escore[n] / sumexp[0];
  float f[16];
  {
    float a[8], b[10];
#pragma unroll
    for (int i = 0; i < 8; i++) a[i] = x1[n*8 + i];
#pragma unroll
    for (int i = 0; i < 10; i++) b[i] = x2[n*10 + i];
#pragma unroll
    for (int j = 0; j < 16; j++) {
      float v = sbv[j];
#pragma unroll
      for (int i = 0; i < 8; i++) v += a[i] * sWv[i*16 + j];
#pragma unroll
      for (int i = 0; i < 10; i++) v += b[i] * sWv[(8 + i)*16 + j];
      f[j] = w * v;
    }
  }
  float hr[32], esv[8], edv[8];
#pragma unroll
  for (int j = 0; j < 32; j++) {
    float s = 0.f;
#pragma unroll
    for (int i = 0; i < 16; i++) s += f[i] * sW1[i*32 + j];
    hr[j] = s;
  }
#pragma unroll
  for (int hh = 0; hh < 8; hh++) {
    float s = 0.f, d = 0.f;
#pragma unroll
    for (int c = 0; c < 4; c++) { s += hr[hh*4+c]*sas[hh*4+c]; d += hr[hh*4+c]*sad[hh*4+c]; }
    esv[hh] = s; edv[hh] = d;
  }
  unsigned* ra = rec1a + (size_t)n*10;
  unsigned* rb = rec1b + (size_t)n*10;
  ra[0] = pk(esv[0], esv[1]); ra[1] = pk(esv[2], esv[3]);
  rb[0] = pk(esv[4], esv[5]); rb[1] = pk(esv[6], esv[7]);
#pragma unroll
  for (int hh = 0; hh < 4; hh++) {
    ra[2+2*hh] = pk(hr[hh*4+0], hr[hh*4+1]);
    ra[3+2*hh] = pk(hr[hh*4+2], hr[hh*4+3]);
    rb[2+2*hh] = pk(hr[16+hh*4+0], hr[16+hh*4+1]);
    rb[3+2*hh] = pk(hr[16+hh*4+2], hr[16+hh*4+3]);
  }
  f32x4 e0 = {edv[0], edv[1], edv[2], edv[3]};
  f32x4 e1 = {edv[4], edv[5], edv[6], edv[7]};
  *(f32x4*)(ed + n*8)     = e0;
  *(f32x4*)(ed + n*8 + 4) = e1;
}

__global__ void __launch_bounds__(TPB) k_B2(
    const float* __restrict__ W2, const float* __restrict__ a2s, const float* __restrict__ a2d,
    const float* __restrict__ X,
    unsigned* __restrict__ rec2, float* __restrict__ ed, int N)
{
  __shared__ float sW[512], sas[16], sad[16];
  for (int i = threadIdx.x; i < 512; i += TPB) sW[i] = W2[i];
  if (threadIdx.x < 16) { sas[threadIdx.x] = a2s[threadIdx.x]; sad[threadIdx.x] = a2d[threadIdx.x]; }
  __syncthreads();
  int n = blockIdx.x * TPB + threadIdx.x;
  if (n >= N) return;
  float Xr[32];
#pragma unroll
  for (int i = 0; i < 8; i++) {
    f32x4 t = __builtin_nontemporal_load((const f32x4*)(X + n*32) + i);
    Xr[i*4+0] = t.x; Xr[i*4+1] = t.y; Xr[i*4+2] = t.z; Xr[i*4+3] = t.w;
  }
  float hr[16];
#pragma unroll
  for (int j = 0; j < 16; j++) {
    float s = 0.f;
#pragma unroll
    for (int f = 0; f < 32; f++) s += Xr[f] * sW[f*16 + j];
    hr[j] = s;
  }
  float esv[4], edv[4];
#pragma unroll
  for (int hh = 0; hh < 4; hh++) {
    float s = 0.f, d = 0.f;
#pragma unroll
    for (int c = 0; c < 4; c++) { s += hr[hh*4+c]*sas[hh*4+c]; d += hr[hh*4+c]*sad[hh*4+c]; }
    esv[hh] = s; edv[hh] = d;
  }
  unsigned* r = rec2 + (size_t)n*10;
  r[0] = pk(esv[0], esv[1]); r[1] = pk(esv[2], esv[3]);
#pragma unroll
  for (int hh = 0; hh < 4; hh++) {
    r[2+2*hh] = pk(hr[hh*4+0], hr[hh*4+1]);
    r[3+2*hh] = pk(hr[hh*4+2], hr[hh*4+3]);
  }
  f32x4 e0 = {edv[0], edv[1], edv[2], edv[3]};
  *(f32x4*)(ed + n*8) = e0;
}

__global__ void __launch_bounds__(TPB) k_B3(
    const float* __restrict__ W3, const float* __restrict__ a3s, const float* __restrict__ a3d,
    const float* __restrict__ X3,
    float* __restrict__ rec3, float* __restrict__ ed, int N)
{
  __shared__ float sW[128], sas[8], sad[8];
  for (int i = threadIdx.x; i < 128; i += TPB) sW[i] = W3[i];
  if (threadIdx.x < 8) { sas[threadIdx.x] = a3s[threadIdx.x]; sad[threadIdx.x] = a3d[threadIdx.x]; }
  __syncthreads();
  int n = blockIdx.x * TPB + threadIdx.x;
  if (n >= N) return;
  float Xr[16];
#pragma unroll
  for (int i = 0; i < 4; i++) {
    f32x4 t = __builtin_nontemporal_load((const f32x4*)(X3 + n*16) + i);
    Xr[i*4+0] = t.x; Xr[i*4+1] = t.y; Xr[i*4+2] = t.z; Xr[i*4+3] = t.w;
  }
  float hr[8];
#pragma unroll
  for (int j = 0; j < 8; j++) {
    float s = 0.f;
#pragma unroll
    for (int f = 0; f < 16; f++) s += Xr[f] * sW[f*8 + j];
    hr[j] = s;
  }
  float* r = rec3 + (size_t)n*10;
#pragma unroll
  for (int hh = 0; hh < 2; hh++) {
    float s = 0.f, d = 0.f;
#pragma unroll
    for (int c = 0; c < 4; c++) { s += hr[hh*4+c]*sas[hh*4+c]; d += hr[hh*4+c]*sad[hh*4+c]; }
    r[hh] = s;
    ed[n*8 + hh] = d;
  }
#pragma unroll
  for (int hh = 0; hh < 2; hh++) {
    f32x2 a = {hr[hh*4+0], hr[hh*4+1]};
    f32x2 b = {hr[hh*4+2], hr[hh*4+3]};
    *(f32x2*)(r + 2 + hh*4)     = a;
    *(f32x2*)(r + 2 + hh*4 + 2) = b;
  }
}

// ==================== wave-per-row gather passes ============================
template<int OS, int HOFF>
__global__ void __launch_bounds__(TPB) k_gat4(
    const int* __restrict__ rowptr, const int* __restrict__ rowend, const int* __restrict__ col,
    const unsigned* __restrict__ rec, const float* __restrict__ ed,
    const float* __restrict__ bias, float* __restrict__ out, int N)
{
  int wave = (blockIdx.x * TPB + threadIdx.x) >> 6;
  if (wave >= N) return;
  int lane = threadIdx.x & 63;
  int hh = lane & 3, j = lane >> 2;
  int d = wave;
  int e0 = rowptr[d], deg = rowend[d] - e0;
  float edv = ed[d*8 + HOFF + hh];
  float z = 0.f;
  f32x4 acc = {0.f, 0.f, 0.f, 0.f};
  for (int t = j; t <= deg; t += 16) {
    int s = (t == deg) ? d : __builtin_nontemporal_load(col + e0 + t);
    const unsigned* rp = rec + (size_t)s*10;
    unsigned ew = rp[hh >> 1];
    uint2 hv = *(const uint2*)(rp + 2 + 2*hh);
    float esv = ubf((ew >> ((hh & 1) * 16)) & 0xFFFFu);
    float w = __expf(lrelu(esv + edv));
    z += w;
    acc.x += w * ubf(hv.x & 0xFFFFu); acc.y += w * ubf(hv.x >> 16);
    acc.z += w * ubf(hv.y & 0xFFFFu); acc.w += w * ubf(hv.y >> 16);
  }
#pragma unroll
  for (int m = 4; m < 64; m <<= 1) {
    z += __shfl_xor(z, m);
    acc.x += __shfl_xor(acc.x, m); acc.y += __shfl_xor(acc.y, m);
    acc.z += __shfl_xor(acc.z, m); acc.w += __shfl_xor(acc.w, m);
  }
  if (j == 0) {
    float inv = 1.f / z;
    const f32x4 bb = *(const f32x4*)(bias + (HOFF + hh)*4);
    f32x4 o = { acc.x*inv + bb.x, acc.y*inv + bb.y, acc.z*inv + bb.z, acc.w*inv + bb.w };
    __builtin_nontemporal_store(o, (f32x4*)(out + (size_t)d*OS + (HOFF + hh)*4));
  }
}

__global__ void __launch_bounds__(TPB) k_gat3(
    const int* __restrict__ rowptr, const int* __restrict__ rowend, const int* __restrict__ col,
    const float* __restrict__ rec, const float* __restrict__ ed,
    const float* __restrict__ b3, float* __restrict__ x4, int N)
{
  int wave = (blockIdx.x * TPB + threadIdx.x) >> 6;
  if (wave >= N) return;
  int lane = threadIdx.x & 63;
  int hh = lane & 1, j = lane >> 1;
  int d = wave;
  int e0 = rowptr[d], deg = rowend[d] - e0;
  float edv = ed[d*8 + hh];
  float z = 0.f;
  f32x4 acc = {0.f, 0.f, 0.f, 0.f};
  for (int t = j; t <= deg; t += 32) {
    int s = (t == deg) ? d : __builtin_nontemporal_load(col + e0 + t);
    const float* rp = rec + (size_t)s*10;
    float esv = rp[hh];
    f32x2 a = *(const f32x2*)(rp + 2 + hh*4);
    f32x2 b = *(const f32x2*)(rp + 2 + hh*4 + 2);
    float w = __expf(lrelu(esv + edv));
    z += w; acc.x += w*a.x; acc.y += w*a.y; acc.z += w*b.x; acc.w += w*b.y;
  }
#pragma unroll
  for (int m = 2; m < 64; m <<= 1) {
    z += __shfl_xor(z, m);
    acc.x += __shfl_xor(acc.x, m); acc.y += __shfl_xor(acc.y, m);
    acc.z += __shfl_xor(acc.z, m); acc.w += __shfl_xor(acc.w, m);
  }
  if (j == 0) {
    float inv = 1.f / z;
    const f32x4 bb = *(const f32x4*)(b3 + hh*4);
    f32x4 o = { acc.x*inv + bb.x, acc.y*inv + bb.y, acc.z*inv + bb.z, acc.w*inv + bb.w };
    __builtin_nontemporal_store(o, (f32x4*)(x4 + d*8 + hh*4));
  }
}

__global__ void __launch_bounds__(TPB) k_adj_final(
    const int* __restrict__ rowptr, const int* __restrict__ rowend, const int* __restrict__ col,
    const float* __restrict__ x4, const float* __restrict__ Wl2,
    float* __restrict__ out, int N)
{
  __shared__ float sW[8];
  if (threadIdx.x < 8) sW[threadIdx.x] = Wl2[threadIdx.x];
  __syncthreads();
  int wave = (blockIdx.x * TPB + threadIdx.x) >> 6;
  if (wave >= N) return;
  int lane = threadIdx.x & 63;
  int q = lane & 1, j = lane >> 1;
  int r = wave;
  int e0 = rowptr[N + r], deg = rowend[N + r] - e0;
  f32x4 acc = {0.f, 0.f, 0.f, 0.f};
  for (int t = j; t < deg; t += 32) {
    int c = __builtin_nontemporal_load(col + e0 + t);
    f32x4 xv = *(const f32x4*)(x4 + c*8 + q*4);
    acc.x += xv.x; acc.y += xv.y; acc.z += xv.z; acc.w += xv.w;
  }
#pragma unroll
  for (int m = 2; m < 64; m <<= 1) {
    acc.x += __shfl_xor(acc.x, m); acc.y += __shfl_xor(acc.y, m);
    acc.z += __shfl_xor(acc.z, m); acc.w += __shfl_xor(acc.w, m);
  }
  float part = 0.f;
  if (j == 0) {
    float inv = deg > 0 ? 1.f / (float)deg : 0.f;
    f32x4 R = { acc.x*inv, acc.y*inv, acc.z*inv, acc.w*inv };
    f32x4 xo = *(const f32x4*)(x4 + r*8 + q*4);
    part = xo.x*R.x + xo.y*R.y + xo.z*R.z + xo.w*R.w
         + R.x*sW[q*4+0] + R.y*sW[q*4+1] + R.z*sW[q*4+2] + R.w*sW[q*4+3];
  }
  part += __shfl_xor(part, 1);
  if (lane == 0) out[r] = part;
}

// ============================ launch ========================================
extern "C" void kernel_launch(void* const* d_in, const int* in_sizes, int n_in,
                              void* d_out, int out_size, void* d_ws, size_t ws_size,
                              hipStream_t stream)
{
  const float* x1  = (const float*)d_in[0];
  const float* x2  = (const float*)d_in[1];
  const int*   ei  = (const int*)d_in[2];
  const float* Wq  = (const float*)d_in[4];
  const float* bq  = (const float*)d_in[5];
  const float* Wk  = (const float*)d_in[6];
  const float* bk  = (const float*)d_in[7];
  const float* Wv  = (const float*)d_in[8];
  const float* bv  = (const float*)d_in[9];
  const float* W1  = (const float*)d_in[10];
  const float* a1s = (const float*)d_in[11];
  const float* a1d = (const float*)d_in[12];
  const float* b1  = (const float*)d_in[13];
  const float* W2  = (const float*)d_in[14];
  const float* a2s = (const float*)d_in[15];
  const float* a2d = (const float*)d_in[16];
  const float* b2  = (const float*)d_in[17];
  const float* W3  = (const float*)d_in[18];
  const float* a3s = (const float*)d_in[19];
  const float* a3d = (const float*)d_in[20];
  const float* b3  = (const float*)d_in[21];
  const float* Wl2 = (const float*)d_in[22];

  int N = in_sizes[0] / 8;
  int E = in_sizes[2] / 2;
  int n2 = 2 * N;
  int NB = (n2 + 255) >> 8;             // CSR buckets (782)
  int gB = (E + EPB - 1) / EPB;         // k_bucket blocks (782)

  // ---- workspace ----
  float* sumexp = (float*)d_ws;                          // 16 (1 used, zeroed)
  int* rowptr   = (int*)(sumexp + 16);                   // 2N
  int* rowend   = rowptr + (size_t)n2;                   // 2N
  unsigned* itemsCSR = (unsigned*)(rowend + (size_t)n2); // NB*CAP (28.8 MB)
  unsigned* regionA  = itemsCSR + (size_t)NB * CAP;
  // phase 1 (CSR build): items2 + ofs live in regionA
  unsigned* items2 = regionA;                            // gB*8192 (25.6 MB)
  int* ofs = (int*)(items2 + (size_t)gB * (2 * EPB));    // gB*784  (2.45 MB)
  size_t raSize = (size_t)gB * (2 * EPB + OFSW);         // uints
  // phase 2 (dense+gather): recs/ed/escore alias regionA (items2/ofs dead)
  unsigned* rec1a = regionA;                             // 10N
  unsigned* rec1b = rec1a + 10ull*N;                     // 10N (aliased by x4 later)
  unsigned* rec2  = rec1b + 10ull*N;                     // 10N
  float* rec3     = (float*)(rec2 + 10ull*N);            // 10N
  float* ed       = rec3 + 10ull*N;                      // 8N
  float* escore   = ed + 8ull*N;                         // N   (49N total < raSize)
  float* X        = (float*)(regionA + raSize);          // 32N (X3 aliases, stride 16)
  float* X3 = X;
  float* x4 = (float*)rec1b;                             // 8N (rec1b dead by then)

  int gN = (N + TPB - 1) / TPB;
  int g64 = (int)(((long long)N * 64 + TPB - 1) / TPB);  // wave-per-row grids

  (void)hipMemsetAsync(sumexp, 0, 16 * sizeof(float), stream);

  // CSR build: block-sort (coalesced, atomic-free) -> per-bucket gather+sort
  k_bucket<<<gB, TPB, 0, stream>>>(ei, E, N, items2, ofs);
  k_csr2<<<NB, TPB, 0, stream>>>(ofs, items2, gB, itemsCSR, rowptr, rowend, n2);
  int* colv = (int*)itemsCSR;

  // dense prologue
  k_score<<<gN, TPB, 0, stream>>>(x1, x2, Wq, bq, Wk, bk, escore, sumexp, N);
  k_A1<<<gN, TPB, 0, stream>>>(x1, x2, Wv, bv, W1, a1s, a1d, escore, sumexp, rec1a, rec1b, ed, N);

  // GAT layer 1 (two 4-head passes)
  k_gat4<32, 0><<<g64, TPB, 0, stream>>>(rowptr, rowend, colv, rec1a, ed, b1, X, N);
  k_gat4<32, 4><<<g64, TPB, 0, stream>>>(rowptr, rowend, colv, rec1b, ed, b1, X, N);
  // GAT layer 2
  k_B2<<<gN, TPB, 0, stream>>>(W2, a2s, a2d, X, rec2, ed, N);
  k_gat4<16, 0><<<g64, TPB, 0, stream>>>(rowptr, rowend, colv, rec2, ed, b2, X3, N);
  // GAT layer 3
  k_B3<<<gN, TPB, 0, stream>>>(W3, a3s, a3d, X3, rec3, ed, N);
  k_gat3<<<g64, TPB, 0, stream>>>(rowptr, rowend, colv, rec3, ed, b3, x4, N);

  // adjacency readout (src-CSR rows [N,2N))
  k_adj_final<<<g64, TPB, 0, stream>>>(rowptr, rowend, colv, x4, Wl2, (float*)d_out, N);
}

// Round 11
// 495.544 us; speedup vs baseline: 3.9755x; 1.0617x over previous
//
#include <hip/hip_runtime.h>

#define TPB 256
#define CAP 9216       // per-bucket capacity (mean 8184, sigma ~90 -> +11 sigma)
#define EPB 4096       // edges per block in k_bucket (16/thread)
#define OFSW 784       // ofs table row stride (>= NB+1, 16-aligned)
#define GBPAD 784      // ofsT row stride (>= gB, 16-aligned)

typedef float f32x4 __attribute__((ext_vector_type(4)));
typedef float f32x2 __attribute__((ext_vector_type(2)));

__device__ __forceinline__ float lrelu(float x) { return x > 0.f ? x : 0.2f * x; }

// bf16 helpers (RNE pack)
__device__ __forceinline__ unsigned bfr(float x) {
  unsigned u = __float_as_uint(x);
  return (u + 0x7FFFu + ((u >> 16) & 1u)) >> 16;
}
__device__ __forceinline__ unsigned pk(float a, float b) { return bfr(a) | (bfr(b) << 16); }
__device__ __forceinline__ float ubf(unsigned us) { return __uint_as_float(us << 16); }

// ============================ bucketed CSR build ============================
// Pass 1: per-block LDS 1024-bin sort of 2*EPB items; output block-contiguous
// (fully coalesced, NO global atomics, NO scattered writes) + the block's
// bucket-offset row (exclusive scan) to a global ofs table.
__global__ void __launch_bounds__(TPB) k_bucket(
    const int* __restrict__ ei, int E, int N,
    unsigned* __restrict__ items2, int* __restrict__ ofs)
{
  __shared__ int hist[1024];            // counts -> rank counters
  __shared__ int lofs[1024];            // exclusive scan (stage offsets)
  __shared__ int scan_s[TPB];
  __shared__ unsigned stage[2 * EPB];   // 8192 items, bucket-major
  int tid = threadIdx.x;
  for (int i = tid; i < 1024; i += TPB) hist[i] = 0;
  int s0 = blockIdx.x * EPB;
  int nE = min(EPB, E - s0);
  int sv[16], dv[16];
  __syncthreads();
#pragma unroll
  for (int k = 0; k < 4; k++) {
    int li = tid * 4 + k * TPB * 4;
    if (li + 3 < nE) {
      int4 s4 = *(const int4*)(ei + s0 + li);
      int4 d4 = *(const int4*)(ei + E + s0 + li);
      sv[k*4+0] = s4.x; sv[k*4+1] = s4.y; sv[k*4+2] = s4.z; sv[k*4+3] = s4.w;
      dv[k*4+0] = d4.x; dv[k*4+1] = d4.y; dv[k*4+2] = d4.z; dv[k*4+3] = d4.w;
#pragma unroll
      for (int j = 0; j < 4; j++) {
        atomicAdd(&hist[dv[k*4+j] >> 8], 1);
        atomicAdd(&hist[(N + sv[k*4+j]) >> 8], 1);
      }
    } else {
      for (int j = 0; j < 4; j++) {
        if (li + j < nE) {
          sv[k*4+j] = ei[s0 + li + j];
          dv[k*4+j] = ei[E + s0 + li + j];
          atomicAdd(&hist[dv[k*4+j] >> 8], 1);
          atomicAdd(&hist[(N + sv[k*4+j]) >> 8], 1);
        }
      }
    }
  }
  __syncthreads();
  // 1024-bin exclusive scan; thread t owns bins 4t..4t+3
  int b0 = tid * 4;
  int c0 = hist[b0], c1 = hist[b0 + 1], c2 = hist[b0 + 2], c3 = hist[b0 + 3];
  int tsum = c0 + c1 + c2 + c3;
  scan_s[tid] = tsum;
  __syncthreads();
#pragma unroll
  for (int o = 1; o < TPB; o <<= 1) {
    int t = (tid >= o) ? scan_s[tid - o] : 0;
    __syncthreads();
    scan_s[tid] += t;
    __syncthreads();
  }
  int run = scan_s[tid] - tsum;
  int cs[4] = {c0, c1, c2, c3};
#pragma unroll
  for (int j = 0; j < 4; j++) {
    int b = b0 + j;
    lofs[b] = run;
    hist[b] = 0;                     // rank counters for phase 3
    run += cs[j];
  }
  __syncthreads();
  // phase 3: rank-scatter payload into LDS (bucket-major)
#pragma unroll
  for (int k = 0; k < 16; k++) {
    int li = tid * 4 + (k >> 2) * TPB * 4 + (k & 3);   // matches load indexing
    if (li < nE) {
      int s = sv[k], d = dv[k];
      int b1 = d >> 8;
      int p1 = lofs[b1] + atomicAdd(&hist[b1], 1);
      stage[p1] = ((unsigned)(d & 255) << 24) | (unsigned)s;
      int k2 = N + s, b2 = k2 >> 8;
      int p2 = lofs[b2] + atomicAdd(&hist[b2], 1);
      stage[p2] = ((unsigned)(k2 & 255) << 24) | (unsigned)d;
    }
  }
  __syncthreads();
  // phase 4: fully coalesced block-contiguous write-out + ofs row
  int total = 2 * nE;
  size_t obase = (size_t)blockIdx.x * (2 * EPB);
  for (int idx = tid; idx < total; idx += TPB)
    __builtin_nontemporal_store(stage[idx], items2 + obase + idx);
  int orow = blockIdx.x * OFSW;
  for (int i = tid; i < OFSW; i += TPB)
    ofs[orow + i] = lofs[i];         // lofs[b]=2*nE for b>=NB (empty bins)
}

// Tiled transpose of the ofs table: ofs[b*OFSW + k] -> ofsT[k*GBPAD + b].
// Makes k_csr2's per-bucket offset reads coalesced rows instead of strided cols.
__global__ void __launch_bounds__(TPB) k_t(
    const int* __restrict__ ofs, int* __restrict__ ofsT, int nB)
{
  __shared__ int tile[32][33];
  int lx = threadIdx.x & 31, ly = threadIdx.x >> 5;   // 32 x 8
  int b0 = blockIdx.y * 32, k0 = blockIdx.x * 32;
#pragma unroll
  for (int r = 0; r < 32; r += 8) {
    int b = b0 + ly + r, k = k0 + lx;
    tile[ly + r][lx] = (b < nB && k < OFSW) ? ofs[b * OFSW + k] : 0;
  }
  __syncthreads();
#pragma unroll
  for (int r = 0; r < 32; r += 8) {
    int k = k0 + ly + r, b = b0 + lx;
    if (k < OFSW && b < GBPAD) ofsT[k * GBPAD + b] = tile[lx][ly + r];
  }
}

// Pass 2: one block per bucket k — coalesced ofsT rows k/k+1, deterministic
// block scan for run destinations (no atomics/segdst), cached run copies,
// then 256-bin row-sort into the CSR.
__global__ void __launch_bounds__(TPB) k_csr2(
    const int* __restrict__ ofsT, const unsigned* __restrict__ items2, int nB,
    unsigned* __restrict__ items, int* __restrict__ rowptr, int* __restrict__ rowend, int n2)
{
  __shared__ unsigned stage[CAP];
  __shared__ int cnt_s[TPB], scan_s[TPB], off_s[TPB];
  int tid = threadIdx.x, k = blockIdx.x;
  cnt_s[tid] = 0;
  // each thread owns runs b = tid + m*TPB (m<4 covers nB<=1024); coalesced ofsT reads
  int o0[4], cl[4];
  int tsum = 0;
#pragma unroll
  for (int m = 0; m < 4; m++) {
    int b = tid + m * TPB;
    if (b < nB) {
      int a0 = ofsT[(size_t)k * GBPAD + b];
      int a1 = ofsT[(size_t)(k + 1) * GBPAD + b];
      o0[m] = a0; cl[m] = a1 - a0;
    } else { o0[m] = 0; cl[m] = 0; }
    tsum += cl[m];
  }
  scan_s[tid] = tsum;
  __syncthreads();
#pragma unroll
  for (int o = 1; o < TPB; o <<= 1) {
    int t = (tid >= o) ? scan_s[tid - o] : 0;
    __syncthreads();
    scan_s[tid] += t;
    __syncthreads();
  }
  int cnt = min(scan_s[TPB - 1], CAP);
  int dst = scan_s[tid] - tsum;
  // run copies: plain cached loads (each thread re-touches its run's lines)
#pragma unroll
  for (int m = 0; m < 4; m++) {
    int b = tid + m * TPB;
    const unsigned* src = items2 + (size_t)b * (2 * EPB) + o0[m];
    for (int j = 0; j < cl[m]; j++) {
      int p = dst + j;
      if (p < CAP) stage[p] = src[j];
    }
    dst += cl[m];
  }
  __syncthreads();
  for (int i = tid; i < cnt; i += TPB) atomicAdd(&cnt_s[stage[i] >> 24], 1);
  __syncthreads();
  int v = cnt_s[tid];
  scan_s[tid] = v;
  __syncthreads();
#pragma unroll
  for (int o = 1; o < TPB; o <<= 1) {
    int t = (tid >= o) ? scan_s[tid - o] : 0;
    __syncthreads();
    scan_s[tid] += t;
    __syncthreads();
  }
  int excl = scan_s[tid] - v;
  off_s[tid] = excl;
  size_t bbase = (size_t)k * CAP;
  int g = k * 256 + tid;
  if (g < n2) { rowptr[g] = (int)bbase + excl; rowend[g] = (int)bbase + excl + v; }
  cnt_s[tid] = 0;
  __syncthreads();
  for (int i = tid; i < cnt; i += TPB) {
    unsigned u = stage[i];
    int kk = u >> 24;
    int r = atomicAdd(&cnt_s[kk], 1);
    items[bbase + off_s[kk] + r] = u & 0xFFFFFFu;
  }
}

// ============================ dense node kernels ============================

__global__ void __launch_bounds__(TPB) k_score(
    const float* __restrict__ x1, const float* __restrict__ x2,
    const float* __restrict__ Wq, const float* __restrict__ bq,
    const float* __restrict__ Wk, const float* __restrict__ bk,
    float* __restrict__ escore, float* __restrict__ sumexp, int N)
{
  __shared__ float sWq[128], sWk[160], sbq[16], sbk[16];
  for (int i = threadIdx.x; i < 128; i += TPB) sWq[i] = Wq[i];
  for (int i = threadIdx.x; i < 160; i += TPB) sWk[i] = Wk[i];
  if (threadIdx.x < 16) { sbq[threadIdx.x] = bq[threadIdx.x]; sbk[threadIdx.x] = bk[threadIdx.x]; }
  __syncthreads();
  int n = blockIdx.x * TPB + threadIdx.x;
  float e = 0.f;
  if (n < N) {
    float a[8], b[10];
#pragma unroll
    for (int i = 0; i < 8; i++) a[i] = x1[n*8 + i];
#pragma unroll
    for (int i = 0; i < 10; i++) b[i] = x2[n*10 + i];
    float score = 0.f;
#pragma unroll
    for (int j = 0; j < 16; j++) {
      float q = sbq[j], k = sbk[j];
#pragma unroll
      for (int i = 0; i < 8; i++) q += a[i] * sWq[i*16 + j];
#pragma unroll
      for (int i = 0; i < 10; i++) k += b[i] * sWk[i*16 + j];
      score += q * k;
    }
    e = __expf(score);   // |score| small: exp safe without max-subtraction
    escore[n] = e;
  }
  float v = e;
#pragma unroll
  for (int off = 32; off > 0; off >>= 1) v += __shfl_down(v, off);
  __shared__ float red[TPB / 64];
  if ((threadIdx.x & 63) == 0) red[threadIdx.x >> 6] = v;
  __syncthreads();
  if (threadIdx.x == 0) {
    float s = 0.f;
#pragma unroll
    for (int w = 0; w < TPB / 64; w++) s += red[w];
    atomicAdd(sumexp, s);
  }
}

__global__ void __launch_bounds__(TPB) k_A1(
    const float* __restrict__ x1, const float* __restrict__ x2,
    const float* __restrict__ Wv, const float* __restrict__ bv,
    const float* __restrict__ W1, const float* __restrict__ a1s, const float* __restrict__ a1d,
    const float* __restrict__ escore, const float* __restrict__ sumexp,
    unsigned* __restrict__ rec1a, unsigned* __restrict__ rec1b,
    float* __restrict__ ed, int N)
{
  __shared__ float sWv[288], sbv[16], sW1[512], sas[32], sad[32];
  for (int i = threadIdx.x; i < 288; i += TPB) sWv[i] = Wv[i];
  for (int i = threadIdx.x; i < 512; i += TPB) sW1[i] = W1[i];
  if (threadIdx.x < 16) sbv[threadIdx.x] = bv[threadIdx.x];
  if (threadIdx.x < 32) { sas[threadIdx.x] = a1s[threadIdx.x]; sad[threadIdx.x] = a1d[threadIdx.x]; }
  __syncthreads();
  int n = blockIdx.x * TPB + threadIdx.x;
  if (n >= N) return;
  float w = escore[n] / sumexp[0];
  float f[16];
  {
    float a[8], b[10];
#pragma unroll
    for (int i = 0; i < 8; i++) a[i] = x1[n*8 + i];
#pragma unroll
    for (int i = 0; i < 10; i++) b[i] = x2[n*10 + i];
#pragma unroll
    for (int j = 0; j < 16; j++) {
      float v = sbv[j];
#pragma unroll
      for (int i = 0; i < 8; i++) v += a[i] * sWv[i*16 + j];
#pragma unroll
      for (int i = 0; i < 10; i++) v += b[i] * sWv[(8 + i)*16 + j];
      f[j] = w * v;
    }
  }
  float hr[32], esv[8], edv[8];
#pragma unroll
  for (int j = 0; j < 32; j++) {
    float s = 0.f;
#pragma unroll
    for (int i = 0; i < 16; i++) s += f[i] * sW1[i*32 + j];
    hr[j] = s;
  }
#pragma unroll
  for (int hh = 0; hh < 8; hh++) {
    float s = 0.f, d = 0.f;
#pragma unroll
    for (int c = 0; c < 4; c++) { s += hr[hh*4+c]*sas[hh*4+c]; d += hr[hh*4+c]*sad[hh*4+c]; }
    esv[hh] = s; edv[hh] = d;
  }
  unsigned* ra = rec1a + (size_t)n*10;
  unsigned* rb = rec1b + (size_t)n*10;
  ra[0] = pk(esv[0], esv[1]); ra[1] = pk(esv[2], esv[3]);
  rb[0] = pk(esv[4], esv[5]); rb[1] = pk(esv[6], esv[7]);
#pragma unroll
  for (int hh = 0; hh < 4; hh++) {
    ra[2+2*hh] = pk(hr[hh*4+0], hr[hh*4+1]);
    ra[3+2*hh] = pk(hr[hh*4+2], hr[hh*4+3]);
    rb[2+2*hh] = pk(hr[16+hh*4+0], hr[16+hh*4+1]);
    rb[3+2*hh] = pk(hr[16+hh*4+2], hr[16+hh*4+3]);
  }
  f32x4 e0 = {edv[0], edv[1], edv[2], edv[3]};
  f32x4 e1 = {edv[4], edv[5], edv[6], edv[7]};
  *(f32x4*)(ed + n*8)     = e0;
  *(f32x4*)(ed + n*8 + 4) = e1;
}

__global__ void __launch_bounds__(TPB) k_B2(
    const float* __restrict__ W2, const float* __restrict__ a2s, const float* __restrict__ a2d,
    const float* __restrict__ X,
    unsigned* __restrict__ rec2, float* __restrict__ ed, int N)
{
  __shared__ float sW[512], sas[16], sad[16];
  for (int i = threadIdx.x; i < 512; i += TPB) sW[i] = W2[i];
  if (threadIdx.x < 16) { sas[threadIdx.x] = a2s[threadIdx.x]; sad[threadIdx.x] = a2d[threadIdx.x]; }
  __syncthreads();
  int n = blockIdx.x * TPB + threadIdx.x;
  if (n >= N) return;
  float Xr[32];
#pragma unroll
  for (int i = 0; i < 8; i++) {
    f32x4 t = __builtin_nontemporal_load((const f32x4*)(X + n*32) + i);
    Xr[i*4+0] = t.x; Xr[i*4+1] = t.y; Xr[i*4+2] = t.z; Xr[i*4+3] = t.w;
  }
  float hr[16];
#pragma unroll
  for (int j = 0; j < 16; j++) {
    float s = 0.f;
#pragma unroll
    for (int f = 0; f < 32; f++) s += Xr[f] * sW[f*16 + j];
    hr[j] = s;
  }
  float esv[4], edv[4];
#pragma unroll
  for (int hh = 0; hh < 4; hh++) {
    float s = 0.f, d = 0.f;
#pragma unroll
    for (int c = 0; c < 4; c++) { s += hr[hh*4+c]*sas[hh*4+c]; d += hr[hh*4+c]*sad[hh*4+c]; }
    esv[hh] = s; edv[hh] = d;
  }
  unsigned* r = rec2 + (size_t)n*10;
  r[0] = pk(esv[0], esv[1]); r[1] = pk(esv[2], esv[3]);
#pragma unroll
  for (int hh = 0; hh < 4; hh++) {
    r[2+2*hh] = pk(hr[hh*4+0], hr[hh*4+1]);
    r[3+2*hh] = pk(hr[hh*4+2], hr[hh*4+3]);
  }
  f32x4 e0 = {edv[0], edv[1], edv[2], edv[3]};
  *(f32x4*)(ed + n*8) = e0;
}

__global__ void __launch_bounds__(TPB) k_B3(
    const float* __restrict__ W3, const float* __restrict__ a3s, const float* __restrict__ a3d,
    const float* __restrict__ X3,
    float* __restrict__ rec3, float* __restrict__ ed, int N)
{
  __shared__ float sW[128], sas[8], sad[8];
  for (int i = threadIdx.x; i < 128; i += TPB) sW[i] = W3[i];
  if (threadIdx.x < 8) { sas[threadIdx.x] = a3s[threadIdx.x]; sad[threadIdx.x] = a3d[threadIdx.x]; }
  __syncthreads();
  int n = blockIdx.x * TPB + threadIdx.x;
  if (n >= N) return;
  float Xr[16];
#pragma unroll
  for (int i = 0; i < 4; i++) {
    f32x4 t = __builtin_nontemporal_load((const f32x4*)(X3 + n*16) + i);
    Xr[i*4+0] = t.x; Xr[i*4+1] = t.y; Xr[i*4+2] = t.z; Xr[i*4+3] = t.w;
  }
  float hr[8];
#pragma unroll
  for (int j = 0; j < 8; j++) {
    float s = 0.f;
#pragma unroll
    for (int f = 0; f < 16; f++) s += Xr[f] * sW[f*8 + j];
    hr[j] = s;
  }
  float* r = rec3 + (size_t)n*10;
#pragma unroll
  for (int hh = 0; hh < 2; hh++) {
    float s = 0.f, d = 0.f;
#pragma unroll
    for (int c = 0; c < 4; c++) { s += hr[hh*4+c]*sas[hh*4+c]; d += hr[hh*4+c]*sad[hh*4+c]; }
    r[hh] = s;
    ed[n*8 + hh] = d;
  }
#pragma unroll
  for (int hh = 0; hh < 2; hh++) {
    f32x2 a = {hr[hh*4+0], hr[hh*4+1]};
    f32x2 b = {hr[hh*4+2], hr[hh*4+3]};
    *(f32x2*)(r + 2 + hh*4)     = a;
    *(f32x2*)(r + 2 + hh*4 + 2) = b;
  }
}

// ==================== wave-per-row gather passes ============================
template<int OS, int HOFF>
__global__ void __launch_bounds__(TPB) k_gat4(
    const int* __restrict__ rowptr, const int* __restrict__ rowend, const int* __restrict__ col,
    const unsigned* __restrict__ rec, const float* __restrict__ ed,
    const float* __restrict__ bias, float* __restrict__ out, int N)
{
  int wave = (blockIdx.x * TPB + threadIdx.x) >> 6;
  if (wave >= N) return;
  int lane = threadIdx.x & 63;
  int hh = lane & 3, j = lane >> 2;
  int d = wave;
  int e0 = rowptr[d], deg = rowend[d] - e0;
  float edv = ed[d*8 + HOFF + hh];
  float z = 0.f;
  f32x4 acc = {0.f, 0.f, 0.f, 0.f};
  for (int t = j; t <= deg; t += 16) {
    int s = (t == deg) ? d : __builtin_nontemporal_load(col + e0 + t);
    const unsigned* rp = rec + (size_t)s*10;
    unsigned ew = rp[hh >> 1];
    uint2 hv = *(const uint2*)(rp + 2 + 2*hh);
    float esv = ubf((ew >> ((hh & 1) * 16)) & 0xFFFFu);
    float w = __expf(lrelu(esv + edv));
    z += w;
    acc.x += w * ubf(hv.x & 0xFFFFu); acc.y += w * ubf(hv.x >> 16);
    acc.z += w * ubf(hv.y & 0xFFFFu); acc.w += w * ubf(hv.y >> 16);
  }
#pragma unroll
  for (int m = 4; m < 64; m <<= 1) {
    z += __shfl_xor(z, m);
    acc.x += __shfl_xor(acc.x, m); acc.y += __shfl_xor(acc.y, m);
    acc.z += __shfl_xor(acc.z, m); acc.w += __shfl_xor(acc.w, m);
  }
  if (j == 0) {
    float inv = 1.f / z;
    const f32x4 bb = *(const f32x4*)(bias + (HOFF + hh)*4);
    f32x4 o = { acc.x*inv + bb.x, acc.y*inv + bb.y, acc.z*inv + bb.z, acc.w*inv + bb.w };
    __builtin_nontemporal_store(o, (f32x4*)(out + (size_t)d*OS + (HOFF + hh)*4));
  }
}

__global__ void __launch_bounds__(TPB) k_gat3(
    const int* __restrict__ rowptr, const int* __restrict__ rowend, const int* __restrict__ col,
    const float* __restrict__ rec, const float* __restrict__ ed,
    const float* __restrict__ b3, float* __restrict__ x4, int N)
{
  int wave = (blockIdx.x * TPB + threadIdx.x) >> 6;
  if (wave >= N) return;
  int lane = threadIdx.x & 63;
  int hh = lane & 1, j = lane >> 1;
  int d = wave;
  int e0 = rowptr[d], deg = rowend[d] - e0;
  float edv = ed[d*8 + hh];
  float z = 0.f;
  f32x4 acc = {0.f, 0.f, 0.f, 0.f};
  for (int t = j; t <= deg; t += 32) {
    int s = (t == deg) ? d : __builtin_nontemporal_load(col + e0 + t);
    const float* rp = rec + (size_t)s*10;
    float esv = rp[hh];
    f32x2 a = *(const f32x2*)(rp + 2 + hh*4);
    f32x2 b = *(const f32x2*)(rp + 2 + hh*4 + 2);
    float w = __expf(lrelu(esv + edv));
    z += w; acc.x += w*a.x; acc.y += w*a.y; acc.z += w*b.x; acc.w += w*b.y;
  }
#pragma unroll
  for (int m = 2; m < 64; m <<= 1) {
    z += __shfl_xor(z, m);
    acc.x += __shfl_xor(acc.x, m); acc.y += __shfl_xor(acc.y, m);
    acc.z += __shfl_xor(acc.z, m); acc.w += __shfl_xor(acc.w, m);
  }
  if (j == 0) {
    float inv = 1.f / z;
    const f32x4 bb = *(const f32x4*)(b3 + hh*4);
    f32x4 o = { acc.x*inv + bb.x, acc.y*inv + bb.y, acc.z*inv + bb.z, acc.w*inv + bb.w };
    __builtin_nontemporal_store(o, (f32x4*)(x4 + d*8 + hh*4));
  }
}

__global__ void __launch_bounds__(TPB) k_adj_final(
    const int* __restrict__ rowptr, const int* __restrict__ rowend, const int* __restrict__ col,
    const float* __restrict__ x4, const float* __restrict__ Wl2,
    float* __restrict__ out, int N)
{
  __shared__ float sW[8];
  if (threadIdx.x < 8) sW[threadIdx.x] = Wl2[threadIdx.x];
  __syncthreads();
  int wave = (blockIdx.x * TPB + threadIdx.x) >> 6;
  if (wave >= N) return;
  int lane = threadIdx.x & 63;
  int q = lane & 1, j = lane >> 1;
  int r = wave;
  int e0 = rowptr[N + r], deg = rowend[N + r] - e0;
  f32x4 acc = {0.f, 0.f, 0.f, 0.f};
  for (int t = j; t < deg; t += 32) {
    int c = __builtin_nontemporal_load(col + e0 + t);
    f32x4 xv = *(const f32x4*)(x4 + c*8 + q*4);
    acc.x += xv.x; acc.y += xv.y; acc.z += xv.z; acc.w += xv.w;
  }
#pragma unroll
  for (int m = 2; m < 64; m <<= 1) {
    acc.x += __shfl_xor(acc.x, m); acc.y += __shfl_xor(acc.y, m);
    acc.z += __shfl_xor(acc.z, m); acc.w += __shfl_xor(acc.w, m);
  }
  float part = 0.f;
  if (j == 0) {
    float inv = deg > 0 ? 1.f / (float)deg : 0.f;
    f32x4 R = { acc.x*inv, acc.y*inv, acc.z*inv, acc.w*inv };
    f32x4 xo = *(const f32x4*)(x4 + r*8 + q*4);
    part = xo.x*R.x + xo.y*R.y + xo.z*R.z + xo.w*R.w
         + R.x*sW[q*4+0] + R.y*sW[q*4+1] + R.z*sW[q*4+2] + R.w*sW[q*4+3];
  }
  part += __shfl_xor(part, 1);
  if (lane == 0) out[r] = part;
}

// ============================ launch ========================================
extern "C" void kernel_launch(void* const* d_in, const int* in_sizes, int n_in,
                              void* d_out, int out_size, void* d_ws, size_t ws_size,
                              hipStream_t stream)
{
  const float* x1  = (const float*)d_in[0];
  const float* x2  = (const float*)d_in[1];
  const int*   ei  = (const int*)d_in[2];
  const float* Wq  = (const float*)d_in[4];
  const float* bq  = (const float*)d_in[5];
  const float* Wk  = (const float*)d_in[6];
  const float* bk  = (const float*)d_in[7];
  const float* Wv  = (const float*)d_in[8];
  const float* bv  = (const float*)d_in[9];
  const float* W1  = (const float*)d_in[10];
  const float* a1s = (const float*)d_in[11];
  const float* a1d = (const float*)d_in[12];
  const float* b1  = (const float*)d_in[13];
  const float* W2  = (const float*)d_in[14];
  const float* a2s = (const float*)d_in[15];
  const float* a2d = (const float*)d_in[16];
  const float* b2  = (const float*)d_in[17];
  const float* W3  = (const float*)d_in[18];
  const float* a3s = (const float*)d_in[19];
  const float* a3d = (const float*)d_in[20];
  const float* b3  = (const float*)d_in[21];
  const float* Wl2 = (const float*)d_in[22];

  int N = in_sizes[0] / 8;
  int E = in_sizes[2] / 2;
  int n2 = 2 * N;
  int NB = (n2 + 255) >> 8;             // CSR buckets (782)
  int gB = (E + EPB - 1) / EPB;         // k_bucket blocks (782)

  // ---- workspace ----
  float* sumexp = (float*)d_ws;                          // 16 (1 used, zeroed)
  int* rowptr   = (int*)(sumexp + 16);                   // 2N
  int* rowend   = rowptr + (size_t)n2;                   // 2N
  unsigned* itemsCSR = (unsigned*)(rowend + (size_t)n2); // NB*CAP (28.8 MB)
  unsigned* regionA  = itemsCSR + (size_t)NB * CAP;
  // phase 1 (CSR build): items2 + ofs + ofsT live in regionA
  unsigned* items2 = regionA;                            // gB*8192 (25.6 MB)
  int* ofs  = (int*)(items2 + (size_t)gB * (2 * EPB));   // gB*OFSW  (2.45 MB)
  int* ofsT = ofs + (size_t)gB * OFSW;                   // OFSW*GBPAD (2.46 MB)
  size_t raSize = (size_t)gB * (2 * EPB + OFSW) + (size_t)OFSW * GBPAD;
  // phase 2 (dense+gather): recs/ed/escore alias regionA (items2/ofs dead)
  unsigned* rec1a = regionA;                             // 10N
  unsigned* rec1b = rec1a + 10ull*N;                     // 10N (aliased by x4 later)
  unsigned* rec2  = rec1b + 10ull*N;                     // 10N
  float* rec3     = (float*)(rec2 + 10ull*N);            // 10N
  float* ed       = rec3 + 10ull*N;                      // 8N
  float* escore   = ed + 8ull*N;                         // N   (49N total < raSize)
  float* X        = (float*)(regionA + raSize);          // 32N (X3 aliases, stride 16)
  float* X3 = X;
  float* x4 = (float*)rec1b;                             // 8N (rec1b dead by then)

  int gN = (N + TPB - 1) / TPB;
  int g64 = (int)(((long long)N * 64 + TPB - 1) / TPB);  // wave-per-row grids

  (void)hipMemsetAsync(sumexp, 0, 16 * sizeof(float), stream);

  // CSR build: block-sort (coalesced, atomic-free) -> transpose ofs -> per-bucket gather+sort
  k_bucket<<<gB, TPB, 0, stream>>>(ei, E, N, items2, ofs);
  dim3 gt((OFSW + 31) / 32, (gB + 31) / 32);
  k_t<<<gt, TPB, 0, stream>>>(ofs, ofsT, gB);
  k_csr2<<<NB, TPB, 0, stream>>>(ofsT, items2, gB, itemsCSR, rowptr, rowend, n2);
  int* colv = (int*)itemsCSR;

  // dense prologue
  k_score<<<gN, TPB, 0, stream>>>(x1, x2, Wq, bq, Wk, bk, escore, sumexp, N);
  k_A1<<<gN, TPB, 0, stream>>>(x1, x2, Wv, bv, W1, a1s, a1d, escore, sumexp, rec1a, rec1b, ed, N);

  // GAT layer 1 (two 4-head passes)
  k_gat4<32, 0><<<g64, TPB, 0, stream>>>(rowptr, rowend, colv, rec1a, ed, b1, X, N);
  k_gat4<32, 4><<<g64, TPB, 0, stream>>>(rowptr, rowend, colv, rec1b, ed, b1, X, N);
  // GAT layer 2
  k_B2<<<gN, TPB, 0, stream>>>(W2, a2s, a2d, X, rec2, ed, N);
  k_gat4<16, 0><<<g64, TPB, 0, stream>>>(rowptr, rowend, colv, rec2, ed, b2, X3, N);
  // GAT layer 3
  k_B3<<<gN, TPB, 0, stream>>>(W3, a3s, a3d, X3, rec3, ed, N);
  k_gat3<<<g64, TPB, 0, stream>>>(rowptr, rowend, colv, rec3, ed, b3, x4, N);

  // adjacency readout (src-CSR rows [N,2N))
  k_adj_final<<<g64, TPB, 0, stream>>>(rowptr, rowend, colv, x4, Wl2, (float*)d_out, N);
}

// Round 12
// 482.771 us; speedup vs baseline: 4.0807x; 1.0265x over previous
//
#include <hip/hip_runtime.h>

#define TPB 256
#define CAP 9216       // per-bucket capacity (mean 8184, sigma ~90 -> +11 sigma)
#define EPB 4096       // edges per block in k_bucket (16/thread)
#define OFSW 784       // ofs table row stride (>= NB+1, 16-aligned)
#define GBPAD 784      // ofsT row stride (>= gB, 16-aligned)

typedef float f32x4 __attribute__((ext_vector_type(4)));
typedef float f32x2 __attribute__((ext_vector_type(2)));
typedef unsigned u32x4 __attribute__((ext_vector_type(4)));

__device__ __forceinline__ float lrelu(float x) { return x > 0.f ? x : 0.2f * x; }

// bf16 helpers (RNE pack)
__device__ __forceinline__ unsigned bfr(float x) {
  unsigned u = __float_as_uint(x);
  return (u + 0x7FFFu + ((u >> 16) & 1u)) >> 16;
}
__device__ __forceinline__ unsigned pk(float a, float b) { return bfr(a) | (bfr(b) << 16); }
__device__ __forceinline__ float ubf(unsigned us) { return __uint_as_float(us << 16); }

// ============================ bucketed CSR build ============================
// Pass 1: per-block LDS 1024-bin sort of 2*EPB items; output block-contiguous
// (fully coalesced, NO global atomics) + the block's bucket-offset row.
__global__ void __launch_bounds__(TPB) k_bucket(
    const int* __restrict__ ei, int E, int N,
    unsigned* __restrict__ items2, int* __restrict__ ofs)
{
  __shared__ int hist[1024];            // counts -> rank counters
  __shared__ int lofs[1024];            // exclusive scan (stage offsets)
  __shared__ int scan_s[TPB];
  __shared__ unsigned stage[2 * EPB];   // 8192 items, bucket-major
  int tid = threadIdx.x;
  for (int i = tid; i < 1024; i += TPB) hist[i] = 0;
  int s0 = blockIdx.x * EPB;
  int nE = min(EPB, E - s0);
  int sv[16], dv[16];
  __syncthreads();
#pragma unroll
  for (int k = 0; k < 4; k++) {
    int li = tid * 4 + k * TPB * 4;
    if (li + 3 < nE) {
      int4 s4 = *(const int4*)(ei + s0 + li);
      int4 d4 = *(const int4*)(ei + E + s0 + li);
      sv[k*4+0] = s4.x; sv[k*4+1] = s4.y; sv[k*4+2] = s4.z; sv[k*4+3] = s4.w;
      dv[k*4+0] = d4.x; dv[k*4+1] = d4.y; dv[k*4+2] = d4.z; dv[k*4+3] = d4.w;
#pragma unroll
      for (int j = 0; j < 4; j++) {
        atomicAdd(&hist[dv[k*4+j] >> 8], 1);
        atomicAdd(&hist[(N + sv[k*4+j]) >> 8], 1);
      }
    } else {
      for (int j = 0; j < 4; j++) {
        if (li + j < nE) {
          sv[k*4+j] = ei[s0 + li + j];
          dv[k*4+j] = ei[E + s0 + li + j];
          atomicAdd(&hist[dv[k*4+j] >> 8], 1);
          atomicAdd(&hist[(N + sv[k*4+j]) >> 8], 1);
        }
      }
    }
  }
  __syncthreads();
  int b0 = tid * 4;
  int c0 = hist[b0], c1 = hist[b0 + 1], c2 = hist[b0 + 2], c3 = hist[b0 + 3];
  int tsum = c0 + c1 + c2 + c3;
  scan_s[tid] = tsum;
  __syncthreads();
#pragma unroll
  for (int o = 1; o < TPB; o <<= 1) {
    int t = (tid >= o) ? scan_s[tid - o] : 0;
    __syncthreads();
    scan_s[tid] += t;
    __syncthreads();
  }
  int run = scan_s[tid] - tsum;
  int cs[4] = {c0, c1, c2, c3};
#pragma unroll
  for (int j = 0; j < 4; j++) {
    int b = b0 + j;
    lofs[b] = run;
    hist[b] = 0;
    run += cs[j];
  }
  __syncthreads();
#pragma unroll
  for (int k = 0; k < 16; k++) {
    int li = tid * 4 + (k >> 2) * TPB * 4 + (k & 3);
    if (li < nE) {
      int s = sv[k], d = dv[k];
      int b1 = d >> 8;
      int p1 = lofs[b1] + atomicAdd(&hist[b1], 1);
      stage[p1] = ((unsigned)(d & 255) << 24) | (unsigned)s;
      int k2 = N + s, b2 = k2 >> 8;
      int p2 = lofs[b2] + atomicAdd(&hist[b2], 1);
      stage[p2] = ((unsigned)(k2 & 255) << 24) | (unsigned)d;
    }
  }
  __syncthreads();
  int total = 2 * nE;
  size_t obase = (size_t)blockIdx.x * (2 * EPB);
  for (int idx = tid; idx < total; idx += TPB)
    __builtin_nontemporal_store(stage[idx], items2 + obase + idx);
  int orow = blockIdx.x * OFSW;
  for (int i = tid; i < OFSW; i += TPB)
    ofs[orow + i] = lofs[i];
}

// Tiled transpose of the ofs table.
__global__ void __launch_bounds__(TPB) k_t(
    const int* __restrict__ ofs, int* __restrict__ ofsT, int nB)
{
  __shared__ int tile[32][33];
  int lx = threadIdx.x & 31, ly = threadIdx.x >> 5;
  int b0 = blockIdx.y * 32, k0 = blockIdx.x * 32;
#pragma unroll
  for (int r = 0; r < 32; r += 8) {
    int b = b0 + ly + r, k = k0 + lx;
    tile[ly + r][lx] = (b < nB && k < OFSW) ? ofs[b * OFSW + k] : 0;
  }
  __syncthreads();
#pragma unroll
  for (int r = 0; r < 32; r += 8) {
    int k = k0 + ly + r, b = b0 + lx;
    if (k < OFSW && b < GBPAD) ofsT[k * GBPAD + b] = tile[lx][ly + r];
  }
}

// Pass 2: coalesced ofsT rows, deterministic block scan, uint4 run copies.
__global__ void __launch_bounds__(TPB) k_csr2(
    const int* __restrict__ ofsT, const unsigned* __restrict__ items2, int nB,
    unsigned* __restrict__ items, int* __restrict__ rowptr, int* __restrict__ rowend, int n2)
{
  __shared__ unsigned stage[CAP];
  __shared__ int cnt_s[TPB], scan_s[TPB], off_s[TPB];
  int tid = threadIdx.x, k = blockIdx.x;
  cnt_s[tid] = 0;
  int o0[4], cl[4];
  int tsum = 0;
#pragma unroll
  for (int m = 0; m < 4; m++) {
    int b = tid + m * TPB;
    if (b < nB) {
      int a0 = ofsT[(size_t)k * GBPAD + b];
      int a1 = ofsT[(size_t)(k + 1) * GBPAD + b];
      o0[m] = a0; cl[m] = a1 - a0;
    } else { o0[m] = 0; cl[m] = 0; }
    tsum += cl[m];
  }
  scan_s[tid] = tsum;
  __syncthreads();
#pragma unroll
  for (int o = 1; o < TPB; o <<= 1) {
    int t = (tid >= o) ? scan_s[tid - o] : 0;
    __syncthreads();
    scan_s[tid] += t;
    __syncthreads();
  }
  int cnt = min(scan_s[TPB - 1], CAP);
  int dst = scan_s[tid] - tsum;
  // run copies: source-aligned uint4 chunks (cached loads), scalar LDS stores
#pragma unroll
  for (int m = 0; m < 4; m++) {
    int b = tid + m * TPB;
    const unsigned* src = items2 + (size_t)b * (2 * EPB) + o0[m];
    int c = cl[m];
    int j = 0;
    int head = (4 - (o0[m] & 3)) & 3; if (head > c) head = c;
    for (; j < head; j++) { int p = dst + j; if (p < CAP) stage[p] = src[j]; }
    for (; j + 3 < c; j += 4) {
      u32x4 v = *(const u32x4*)(src + j);
      int p = dst + j;
      if (p + 3 < CAP) {
        stage[p] = v.x; stage[p+1] = v.y; stage[p+2] = v.z; stage[p+3] = v.w;
      } else {
        if (p < CAP) stage[p] = v.x;
        if (p+1 < CAP) stage[p+1] = v.y;
        if (p+2 < CAP) stage[p+2] = v.z;
        if (p+3 < CAP) stage[p+3] = v.w;
      }
    }
    for (; j < c; j++) { int p = dst + j; if (p < CAP) stage[p] = src[j]; }
    dst += c;
  }
  __syncthreads();
  for (int i = tid; i < cnt; i += TPB) atomicAdd(&cnt_s[stage[i] >> 24], 1);
  __syncthreads();
  int v = cnt_s[tid];
  scan_s[tid] = v;
  __syncthreads();
#pragma unroll
  for (int o = 1; o < TPB; o <<= 1) {
    int t = (tid >= o) ? scan_s[tid - o] : 0;
    __syncthreads();
    scan_s[tid] += t;
    __syncthreads();
  }
  int excl = scan_s[tid] - v;
  off_s[tid] = excl;
  size_t bbase = (size_t)k * CAP;
  int g = k * 256 + tid;
  if (g < n2) { rowptr[g] = (int)bbase + excl; rowend[g] = (int)bbase + excl + v; }
  cnt_s[tid] = 0;
  __syncthreads();
  for (int i = tid; i < cnt; i += TPB) {
    unsigned u = stage[i];
    int kk = u >> 24;
    int r = atomicAdd(&cnt_s[kk], 1);
    items[bbase + off_s[kk] + r] = u & 0xFFFFFFu;
  }
}

// ============================ dense node kernels ============================
// Record layout (head-contiguous, 16 B per head, 64 B-aligned):
//   u[hh*4+0] = f32 es[hh];  u[hh*4+1] = bf16 h[hh][0..1];  u[hh*4+2] = h[hh][2..3]
// One uint4 load per (edge, head) in the gathers; 4 heads share one 64 B line.

__global__ void __launch_bounds__(TPB) k_score(
    const float* __restrict__ x1, const float* __restrict__ x2,
    const float* __restrict__ Wq, const float* __restrict__ bq,
    const float* __restrict__ Wk, const float* __restrict__ bk,
    float* __restrict__ escore, float* __restrict__ sumexp, int N)
{
  __shared__ float sWq[128], sWk[160], sbq[16], sbk[16];
  for (int i = threadIdx.x; i < 128; i += TPB) sWq[i] = Wq[i];
  for (int i = threadIdx.x; i < 160; i += TPB) sWk[i] = Wk[i];
  if (threadIdx.x < 16) { sbq[threadIdx.x] = bq[threadIdx.x]; sbk[threadIdx.x] = bk[threadIdx.x]; }
  __syncthreads();
  int n = blockIdx.x * TPB + threadIdx.x;
  float e = 0.f;
  if (n < N) {
    float a[8], b[10];
#pragma unroll
    for (int i = 0; i < 8; i++) a[i] = x1[n*8 + i];
#pragma unroll
    for (int i = 0; i < 10; i++) b[i] = x2[n*10 + i];
    float score = 0.f;
#pragma unroll
    for (int j = 0; j < 16; j++) {
      float q = sbq[j], k = sbk[j];
#pragma unroll
      for (int i = 0; i < 8; i++) q += a[i] * sWq[i*16 + j];
#pragma unroll
      for (int i = 0; i < 10; i++) k += b[i] * sWk[i*16 + j];
      score += q * k;
    }
    e = __expf(score);   // |score| small: exp safe without max-subtraction
    escore[n] = e;
  }
  float v = e;
#pragma unroll
  for (int off = 32; off > 0; off >>= 1) v += __shfl_down(v, off);
  __shared__ float red[TPB / 64];
  if ((threadIdx.x & 63) == 0) red[threadIdx.x >> 6] = v;
  __syncthreads();
  if (threadIdx.x == 0) {
    float s = 0.f;
#pragma unroll
    for (int w = 0; w < TPB / 64; w++) s += red[w];
    atomicAdd(sumexp, s);
  }
}

__global__ void __launch_bounds__(TPB) k_A1(
    const float* __restrict__ x1, const float* __restrict__ x2,
    const float* __restrict__ Wv, const float* __restrict__ bv,
    const float* __restrict__ W1, const float* __restrict__ a1s, const float* __restrict__ a1d,
    const float* __restrict__ escore, const float* __restrict__ sumexp,
    unsigned* __restrict__ rec1a, unsigned* __restrict__ rec1b,
    float* __restrict__ ed, int N)
{
  __shared__ float sWv[288], sbv[16], sW1[512], sas[32], sad[32];
  for (int i = threadIdx.x; i < 288; i += TPB) sWv[i] = Wv[i];
  for (int i = threadIdx.x; i < 512; i += TPB) sW1[i] = W1[i];
  if (threadIdx.x < 16) sbv[threadIdx.x] = bv[threadIdx.x];
  if (threadIdx.x < 32) { sas[threadIdx.x] = a1s[threadIdx.x]; sad[threadIdx.x] = a1d[threadIdx.x]; }
  __syncthreads();
  int n = blockIdx.x * TPB + threadIdx.x;
  if (n >= N) return;
  float w = escore[n] / sumexp[0];
  float f[16];
  {
    float a[8], b[10];
#pragma unroll
    for (int i = 0; i < 8; i++) a[i] = x1[n*8 + i];
#pragma unroll
    for (int i = 0; i < 10; i++) b[i] = x2[n*10 + i];
#pragma unroll
    for (int j = 0; j < 16; j++) {
      float v = sbv[j];
#pragma unroll
      for (int i = 0; i < 8; i++) v += a[i] * sWv[i*16 + j];
#pragma unroll
      for (int i = 0; i < 10; i++) v += b[i] * sWv[(8 + i)*16 + j];
      f[j] = w * v;
    }
  }
  float hr[32], esv[8], edv[8];
#pragma unroll
  for (int j = 0; j < 32; j++) {
    float s = 0.f;
#pragma unroll
    for (int i = 0; i < 16; i++) s += f[i] * sW1[i*32 + j];
    hr[j] = s;
  }
#pragma unroll
  for (int hh = 0; hh < 8; hh++) {
    float s = 0.f, d = 0.f;
#pragma unroll
    for (int c = 0; c < 4; c++) { s += hr[hh*4+c]*sas[hh*4+c]; d += hr[hh*4+c]*sad[hh*4+c]; }
    esv[hh] = s; edv[hh] = d;
  }
  unsigned* ra = rec1a + (size_t)n*16;
  unsigned* rb = rec1b + (size_t)n*16;
#pragma unroll
  for (int hh = 0; hh < 4; hh++) {
    u32x4 qa = { __float_as_uint(esv[hh]),
                 pk(hr[hh*4+0], hr[hh*4+1]), pk(hr[hh*4+2], hr[hh*4+3]), 0u };
    u32x4 qb = { __float_as_uint(esv[4+hh]),
                 pk(hr[16+hh*4+0], hr[16+hh*4+1]), pk(hr[16+hh*4+2], hr[16+hh*4+3]), 0u };
    __builtin_nontemporal_store(qa, (u32x4*)(ra + hh*4));
    __builtin_nontemporal_store(qb, (u32x4*)(rb + hh*4));
  }
  f32x4 e0 = {edv[0], edv[1], edv[2], edv[3]};
  f32x4 e1 = {edv[4], edv[5], edv[6], edv[7]};
  *(f32x4*)(ed + n*8)     = e0;
  *(f32x4*)(ed + n*8 + 4) = e1;
}

__global__ void __launch_bounds__(TPB) k_B2(
    const float* __restrict__ W2, const float* __restrict__ a2s, const float* __restrict__ a2d,
    const float* __restrict__ X,
    unsigned* __restrict__ rec2, float* __restrict__ ed, int N)
{
  __shared__ float sW[512], sas[16], sad[16];
  for (int i = threadIdx.x; i < 512; i += TPB) sW[i] = W2[i];
  if (threadIdx.x < 16) { sas[threadIdx.x] = a2s[threadIdx.x]; sad[threadIdx.x] = a2d[threadIdx.x]; }
  __syncthreads();
  int n = blockIdx.x * TPB + threadIdx.x;
  if (n >= N) return;
  float Xr[32];
#pragma unroll
  for (int i = 0; i < 8; i++) {
    f32x4 t = __builtin_nontemporal_load((const f32x4*)(X + n*32) + i);
    Xr[i*4+0] = t.x; Xr[i*4+1] = t.y; Xr[i*4+2] = t.z; Xr[i*4+3] = t.w;
  }
  float hr[16];
#pragma unroll
  for (int j = 0; j < 16; j++) {
    float s = 0.f;
#pragma unroll
    for (int f = 0; f < 32; f++) s += Xr[f] * sW[f*16 + j];
    hr[j] = s;
  }
  unsigned* r = rec2 + (size_t)n*16;
#pragma unroll
  for (int hh = 0; hh < 4; hh++) {
    float s = 0.f, d = 0.f;
#pragma unroll
    for (int c = 0; c < 4; c++) { s += hr[hh*4+c]*sas[hh*4+c]; d += hr[hh*4+c]*sad[hh*4+c]; }
    u32x4 q = { __float_as_uint(s),
                pk(hr[hh*4+0], hr[hh*4+1]), pk(hr[hh*4+2], hr[hh*4+3]), 0u };
    __builtin_nontemporal_store(q, (u32x4*)(r + hh*4));
    ed[n*8 + hh] = d;
  }
}

__global__ void __launch_bounds__(TPB) k_B3(
    const float* __restrict__ W3, const float* __restrict__ a3s, const float* __restrict__ a3d,
    const float* __restrict__ X3,
    unsigned* __restrict__ rec3, float* __restrict__ ed, int N)
{
  __shared__ float sW[128], sas[8], sad[8];
  for (int i = threadIdx.x; i < 128; i += TPB) sW[i] = W3[i];
  if (threadIdx.x < 8) { sas[threadIdx.x] = a3s[threadIdx.x]; sad[threadIdx.x] = a3d[threadIdx.x]; }
  __syncthreads();
  int n = blockIdx.x * TPB + threadIdx.x;
  if (n >= N) return;
  float Xr[16];
#pragma unroll
  for (int i = 0; i < 4; i++) {
    f32x4 t = __builtin_nontemporal_load((const f32x4*)(X3 + n*16) + i);
    Xr[i*4+0] = t.x; Xr[i*4+1] = t.y; Xr[i*4+2] = t.z; Xr[i*4+3] = t.w;
  }
  float hr[8];
#pragma unroll
  for (int j = 0; j < 8; j++) {
    float s = 0.f;
#pragma unroll
    for (int f = 0; f < 16; f++) s += Xr[f] * sW[f*8 + j];
    hr[j] = s;
  }
  unsigned* r = rec3 + (size_t)n*8;   // 32 B record, 2 heads x 16 B
#pragma unroll
  for (int hh = 0; hh < 2; hh++) {
    float s = 0.f, d = 0.f;
#pragma unroll
    for (int c = 0; c < 4; c++) { s += hr[hh*4+c]*sas[hh*4+c]; d += hr[hh*4+c]*sad[hh*4+c]; }
    u32x4 q = { __float_as_uint(s),
                pk(hr[hh*4+0], hr[hh*4+1]), pk(hr[hh*4+2], hr[hh*4+3]), 0u };
    __builtin_nontemporal_store(q, (u32x4*)(r + hh*4));
    ed[n*8 + hh] = d;
  }
}

// ==================== wave-per-row gather passes ============================
// 4 heads x 16 slots; ONE uint4 record load per (edge, head); the 4 heads of
// a slot share one 64 B line. Self-loop at t==deg.
template<int OS, int HOFF>
__global__ void __launch_bounds__(TPB) k_gat4(
    const int* __restrict__ rowptr, const int* __restrict__ rowend, const int* __restrict__ col,
    const unsigned* __restrict__ rec, const float* __restrict__ ed,
    const float* __restrict__ bias, float* __restrict__ out, int N)
{
  int wave = (blockIdx.x * TPB + threadIdx.x) >> 6;
  if (wave >= N) return;
  int lane = threadIdx.x & 63;
  int hh = lane & 3, j = lane >> 2;
  int d = wave;
  int e0 = rowptr[d], deg = rowend[d] - e0;
  float edv = ed[d*8 + HOFF + hh];
  float z = 0.f;
  f32x4 acc = {0.f, 0.f, 0.f, 0.f};
  for (int t = j; t <= deg; t += 16) {
    int s = (t == deg) ? d : __builtin_nontemporal_load(col + e0 + t);
    u32x4 q = *(const u32x4*)(rec + (size_t)s*16 + hh*4);
    float w = __expf(lrelu(__uint_as_float(q.x) + edv));
    z += w;
    acc.x += w * ubf(q.y & 0xFFFFu); acc.y += w * ubf(q.y >> 16);
    acc.z += w * ubf(q.z & 0xFFFFu); acc.w += w * ubf(q.z >> 16);
  }
#pragma unroll
  for (int m = 4; m < 64; m <<= 1) {
    z += __shfl_xor(z, m);
    acc.x += __shfl_xor(acc.x, m); acc.y += __shfl_xor(acc.y, m);
    acc.z += __shfl_xor(acc.z, m); acc.w += __shfl_xor(acc.w, m);
  }
  if (j == 0) {
    float inv = 1.f / z;
    const f32x4 bb = *(const f32x4*)(bias + (HOFF + hh)*4);
    f32x4 o = { acc.x*inv + bb.x, acc.y*inv + bb.y, acc.z*inv + bb.z, acc.w*inv + bb.w };
    __builtin_nontemporal_store(o, (f32x4*)(out + (size_t)d*OS + (HOFF + hh)*4));
  }
}

// Layer 3: 2 heads x 32 slots; 32 B records.
__global__ void __launch_bounds__(TPB) k_gat3(
    const int* __restrict__ rowptr, const int* __restrict__ rowend, const int* __restrict__ col,
    const unsigned* __restrict__ rec, const float* __restrict__ ed,
    const float* __restrict__ b3, float* __restrict__ x4, int N)
{
  int wave = (blockIdx.x * TPB + threadIdx.x) >> 6;
  if (wave >= N) return;
  int lane = threadIdx.x & 63;
  int hh = lane & 1, j = lane >> 1;
  int d = wave;
  int e0 = rowptr[d], deg = rowend[d] - e0;
  float edv = ed[d*8 + hh];
  float z = 0.f;
  f32x4 acc = {0.f, 0.f, 0.f, 0.f};
  for (int t = j; t <= deg; t += 32) {
    int s = (t == deg) ? d : __builtin_nontemporal_load(col + e0 + t);
    u32x4 q = *(const u32x4*)(rec + (size_t)s*8 + hh*4);
    float w = __expf(lrelu(__uint_as_float(q.x) + edv));
    z += w;
    acc.x += w * ubf(q.y & 0xFFFFu); acc.y += w * ubf(q.y >> 16);
    acc.z += w * ubf(q.z & 0xFFFFu); acc.w += w * ubf(q.z >> 16);
  }
#pragma unroll
  for (int m = 2; m < 64; m <<= 1) {
    z += __shfl_xor(z, m);
    acc.x += __shfl_xor(acc.x, m); acc.y += __shfl_xor(acc.y, m);
    acc.z += __shfl_xor(acc.z, m); acc.w += __shfl_xor(acc.w, m);
  }
  if (j == 0) {
    float inv = 1.f / z;
    const f32x4 bb = *(const f32x4*)(b3 + hh*4);
    f32x4 o = { acc.x*inv + bb.x, acc.y*inv + bb.y, acc.z*inv + bb.z, acc.w*inv + bb.w };
    __builtin_nontemporal_store(o, (f32x4*)(x4 + d*8 + hh*4));
  }
}

__global__ void __launch_bounds__(TPB) k_adj_final(
    const int* __restrict__ rowptr, const int* __restrict__ rowend, const int* __restrict__ col,
    const float* __restrict__ x4, const float* __restrict__ Wl2,
    float* __restrict__ out, int N)
{
  __shared__ float sW[8];
  if (threadIdx.x < 8) sW[threadIdx.x] = Wl2[threadIdx.x];
  __syncthreads();
  int wave = (blockIdx.x * TPB + threadIdx.x) >> 6;
  if (wave >= N) return;
  int lane = threadIdx.x & 63;
  int q = lane & 1, j = lane >> 1;
  int r = wave;
  int e0 = rowptr[N + r], deg = rowend[N + r] - e0;
  f32x4 acc = {0.f, 0.f, 0.f, 0.f};
  for (int t = j; t < deg; t += 32) {
    int c = __builtin_nontemporal_load(col + e0 + t);
    f32x4 xv = *(const f32x4*)(x4 + c*8 + q*4);
    acc.x += xv.x; acc.y += xv.y; acc.z += xv.z; acc.w += xv.w;
  }
#pragma unroll
  for (int m = 2; m < 64; m <<= 1) {
    acc.x += __shfl_xor(acc.x, m); acc.y += __shfl_xor(acc.y, m);
    acc.z += __shfl_xor(acc.z, m); acc.w += __shfl_xor(acc.w, m);
  }
  float part = 0.f;
  if (j == 0) {
    float inv = deg > 0 ? 1.f / (float)deg : 0.f;
    f32x4 R = { acc.x*inv, acc.y*inv, acc.z*inv, acc.w*inv };
    f32x4 xo = *(const f32x4*)(x4 + r*8 + q*4);
    part = xo.x*R.x + xo.y*R.y + xo.z*R.z + xo.w*R.w
         + R.x*sW[q*4+0] + R.y*sW[q*4+1] + R.z*sW[q*4+2] + R.w*sW[q*4+3];
  }
  part += __shfl_xor(part, 1);
  if (lane == 0) out[r] = part;
}

// ============================ launch ========================================
extern "C" void kernel_launch(void* const* d_in, const int* in_sizes, int n_in,
                              void* d_out, int out_size, void* d_ws, size_t ws_size,
                              hipStream_t stream)
{
  const float* x1  = (const float*)d_in[0];
  const float* x2  = (const float*)d_in[1];
  const int*   ei  = (const int*)d_in[2];
  const float* Wq  = (const float*)d_in[4];
  const float* bq  = (const float*)d_in[5];
  const float* Wk  = (const float*)d_in[6];
  const float* bk  = (const float*)d_in[7];
  const float* Wv  = (const float*)d_in[8];
  const float* bv  = (const float*)d_in[9];
  const float* W1  = (const float*)d_in[10];
  const float* a1s = (const float*)d_in[11];
  const float* a1d = (const float*)d_in[12];
  const float* b1  = (const float*)d_in[13];
  const float* W2  = (const float*)d_in[14];
  const float* a2s = (const float*)d_in[15];
  const float* a2d = (const float*)d_in[16];
  const float* b2  = (const float*)d_in[17];
  const float* W3  = (const float*)d_in[18];
  const float* a3s = (const float*)d_in[19];
  const float* a3d = (const float*)d_in[20];
  const float* b3  = (const float*)d_in[21];
  const float* Wl2 = (const float*)d_in[22];

  int N = in_sizes[0] / 8;
  int E = in_sizes[2] / 2;
  int n2 = 2 * N;
  int NB = (n2 + 255) >> 8;             // CSR buckets (782)
  int gB = (E + EPB - 1) / EPB;         // k_bucket blocks (782)

  // ---- workspace ----
  float* sumexp = (float*)d_ws;                          // 16 (1 used, zeroed)
  int* rowptr   = (int*)(sumexp + 16);                   // 2N
  int* rowend   = rowptr + (size_t)n2;                   // 2N
  unsigned* itemsCSR = (unsigned*)(rowend + (size_t)n2); // NB*CAP (28.8 MB)
  unsigned* regionA  = itemsCSR + (size_t)NB * CAP;
  // phase 1 (CSR build): items2 + ofs + ofsT live in regionA
  unsigned* items2 = regionA;                            // gB*8192 (25.6 MB)
  int* ofs  = (int*)(items2 + (size_t)gB * (2 * EPB));   // gB*OFSW
  int* ofsT = ofs + (size_t)gB * OFSW;                   // OFSW*GBPAD
  size_t raSize = (size_t)gB * (2 * EPB + OFSW) + (size_t)OFSW * GBPAD;
  // phase 2: recs/ed/escore alias regionA (items2/ofs dead). 16N+16N+16N+8N+8N+N = 65N < raSize ✓
  unsigned* rec1a = regionA;                             // 16N (6.4 MB)
  unsigned* rec1b = rec1a + 16ull*N;                     // 16N (aliased by x4 later)
  unsigned* rec2  = rec1b + 16ull*N;                     // 16N
  unsigned* rec3  = rec2 + 16ull*N;                      // 8N (3.2 MB)
  float* ed       = (float*)(rec3 + 8ull*N);             // 8N
  float* escore   = ed + 8ull*N;                         // N
  float* X        = (float*)(regionA + raSize);          // 32N (X3 aliases, stride 16)
  float* X3 = X;
  float* x4 = (float*)rec1b;                             // 8N (rec1b dead by then)

  int gN = (N + TPB - 1) / TPB;
  int g64 = (int)(((long long)N * 64 + TPB - 1) / TPB);  // wave-per-row grids

  (void)hipMemsetAsync(sumexp, 0, 16 * sizeof(float), stream);

  // CSR build
  k_bucket<<<gB, TPB, 0, stream>>>(ei, E, N, items2, ofs);
  dim3 gt((OFSW + 31) / 32, (gB + 31) / 32);
  k_t<<<gt, TPB, 0, stream>>>(ofs, ofsT, gB);
  k_csr2<<<NB, TPB, 0, stream>>>(ofsT, items2, gB, itemsCSR, rowptr, rowend, n2);
  int* colv = (int*)itemsCSR;

  // dense prologue
  k_score<<<gN, TPB, 0, stream>>>(x1, x2, Wq, bq, Wk, bk, escore, sumexp, N);
  k_A1<<<gN, TPB, 0, stream>>>(x1, x2, Wv, bv, W1, a1s, a1d, escore, sumexp, rec1a, rec1b, ed, N);

  // GAT layer 1 (two 4-head passes)
  k_gat4<32, 0><<<g64, TPB, 0, stream>>>(rowptr, rowend, colv, rec1a, ed, b1, X, N);
  k_gat4<32, 4><<<g64, TPB, 0, stream>>>(rowptr, rowend, colv, rec1b, ed, b1, X, N);
  // GAT layer 2
  k_B2<<<gN, TPB, 0, stream>>>(W2, a2s, a2d, X, rec2, ed, N);
  k_gat4<16, 0><<<g64, TPB, 0, stream>>>(rowptr, rowend, colv, rec2, ed, b2, X3, N);
  // GAT layer 3
  k_B3<<<gN, TPB, 0, stream>>>(W3, a3s, a3d, X3, rec3, ed, N);
  k_gat3<<<g64, TPB, 0, stream>>>(rowptr, rowend, colv, rec3, ed, b3, x4, N);

  // adjacency readout (src-CSR rows [N,2N))
  k_adj_final<<<g64, TPB, 0, stream>>>(rowptr, rowend, colv, x4, Wl2, (float*)d_out, N);
}

// Round 13
// 475.346 us; speedup vs baseline: 4.1444x; 1.0156x over previous
//
#include <hip/hip_runtime.h>

#define TPB 256
#define CAP 9216       // per-bucket capacity (mean 8184, sigma ~90 -> +11 sigma)
#define EPB 4096       // edges per block in k_bucket (16/thread)
#define OFSW 784       // ofs table row stride (>= NB+1, 16-aligned)
#define GBPAD 784      // ofsT row stride (>= gB, 16-aligned)

typedef float f32x4 __attribute__((ext_vector_type(4)));
typedef float f32x2 __attribute__((ext_vector_type(2)));
typedef unsigned u32x4 __attribute__((ext_vector_type(4)));

__device__ __forceinline__ float lrelu(float x) { return x > 0.f ? x : 0.2f * x; }

// bf16 helpers (RNE pack)
__device__ __forceinline__ unsigned bfr(float x) {
  unsigned u = __float_as_uint(x);
  return (u + 0x7FFFu + ((u >> 16) & 1u)) >> 16;
}
__device__ __forceinline__ unsigned pk(float a, float b) { return bfr(a) | (bfr(b) << 16); }
__device__ __forceinline__ float ubf(unsigned us) { return __uint_as_float(us << 16); }

// ============================ bucketed CSR build ============================
__global__ void __launch_bounds__(TPB) k_bucket(
    const int* __restrict__ ei, int E, int N,
    unsigned* __restrict__ items2, int* __restrict__ ofs)
{
  __shared__ int hist[1024];
  __shared__ int lofs[1024];
  __shared__ int scan_s[TPB];
  __shared__ unsigned stage[2 * EPB];
  int tid = threadIdx.x;
  for (int i = tid; i < 1024; i += TPB) hist[i] = 0;
  int s0 = blockIdx.x * EPB;
  int nE = min(EPB, E - s0);
  int sv[16], dv[16];
  __syncthreads();
#pragma unroll
  for (int k = 0; k < 4; k++) {
    int li = tid * 4 + k * TPB * 4;
    if (li + 3 < nE) {
      int4 s4 = *(const int4*)(ei + s0 + li);
      int4 d4 = *(const int4*)(ei + E + s0 + li);
      sv[k*4+0] = s4.x; sv[k*4+1] = s4.y; sv[k*4+2] = s4.z; sv[k*4+3] = s4.w;
      dv[k*4+0] = d4.x; dv[k*4+1] = d4.y; dv[k*4+2] = d4.z; dv[k*4+3] = d4.w;
#pragma unroll
      for (int j = 0; j < 4; j++) {
        atomicAdd(&hist[dv[k*4+j] >> 8], 1);
        atomicAdd(&hist[(N + sv[k*4+j]) >> 8], 1);
      }
    } else {
      for (int j = 0; j < 4; j++) {
        if (li + j < nE) {
          sv[k*4+j] = ei[s0 + li + j];
          dv[k*4+j] = ei[E + s0 + li + j];
          atomicAdd(&hist[dv[k*4+j] >> 8], 1);
          atomicAdd(&hist[(N + sv[k*4+j]) >> 8], 1);
        }
      }
    }
  }
  __syncthreads();
  int b0 = tid * 4;
  int c0 = hist[b0], c1 = hist[b0 + 1], c2 = hist[b0 + 2], c3 = hist[b0 + 3];
  int tsum = c0 + c1 + c2 + c3;
  scan_s[tid] = tsum;
  __syncthreads();
#pragma unroll
  for (int o = 1; o < TPB; o <<= 1) {
    int t = (tid >= o) ? scan_s[tid - o] : 0;
    __syncthreads();
    scan_s[tid] += t;
    __syncthreads();
  }
  int run = scan_s[tid] - tsum;
  int cs[4] = {c0, c1, c2, c3};
#pragma unroll
  for (int j = 0; j < 4; j++) {
    int b = b0 + j;
    lofs[b] = run;
    hist[b] = 0;
    run += cs[j];
  }
  __syncthreads();
#pragma unroll
  for (int k = 0; k < 16; k++) {
    int li = tid * 4 + (k >> 2) * TPB * 4 + (k & 3);
    if (li < nE) {
      int s = sv[k], d = dv[k];
      int b1 = d >> 8;
      int p1 = lofs[b1] + atomicAdd(&hist[b1], 1);
      stage[p1] = ((unsigned)(d & 255) << 24) | (unsigned)s;
      int k2 = N + s, b2 = k2 >> 8;
      int p2 = lofs[b2] + atomicAdd(&hist[b2], 1);
      stage[p2] = ((unsigned)(k2 & 255) << 24) | (unsigned)d;
    }
  }
  __syncthreads();
  int total = 2 * nE;
  size_t obase = (size_t)blockIdx.x * (2 * EPB);
  for (int idx = tid; idx < total; idx += TPB)
    __builtin_nontemporal_store(stage[idx], items2 + obase + idx);
  int orow = blockIdx.x * OFSW;
  for (int i = tid; i < OFSW; i += TPB)
    ofs[orow + i] = lofs[i];
}

// Tiled transpose of the ofs table.
__global__ void __launch_bounds__(TPB) k_t(
    const int* __restrict__ ofs, int* __restrict__ ofsT, int nB)
{
  __shared__ int tile[32][33];
  int lx = threadIdx.x & 31, ly = threadIdx.x >> 5;
  int b0 = blockIdx.y * 32, k0 = blockIdx.x * 32;
#pragma unroll
  for (int r = 0; r < 32; r += 8) {
    int b = b0 + ly + r, k = k0 + lx;
    tile[ly + r][lx] = (b < nB && k < OFSW) ? ofs[b * OFSW + k] : 0;
  }
  __syncthreads();
#pragma unroll
  for (int r = 0; r < 32; r += 8) {
    int k = k0 + ly + r, b = b0 + lx;
    if (k < OFSW && b < GBPAD) ofsT[k * GBPAD + b] = tile[lx][ly + r];
  }
}

// Pass 2: coalesced ofsT rows, deterministic block scan, uint4 run copies.
__global__ void __launch_bounds__(TPB) k_csr2(
    const int* __restrict__ ofsT, const unsigned* __restrict__ items2, int nB,
    unsigned* __restrict__ items, int* __restrict__ rowptr, int* __restrict__ rowend, int n2)
{
  __shared__ unsigned stage[CAP];
  __shared__ int cnt_s[TPB], scan_s[TPB], off_s[TPB];
  int tid = threadIdx.x, k = blockIdx.x;
  cnt_s[tid] = 0;
  int o0[4], cl[4];
  int tsum = 0;
#pragma unroll
  for (int m = 0; m < 4; m++) {
    int b = tid + m * TPB;
    if (b < nB) {
      int a0 = ofsT[(size_t)k * GBPAD + b];
      int a1 = ofsT[(size_t)(k + 1) * GBPAD + b];
      o0[m] = a0; cl[m] = a1 - a0;
    } else { o0[m] = 0; cl[m] = 0; }
    tsum += cl[m];
  }
  scan_s[tid] = tsum;
  __syncthreads();
#pragma unroll
  for (int o = 1; o < TPB; o <<= 1) {
    int t = (tid >= o) ? scan_s[tid - o] : 0;
    __syncthreads();
    scan_s[tid] += t;
    __syncthreads();
  }
  int cnt = min(scan_s[TPB - 1], CAP);
  int dst = scan_s[tid] - tsum;
#pragma unroll
  for (int m = 0; m < 4; m++) {
    int b = tid + m * TPB;
    const unsigned* src = items2 + (size_t)b * (2 * EPB) + o0[m];
    int c = cl[m];
    int j = 0;
    int head = (4 - (o0[m] & 3)) & 3; if (head > c) head = c;
    for (; j < head; j++) { int p = dst + j; if (p < CAP) stage[p] = src[j]; }
    for (; j + 3 < c; j += 4) {
      u32x4 v = *(const u32x4*)(src + j);
      int p = dst + j;
      if (p + 3 < CAP) {
        stage[p] = v.x; stage[p+1] = v.y; stage[p+2] = v.z; stage[p+3] = v.w;
      } else {
        if (p < CAP) stage[p] = v.x;
        if (p+1 < CAP) stage[p+1] = v.y;
        if (p+2 < CAP) stage[p+2] = v.z;
        if (p+3 < CAP) stage[p+3] = v.w;
      }
    }
    for (; j < c; j++) { int p = dst + j; if (p < CAP) stage[p] = src[j]; }
    dst += c;
  }
  __syncthreads();
  for (int i = tid; i < cnt; i += TPB) atomicAdd(&cnt_s[stage[i] >> 24], 1);
  __syncthreads();
  int v = cnt_s[tid];
  scan_s[tid] = v;
  __syncthreads();
#pragma unroll
  for (int o = 1; o < TPB; o <<= 1) {
    int t = (tid >= o) ? scan_s[tid - o] : 0;
    __syncthreads();
    scan_s[tid] += t;
    __syncthreads();
  }
  int excl = scan_s[tid] - v;
  off_s[tid] = excl;
  size_t bbase = (size_t)k * CAP;
  int g = k * 256 + tid;
  if (g < n2) { rowptr[g] = (int)bbase + excl; rowend[g] = (int)bbase + excl + v; }
  cnt_s[tid] = 0;
  __syncthreads();
  for (int i = tid; i < cnt; i += TPB) {
    unsigned u = stage[i];
    int kk = u >> 24;
    int r = atomicAdd(&cnt_s[kk], 1);
    items[bbase + off_s[kk] + r] = u & 0xFFFFFFu;
  }
}

// ============================ dense node kernels ============================
// Record layout: 16 B per head ({f32 es, bf16 h0..1, bf16 h2..3, pad}),
// heads contiguous per node. rec1: 8 heads = 128 B/node; rec2: 4 = 64 B;
// rec3: 2 = 32 B. One uint4 load per (edge, head) in the gathers.

__global__ void __launch_bounds__(TPB) k_score(
    const float* __restrict__ x1, const float* __restrict__ x2,
    const float* __restrict__ Wq, const float* __restrict__ bq,
    const float* __restrict__ Wk, const float* __restrict__ bk,
    float* __restrict__ escore, float* __restrict__ sumexp, int N)
{
  __shared__ float sWq[128], sWk[160], sbq[16], sbk[16];
  for (int i = threadIdx.x; i < 128; i += TPB) sWq[i] = Wq[i];
  for (int i = threadIdx.x; i < 160; i += TPB) sWk[i] = Wk[i];
  if (threadIdx.x < 16) { sbq[threadIdx.x] = bq[threadIdx.x]; sbk[threadIdx.x] = bk[threadIdx.x]; }
  __syncthreads();
  int n = blockIdx.x * TPB + threadIdx.x;
  float e = 0.f;
  if (n < N) {
    float a[8], b[10];
#pragma unroll
    for (int i = 0; i < 8; i++) a[i] = x1[n*8 + i];
#pragma unroll
    for (int i = 0; i < 10; i++) b[i] = x2[n*10 + i];
    float score = 0.f;
#pragma unroll
    for (int j = 0; j < 16; j++) {
      float q = sbq[j], k = sbk[j];
#pragma unroll
      for (int i = 0; i < 8; i++) q += a[i] * sWq[i*16 + j];
#pragma unroll
      for (int i = 0; i < 10; i++) k += b[i] * sWk[i*16 + j];
      score += q * k;
    }
    e = __expf(score);   // |score| small: exp safe without max-subtraction
    escore[n] = e;
  }
  float v = e;
#pragma unroll
  for (int off = 32; off > 0; off >>= 1) v += __shfl_down(v, off);
  __shared__ float red[TPB / 64];
  if ((threadIdx.x & 63) == 0) red[threadIdx.x >> 6] = v;
  __syncthreads();
  if (threadIdx.x == 0) {
    float s = 0.f;
#pragma unroll
    for (int w = 0; w < TPB / 64; w++) s += red[w];
    atomicAdd(sumexp, s);
  }
}

__global__ void __launch_bounds__(TPB) k_A1(
    const float* __restrict__ x1, const float* __restrict__ x2,
    const float* __restrict__ Wv, const float* __restrict__ bv,
    const float* __restrict__ W1, const float* __restrict__ a1s, const float* __restrict__ a1d,
    const float* __restrict__ escore, const float* __restrict__ sumexp,
    unsigned* __restrict__ rec1, float* __restrict__ ed, int N)
{
  __shared__ float sWv[288], sbv[16], sW1[512], sas[32], sad[32];
  for (int i = threadIdx.x; i < 288; i += TPB) sWv[i] = Wv[i];
  for (int i = threadIdx.x; i < 512; i += TPB) sW1[i] = W1[i];
  if (threadIdx.x < 16) sbv[threadIdx.x] = bv[threadIdx.x];
  if (threadIdx.x < 32) { sas[threadIdx.x] = a1s[threadIdx.x]; sad[threadIdx.x] = a1d[threadIdx.x]; }
  __syncthreads();
  int n = blockIdx.x * TPB + threadIdx.x;
  if (n >= N) return;
  float w = escore[n] / sumexp[0];
  float f[16];
  {
    float a[8], b[10];
#pragma unroll
    for (int i = 0; i < 8; i++) a[i] = x1[n*8 + i];
#pragma unroll
    for (int i = 0; i < 10; i++) b[i] = x2[n*10 + i];
#pragma unroll
    for (int j = 0; j < 16; j++) {
      float v = sbv[j];
#pragma unroll
      for (int i = 0; i < 8; i++) v += a[i] * sWv[i*16 + j];
#pragma unroll
      for (int i = 0; i < 10; i++) v += b[i] * sWv[(8 + i)*16 + j];
      f[j] = w * v;
    }
  }
  float hr[32], esv[8], edv[8];
#pragma unroll
  for (int j = 0; j < 32; j++) {
    float s = 0.f;
#pragma unroll
    for (int i = 0; i < 16; i++) s += f[i] * sW1[i*32 + j];
    hr[j] = s;
  }
#pragma unroll
  for (int hh = 0; hh < 8; hh++) {
    float s = 0.f, d = 0.f;
#pragma unroll
    for (int c = 0; c < 4; c++) { s += hr[hh*4+c]*sas[hh*4+c]; d += hr[hh*4+c]*sad[hh*4+c]; }
    esv[hh] = s; edv[hh] = d;
  }
  unsigned* r = rec1 + (size_t)n*32;    // 128 B/node, 8 heads x 16 B
#pragma unroll
  for (int hh = 0; hh < 8; hh++) {
    u32x4 q = { __float_as_uint(esv[hh]),
                pk(hr[hh*4+0], hr[hh*4+1]), pk(hr[hh*4+2], hr[hh*4+3]), 0u };
    __builtin_nontemporal_store(q, (u32x4*)(r + hh*4));
  }
  f32x4 e0 = {edv[0], edv[1], edv[2], edv[3]};
  f32x4 e1 = {edv[4], edv[5], edv[6], edv[7]};
  *(f32x4*)(ed + n*8)     = e0;
  *(f32x4*)(ed + n*8 + 4) = e1;
}

__global__ void __launch_bounds__(TPB) k_B2(
    const float* __restrict__ W2, const float* __restrict__ a2s, const float* __restrict__ a2d,
    const float* __restrict__ X,
    unsigned* __restrict__ rec2, float* __restrict__ ed, int N)
{
  __shared__ float sW[512], sas[16], sad[16];
  for (int i = threadIdx.x; i < 512; i += TPB) sW[i] = W2[i];
  if (threadIdx.x < 16) { sas[threadIdx.x] = a2s[threadIdx.x]; sad[threadIdx.x] = a2d[threadIdx.x]; }
  __syncthreads();
  int n = blockIdx.x * TPB + threadIdx.x;
  if (n >= N) return;
  float Xr[32];
#pragma unroll
  for (int i = 0; i < 8; i++) {
    f32x4 t = __builtin_nontemporal_load((const f32x4*)(X + n*32) + i);
    Xr[i*4+0] = t.x; Xr[i*4+1] = t.y; Xr[i*4+2] = t.z; Xr[i*4+3] = t.w;
  }
  float hr[16];
#pragma unroll
  for (int j = 0; j < 16; j++) {
    float s = 0.f;
#pragma unroll
    for (int f = 0; f < 32; f++) s += Xr[f] * sW[f*16 + j];
    hr[j] = s;
  }
  unsigned* r = rec2 + (size_t)n*16;
#pragma unroll
  for (int hh = 0; hh < 4; hh++) {
    float s = 0.f, d = 0.f;
#pragma unroll
    for (int c = 0; c < 4; c++) { s += hr[hh*4+c]*sas[hh*4+c]; d += hr[hh*4+c]*sad[hh*4+c]; }
    u32x4 q = { __float_as_uint(s),
                pk(hr[hh*4+0], hr[hh*4+1]), pk(hr[hh*4+2], hr[hh*4+3]), 0u };
    __builtin_nontemporal_store(q, (u32x4*)(r + hh*4));
    ed[n*8 + hh] = d;
  }
}

__global__ void __launch_bounds__(TPB) k_B3(
    const float* __restrict__ W3, const float* __restrict__ a3s, const float* __restrict__ a3d,
    const float* __restrict__ X3,
    unsigned* __restrict__ rec3, float* __restrict__ ed, int N)
{
  __shared__ float sW[128], sas[8], sad[8];
  for (int i = threadIdx.x; i < 128; i += TPB) sW[i] = W3[i];
  if (threadIdx.x < 8) { sas[threadIdx.x] = a3s[threadIdx.x]; sad[threadIdx.x] = a3d[threadIdx.x]; }
  __syncthreads();
  int n = blockIdx.x * TPB + threadIdx.x;
  if (n >= N) return;
  float Xr[16];
#pragma unroll
  for (int i = 0; i < 4; i++) {
    f32x4 t = __builtin_nontemporal_load((const f32x4*)(X3 + n*16) + i);
    Xr[i*4+0] = t.x; Xr[i*4+1] = t.y; Xr[i*4+2] = t.z; Xr[i*4+3] = t.w;
  }
  float hr[8];
#pragma unroll
  for (int j = 0; j < 8; j++) {
    float s = 0.f;
#pragma unroll
    for (int f = 0; f < 16; f++) s += Xr[f] * sW[f*8 + j];
    hr[j] = s;
  }
  unsigned* r = rec3 + (size_t)n*8;   // 32 B record, 2 heads x 16 B
#pragma unroll
  for (int hh = 0; hh < 2; hh++) {
    float s = 0.f, d = 0.f;
#pragma unroll
    for (int c = 0; c < 4; c++) { s += hr[hh*4+c]*sas[hh*4+c]; d += hr[hh*4+c]*sad[hh*4+c]; }
    u32x4 q = { __float_as_uint(s),
                pk(hr[hh*4+0], hr[hh*4+1]), pk(hr[hh*4+2], hr[hh*4+3]), 0u };
    __builtin_nontemporal_store(q, (u32x4*)(r + hh*4));
    ed[n*8 + hh] = d;
  }
}

// ==================== wave-per-row gather passes ============================
// Layer 1 merged: 8 heads x 8 slots; one uint4 load per (edge, head); the 8
// head-lanes of a slot span the node's 2 contiguous 64 B lines. Self-loop at
// t==deg; butterfly over slot bits (8,16,32).
__global__ void __launch_bounds__(TPB) k_gat1(
    const int* __restrict__ rowptr, const int* __restrict__ rowend, const int* __restrict__ col,
    const unsigned* __restrict__ rec, const float* __restrict__ ed,
    const float* __restrict__ bias, float* __restrict__ out, int N)
{
  int wave = (blockIdx.x * TPB + threadIdx.x) >> 6;
  if (wave >= N) return;
  int lane = threadIdx.x & 63;
  int hh = lane & 7, j = lane >> 3;
  int d = wave;
  int e0 = rowptr[d], deg = rowend[d] - e0;
  float edv = ed[d*8 + hh];
  float z = 0.f;
  f32x4 acc = {0.f, 0.f, 0.f, 0.f};
  for (int t = j; t <= deg; t += 8) {
    int s = (t == deg) ? d : __builtin_nontemporal_load(col + e0 + t);
    u32x4 q = *(const u32x4*)(rec + (size_t)s*32 + hh*4);
    float w = __expf(lrelu(__uint_as_float(q.x) + edv));
    z += w;
    acc.x += w * ubf(q.y & 0xFFFFu); acc.y += w * ubf(q.y >> 16);
    acc.z += w * ubf(q.z & 0xFFFFu); acc.w += w * ubf(q.z >> 16);
  }
#pragma unroll
  for (int m = 8; m < 64; m <<= 1) {
    z += __shfl_xor(z, m);
    acc.x += __shfl_xor(acc.x, m); acc.y += __shfl_xor(acc.y, m);
    acc.z += __shfl_xor(acc.z, m); acc.w += __shfl_xor(acc.w, m);
  }
  if (j == 0) {
    float inv = 1.f / z;
    const f32x4 bb = *(const f32x4*)(bias + hh*4);
    f32x4 o = { acc.x*inv + bb.x, acc.y*inv + bb.y, acc.z*inv + bb.z, acc.w*inv + bb.w };
    __builtin_nontemporal_store(o, (f32x4*)(out + (size_t)d*32 + hh*4));
  }
}

// Layer 2: 4 heads x 16 slots; 64 B records.
__global__ void __launch_bounds__(TPB) k_gat2(
    const int* __restrict__ rowptr, const int* __restrict__ rowend, const int* __restrict__ col,
    const unsigned* __restrict__ rec, const float* __restrict__ ed,
    const float* __restrict__ bias, float* __restrict__ out, int N)
{
  int wave = (blockIdx.x * TPB + threadIdx.x) >> 6;
  if (wave >= N) return;
  int lane = threadIdx.x & 63;
  int hh = lane & 3, j = lane >> 2;
  int d = wave;
  int e0 = rowptr[d], deg = rowend[d] - e0;
  float edv = ed[d*8 + hh];
  float z = 0.f;
  f32x4 acc = {0.f, 0.f, 0.f, 0.f};
  for (int t = j; t <= deg; t += 16) {
    int s = (t == deg) ? d : __builtin_nontemporal_load(col + e0 + t);
    u32x4 q = *(const u32x4*)(rec + (size_t)s*16 + hh*4);
    float w = __expf(lrelu(__uint_as_float(q.x) + edv));
    z += w;
    acc.x += w * ubf(q.y & 0xFFFFu); acc.y += w * ubf(q.y >> 16);
    acc.z += w * ubf(q.z & 0xFFFFu); acc.w += w * ubf(q.z >> 16);
  }
#pragma unroll
  for (int m = 4; m < 64; m <<= 1) {
    z += __shfl_xor(z, m);
    acc.x += __shfl_xor(acc.x, m); acc.y += __shfl_xor(acc.y, m);
    acc.z += __shfl_xor(acc.z, m); acc.w += __shfl_xor(acc.w, m);
  }
  if (j == 0) {
    float inv = 1.f / z;
    const f32x4 bb = *(const f32x4*)(bias + hh*4);
    f32x4 o = { acc.x*inv + bb.x, acc.y*inv + bb.y, acc.z*inv + bb.z, acc.w*inv + bb.w };
    __builtin_nontemporal_store(o, (f32x4*)(out + (size_t)d*16 + hh*4));
  }
}

// Layer 3: 2 heads x 32 slots; 32 B records.
__global__ void __launch_bounds__(TPB) k_gat3(
    const int* __restrict__ rowptr, const int* __restrict__ rowend, const int* __restrict__ col,
    const unsigned* __restrict__ rec, const float* __restrict__ ed,
    const float* __restrict__ b3, float* __restrict__ x4, int N)
{
  int wave = (blockIdx.x * TPB + threadIdx.x) >> 6;
  if (wave >= N) return;
  int lane = threadIdx.x & 63;
  int hh = lane & 1, j = lane >> 1;
  int d = wave;
  int e0 = rowptr[d], deg = rowend[d] - e0;
  float edv = ed[d*8 + hh];
  float z = 0.f;
  f32x4 acc = {0.f, 0.f, 0.f, 0.f};
  for (int t = j; t <= deg; t += 32) {
    int s = (t == deg) ? d : __builtin_nontemporal_load(col + e0 + t);
    u32x4 q = *(const u32x4*)(rec + (size_t)s*8 + hh*4);
    float w = __expf(lrelu(__uint_as_float(q.x) + edv));
    z += w;
    acc.x += w * ubf(q.y & 0xFFFFu); acc.y += w * ubf(q.y >> 16);
    acc.z += w * ubf(q.z & 0xFFFFu); acc.w += w * ubf(q.z >> 16);
  }
#pragma unroll
  for (int m = 2; m < 64; m <<= 1) {
    z += __shfl_xor(z, m);
    acc.x += __shfl_xor(acc.x, m); acc.y += __shfl_xor(acc.y, m);
    acc.z += __shfl_xor(acc.z, m); acc.w += __shfl_xor(acc.w, m);
  }
  if (j == 0) {
    float inv = 1.f / z;
    const f32x4 bb = *(const f32x4*)(b3 + hh*4);
    f32x4 o = { acc.x*inv + bb.x, acc.y*inv + bb.y, acc.z*inv + bb.z, acc.w*inv + bb.w };
    __builtin_nontemporal_store(o, (f32x4*)(x4 + d*8 + hh*4));
  }
}

__global__ void __launch_bounds__(TPB) k_adj_final(
    const int* __restrict__ rowptr, const int* __restrict__ rowend, const int* __restrict__ col,
    const float* __restrict__ x4, const float* __restrict__ Wl2,
    float* __restrict__ out, int N)
{
  __shared__ float sW[8];
  if (threadIdx.x < 8) sW[threadIdx.x] = Wl2[threadIdx.x];
  __syncthreads();
  int wave = (blockIdx.x * TPB + threadIdx.x) >> 6;
  if (wave >= N) return;
  int lane = threadIdx.x & 63;
  int q = lane & 1, j = lane >> 1;
  int r = wave;
  int e0 = rowptr[N + r], deg = rowend[N + r] - e0;
  f32x4 acc = {0.f, 0.f, 0.f, 0.f};
  for (int t = j; t < deg; t += 32) {
    int c = __builtin_nontemporal_load(col + e0 + t);
    f32x4 xv = *(const f32x4*)(x4 + c*8 + q*4);
    acc.x += xv.x; acc.y += xv.y; acc.z += xv.z; acc.w += xv.w;
  }
#pragma unroll
  for (int m = 2; m < 64; m <<= 1) {
    acc.x += __shfl_xor(acc.x, m); acc.y += __shfl_xor(acc.y, m);
    acc.z += __shfl_xor(acc.z, m); acc.w += __shfl_xor(acc.w, m);
  }
  float part = 0.f;
  if (j == 0) {
    float inv = deg > 0 ? 1.f / (float)deg : 0.f;
    f32x4 R = { acc.x*inv, acc.y*inv, acc.z*inv, acc.w*inv };
    f32x4 xo = *(const f32x4*)(x4 + r*8 + q*4);
    part = xo.x*R.x + xo.y*R.y + xo.z*R.z + xo.w*R.w
         + R.x*sW[q*4+0] + R.y*sW[q*4+1] + R.z*sW[q*4+2] + R.w*sW[q*4+3];
  }
  part += __shfl_xor(part, 1);
  if (lane == 0) out[r] = part;
}

// ============================ launch ========================================
extern "C" void kernel_launch(void* const* d_in, const int* in_sizes, int n_in,
                              void* d_out, int out_size, void* d_ws, size_t ws_size,
                              hipStream_t stream)
{
  const float* x1  = (const float*)d_in[0];
  const float* x2  = (const float*)d_in[1];
  const int*   ei  = (const int*)d_in[2];
  const float* Wq  = (const float*)d_in[4];
  const float* bq  = (const float*)d_in[5];
  const float* Wk  = (const float*)d_in[6];
  const float* bk  = (const float*)d_in[7];
  const float* Wv  = (const float*)d_in[8];
  const float* bv  = (const float*)d_in[9];
  const float* W1  = (const float*)d_in[10];
  const float* a1s = (const float*)d_in[11];
  const float* a1d = (const float*)d_in[12];
  const float* b1  = (const float*)d_in[13];
  const float* W2  = (const float*)d_in[14];
  const float* a2s = (const float*)d_in[15];
  const float* a2d = (const float*)d_in[16];
  const float* b2  = (const float*)d_in[17];
  const float* W3  = (const float*)d_in[18];
  const float* a3s = (const float*)d_in[19];
  const float* a3d = (const float*)d_in[20];
  const float* b3  = (const float*)d_in[21];
  const float* Wl2 = (const float*)d_in[22];

  int N = in_sizes[0] / 8;
  int E = in_sizes[2] / 2;
  int n2 = 2 * N;
  int NB = (n2 + 255) >> 8;             // CSR buckets (782)
  int gB = (E + EPB - 1) / EPB;         // k_bucket blocks (782)

  // ---- workspace ----
  float* sumexp = (float*)d_ws;                          // 16 (1 used, zeroed)
  int* rowptr   = (int*)(sumexp + 16);                   // 2N
  int* rowend   = rowptr + (size_t)n2;                   // 2N
  unsigned* itemsCSR = (unsigned*)(rowend + (size_t)n2); // NB*CAP (28.8 MB)
  unsigned* regionA  = itemsCSR + (size_t)NB * CAP;
  // phase 1 (CSR build): items2 + ofs + ofsT live in regionA
  unsigned* items2 = regionA;                            // gB*8192 (25.6 MB)
  int* ofs  = (int*)(items2 + (size_t)gB * (2 * EPB));   // gB*OFSW
  int* ofsT = ofs + (size_t)gB * OFSW;                   // OFSW*GBPAD
  size_t raSize = (size_t)gB * (2 * EPB + OFSW) + (size_t)OFSW * GBPAD;
  // phase 2: recs/ed/escore alias regionA (items2/ofs dead). 32N+16N+8N+8N+N = 65N < raSize ✓
  unsigned* rec1  = regionA;                             // 32N (12.8 MB)
  unsigned* rec2  = rec1 + 32ull*N;                      // 16N
  unsigned* rec3  = rec2 + 16ull*N;                      // 8N
  float* ed       = (float*)(rec3 + 8ull*N);             // 8N
  float* escore   = ed + 8ull*N;                         // N
  float* X        = (float*)(regionA + raSize);          // 32N (X3 aliases, stride 16)
  float* X3 = X;
  float* x4 = (float*)rec1;                              // 8N (rec1 dead after k_gat1)

  int gN = (N + TPB - 1) / TPB;
  int g64 = (int)(((long long)N * 64 + TPB - 1) / TPB);  // wave-per-row grids

  (void)hipMemsetAsync(sumexp, 0, 16 * sizeof(float), stream);

  // CSR build
  k_bucket<<<gB, TPB, 0, stream>>>(ei, E, N, items2, ofs);
  dim3 gt((OFSW + 31) / 32, (gB + 31) / 32);
  k_t<<<gt, TPB, 0, stream>>>(ofs, ofsT, gB);
  k_csr2<<<NB, TPB, 0, stream>>>(ofsT, items2, gB, itemsCSR, rowptr, rowend, n2);
  int* colv = (int*)itemsCSR;

  // dense prologue
  k_score<<<gN, TPB, 0, stream>>>(x1, x2, Wq, bq, Wk, bk, escore, sumexp, N);
  k_A1<<<gN, TPB, 0, stream>>>(x1, x2, Wv, bv, W1, a1s, a1d, escore, sumexp, rec1, ed, N);

  // GAT layer 1 (single merged 8-head pass)
  k_gat1<<<g64, TPB, 0, stream>>>(rowptr, rowend, colv, rec1, ed, b1, X, N);
  // GAT layer 2
  k_B2<<<gN, TPB, 0, stream>>>(W2, a2s, a2d, X, rec2, ed, N);
  k_gat2<<<g64, TPB, 0, stream>>>(rowptr, rowend, colv, rec2, ed, b2, X3, N);
  // GAT layer 3
  k_B3<<<gN, TPB, 0, stream>>>(W3, a3s, a3d, X3, rec3, ed, N);
  k_gat3<<<g64, TPB, 0, stream>>>(rowptr, rowend, colv, rec3, ed, b3, x4, N);

  // adjacency readout (src-CSR rows [N,2N))
  k_adj_final<<<g64, TPB, 0, stream>>>(rowptr, rowend, colv, x4, Wl2, (float*)d_out, N);
}

// Round 14
// 472.342 us; speedup vs baseline: 4.1708x; 1.0064x over previous
//
#include <hip/hip_runtime.h>

#define TPB 256
#define CAP 9216       // per-bucket capacity (mean 8184, sigma ~90 -> +11 sigma)
#define EPB 4096       // edges per block in k_bucket (16/thread)
#define OFSW 784       // ofs table row stride (>= NB+1, 16-aligned)
#define GBPAD 784      // ofsT row stride (>= gB, 16-aligned)

typedef float f32x4 __attribute__((ext_vector_type(4)));
typedef float f32x2 __attribute__((ext_vector_type(2)));
typedef unsigned u32x4 __attribute__((ext_vector_type(4)));

__device__ __forceinline__ float lrelu(float x) { return x > 0.f ? x : 0.2f * x; }

// bf16 helpers (RNE pack)
__device__ __forceinline__ unsigned bfr(float x) {
  unsigned u = __float_as_uint(x);
  return (u + 0x7FFFu + ((u >> 16) & 1u)) >> 16;
}
__device__ __forceinline__ unsigned pk(float a, float b) { return bfr(a) | (bfr(b) << 16); }
__device__ __forceinline__ float ubf(unsigned us) { return __uint_as_float(us << 16); }

// ============================ bucketed CSR build ============================
__global__ void __launch_bounds__(TPB) k_bucket(
    const int* __restrict__ ei, int E, int N,
    unsigned* __restrict__ items2, int* __restrict__ ofs)
{
  __shared__ int hist[1024];
  __shared__ int lofs[1024];
  __shared__ int scan_s[TPB];
  __shared__ unsigned stage[2 * EPB];
  int tid = threadIdx.x;
  for (int i = tid; i < 1024; i += TPB) hist[i] = 0;
  int s0 = blockIdx.x * EPB;
  int nE = min(EPB, E - s0);
  int sv[16], dv[16];
  __syncthreads();
#pragma unroll
  for (int k = 0; k < 4; k++) {
    int li = tid * 4 + k * TPB * 4;
    if (li + 3 < nE) {
      int4 s4 = *(const int4*)(ei + s0 + li);
      int4 d4 = *(const int4*)(ei + E + s0 + li);
      sv[k*4+0] = s4.x; sv[k*4+1] = s4.y; sv[k*4+2] = s4.z; sv[k*4+3] = s4.w;
      dv[k*4+0] = d4.x; dv[k*4+1] = d4.y; dv[k*4+2] = d4.z; dv[k*4+3] = d4.w;
#pragma unroll
      for (int j = 0; j < 4; j++) {
        atomicAdd(&hist[dv[k*4+j] >> 8], 1);
        atomicAdd(&hist[(N + sv[k*4+j]) >> 8], 1);
      }
    } else {
      for (int j = 0; j < 4; j++) {
        if (li + j < nE) {
          sv[k*4+j] = ei[s0 + li + j];
          dv[k*4+j] = ei[E + s0 + li + j];
          atomicAdd(&hist[dv[k*4+j] >> 8], 1);
          atomicAdd(&hist[(N + sv[k*4+j]) >> 8], 1);
        }
      }
    }
  }
  __syncthreads();
  int b0 = tid * 4;
  int c0 = hist[b0], c1 = hist[b0 + 1], c2 = hist[b0 + 2], c3 = hist[b0 + 3];
  int tsum = c0 + c1 + c2 + c3;
  scan_s[tid] = tsum;
  __syncthreads();
#pragma unroll
  for (int o = 1; o < TPB; o <<= 1) {
    int t = (tid >= o) ? scan_s[tid - o] : 0;
    __syncthreads();
    scan_s[tid] += t;
    __syncthreads();
  }
  int run = scan_s[tid] - tsum;
  int cs[4] = {c0, c1, c2, c3};
#pragma unroll
  for (int j = 0; j < 4; j++) {
    int b = b0 + j;
    lofs[b] = run;
    hist[b] = 0;
    run += cs[j];
  }
  __syncthreads();
#pragma unroll
  for (int k = 0; k < 16; k++) {
    int li = tid * 4 + (k >> 2) * TPB * 4 + (k & 3);
    if (li < nE) {
      int s = sv[k], d = dv[k];
      int b1 = d >> 8;
      int p1 = lofs[b1] + atomicAdd(&hist[b1], 1);
      stage[p1] = ((unsigned)(d & 255) << 24) | (unsigned)s;
      int k2 = N + s, b2 = k2 >> 8;
      int p2 = lofs[b2] + atomicAdd(&hist[b2], 1);
      stage[p2] = ((unsigned)(k2 & 255) << 24) | (unsigned)d;
    }
  }
  __syncthreads();
  int total = 2 * nE;
  size_t obase = (size_t)blockIdx.x * (2 * EPB);
  for (int idx = tid; idx < total; idx += TPB)
    __builtin_nontemporal_store(stage[idx], items2 + obase + idx);
  int orow = blockIdx.x * OFSW;
  for (int i = tid; i < OFSW; i += TPB)
    ofs[orow + i] = lofs[i];
}

// Tiled transpose of the ofs table.
__global__ void __launch_bounds__(TPB) k_t(
    const int* __restrict__ ofs, int* __restrict__ ofsT, int nB)
{
  __shared__ int tile[32][33];
  int lx = threadIdx.x & 31, ly = threadIdx.x >> 5;
  int b0 = blockIdx.y * 32, k0 = blockIdx.x * 32;
#pragma unroll
  for (int r = 0; r < 32; r += 8) {
    int b = b0 + ly + r, k = k0 + lx;
    tile[ly + r][lx] = (b < nB && k < OFSW) ? ofs[b * OFSW + k] : 0;
  }
  __syncthreads();
#pragma unroll
  for (int r = 0; r < 32; r += 8) {
    int k = k0 + ly + r, b = b0 + lx;
    if (k < OFSW && b < GBPAD) ofsT[k * GBPAD + b] = tile[lx][ly + r];
  }
}

// Pass 2: coalesced ofsT rows, deterministic block scan, uint4 run copies.
__global__ void __launch_bounds__(TPB) k_csr2(
    const int* __restrict__ ofsT, const unsigned* __restrict__ items2, int nB,
    unsigned* __restrict__ items, int* __restrict__ rowptr, int* __restrict__ rowend, int n2)
{
  __shared__ unsigned stage[CAP];
  __shared__ int cnt_s[TPB], scan_s[TPB], off_s[TPB];
  int tid = threadIdx.x, k = blockIdx.x;
  cnt_s[tid] = 0;
  int o0[4], cl[4];
  int tsum = 0;
#pragma unroll
  for (int m = 0; m < 4; m++) {
    int b = tid + m * TPB;
    if (b < nB) {
      int a0 = ofsT[(size_t)k * GBPAD + b];
      int a1 = ofsT[(size_t)(k + 1) * GBPAD + b];
      o0[m] = a0; cl[m] = a1 - a0;
    } else { o0[m] = 0; cl[m] = 0; }
    tsum += cl[m];
  }
  scan_s[tid] = tsum;
  __syncthreads();
#pragma unroll
  for (int o = 1; o < TPB; o <<= 1) {
    int t = (tid >= o) ? scan_s[tid - o] : 0;
    __syncthreads();
    scan_s[tid] += t;
    __syncthreads();
  }
  int cnt = min(scan_s[TPB - 1], CAP);
  int dst = scan_s[tid] - tsum;
#pragma unroll
  for (int m = 0; m < 4; m++) {
    int b = tid + m * TPB;
    const unsigned* src = items2 + (size_t)b * (2 * EPB) + o0[m];
    int c = cl[m];
    int j = 0;
    int head = (4 - (o0[m] & 3)) & 3; if (head > c) head = c;
    for (; j < head; j++) { int p = dst + j; if (p < CAP) stage[p] = src[j]; }
    for (; j + 3 < c; j += 4) {
      u32x4 v = *(const u32x4*)(src + j);
      int p = dst + j;
      if (p + 3 < CAP) {
        stage[p] = v.x; stage[p+1] = v.y; stage[p+2] = v.z; stage[p+3] = v.w;
      } else {
        if (p < CAP) stage[p] = v.x;
        if (p+1 < CAP) stage[p+1] = v.y;
        if (p+2 < CAP) stage[p+2] = v.z;
        if (p+3 < CAP) stage[p+3] = v.w;
      }
    }
    for (; j < c; j++) { int p = dst + j; if (p < CAP) stage[p] = src[j]; }
    dst += c;
  }
  __syncthreads();
  for (int i = tid; i < cnt; i += TPB) atomicAdd(&cnt_s[stage[i] >> 24], 1);
  __syncthreads();
  int v = cnt_s[tid];
  scan_s[tid] = v;
  __syncthreads();
#pragma unroll
  for (int o = 1; o < TPB; o <<= 1) {
    int t = (tid >= o) ? scan_s[tid - o] : 0;
    __syncthreads();
    scan_s[tid] += t;
    __syncthreads();
  }
  int excl = scan_s[tid] - v;
  off_s[tid] = excl;
  size_t bbase = (size_t)k * CAP;
  int g = k * 256 + tid;
  if (g < n2) { rowptr[g] = (int)bbase + excl; rowend[g] = (int)bbase + excl + v; }
  cnt_s[tid] = 0;
  __syncthreads();
  for (int i = tid; i < cnt; i += TPB) {
    unsigned u = stage[i];
    int kk = u >> 24;
    int r = atomicAdd(&cnt_s[kk], 1);
    items[bbase + off_s[kk] + r] = u & 0xFFFFFFu;
  }
}

// ============================ dense node kernels ============================
// 40 B packed records (L2-resident: 4.0 MB per 4-head record array):
//   u0 = bf16 es[0..1], u1 = bf16 es[2..3], u[2+2h]/u[3+2h] = bf16 h[h][0..3]

__global__ void __launch_bounds__(TPB) k_score(
    const float* __restrict__ x1, const float* __restrict__ x2,
    const float* __restrict__ Wq, const float* __restrict__ bq,
    const float* __restrict__ Wk, const float* __restrict__ bk,
    float* __restrict__ escore, float* __restrict__ sumexp, int N)
{
  __shared__ float sWq[128], sWk[160], sbq[16], sbk[16];
  for (int i = threadIdx.x; i < 128; i += TPB) sWq[i] = Wq[i];
  for (int i = threadIdx.x; i < 160; i += TPB) sWk[i] = Wk[i];
  if (threadIdx.x < 16) { sbq[threadIdx.x] = bq[threadIdx.x]; sbk[threadIdx.x] = bk[threadIdx.x]; }
  __syncthreads();
  int n = blockIdx.x * TPB + threadIdx.x;
  float e = 0.f;
  if (n < N) {
    float a[8], b[10];
#pragma unroll
    for (int i = 0; i < 8; i++) a[i] = x1[n*8 + i];
#pragma unroll
    for (int i = 0; i < 10; i++) b[i] = x2[n*10 + i];
    float score = 0.f;
#pragma unroll
    for (int j = 0; j < 16; j++) {
      float q = sbq[j], k = sbk[j];
#pragma unroll
      for (int i = 0; i < 8; i++) q += a[i] * sWq[i*16 + j];
#pragma unroll
      for (int i = 0; i < 10; i++) k += b[i] * sWk[i*16 + j];
      score += q * k;
    }
    e = __expf(score);   // |score| small: exp safe without max-subtraction
    escore[n] = e;
  }
  float v = e;
#pragma unroll
  for (int off = 32; off > 0; off >>= 1) v += __shfl_down(v, off);
  __shared__ float red[TPB / 64];
  if ((threadIdx.x & 63) == 0) red[threadIdx.x >> 6] = v;
  __syncthreads();
  if (threadIdx.x == 0) {
    float s = 0.f;
#pragma unroll
    for (int w = 0; w < TPB / 64; w++) s += red[w];
    atomicAdd(sumexp, s);
  }
}

__global__ void __launch_bounds__(TPB) k_A1(
    const float* __restrict__ x1, const float* __restrict__ x2,
    const float* __restrict__ Wv, const float* __restrict__ bv,
    const float* __restrict__ W1, const float* __restrict__ a1s, const float* __restrict__ a1d,
    const float* __restrict__ escore, const float* __restrict__ sumexp,
    unsigned* __restrict__ rec1a, unsigned* __restrict__ rec1b,
    float* __restrict__ ed, int N)
{
  __shared__ float sWv[288], sbv[16], sW1[512], sas[32], sad[32];
  for (int i = threadIdx.x; i < 288; i += TPB) sWv[i] = Wv[i];
  for (int i = threadIdx.x; i < 512; i += TPB) sW1[i] = W1[i];
  if (threadIdx.x < 16) sbv[threadIdx.x] = bv[threadIdx.x];
  if (threadIdx.x < 32) { sas[threadIdx.x] = a1s[threadIdx.x]; sad[threadIdx.x] = a1d[threadIdx.x]; }
  __syncthreads();
  int n = blockIdx.x * TPB + threadIdx.x;
  if (n >= N) return;
  float w = escore[n] / sumexp[0];
  float f[16];
  {
    float a[8], b[10];
#pragma unroll
    for (int i = 0; i < 8; i++) a[i] = x1[n*8 + i];
#pragma unroll
    for (int i = 0; i < 10; i++) b[i] = x2[n*10 + i];
#pragma unroll
    for (int j = 0; j < 16; j++) {
      float v = sbv[j];
#pragma unroll
      for (int i = 0; i < 8; i++) v += a[i] * sWv[i*16 + j];
#pragma unroll
      for (int i = 0; i < 10; i++) v += b[i] * sWv[(8 + i)*16 + j];
      f[j] = w * v;
    }
  }
  float hr[32], esv[8], edv[8];
#pragma unroll
  for (int j = 0; j < 32; j++) {
    float s = 0.f;
#pragma unroll
    for (int i = 0; i < 16; i++) s += f[i] * sW1[i*32 + j];
    hr[j] = s;
  }
#pragma unroll
  for (int hh = 0; hh < 8; hh++) {
    float s = 0.f, d = 0.f;
#pragma unroll
    for (int c = 0; c < 4; c++) { s += hr[hh*4+c]*sas[hh*4+c]; d += hr[hh*4+c]*sad[hh*4+c]; }
    esv[hh] = s; edv[hh] = d;
  }
  unsigned* ra = rec1a + (size_t)n*10;
  unsigned* rb = rec1b + (size_t)n*10;
  ra[0] = pk(esv[0], esv[1]); ra[1] = pk(esv[2], esv[3]);
  rb[0] = pk(esv[4], esv[5]); rb[1] = pk(esv[6], esv[7]);
#pragma unroll
  for (int hh = 0; hh < 4; hh++) {
    ra[2+2*hh] = pk(hr[hh*4+0], hr[hh*4+1]);
    ra[3+2*hh] = pk(hr[hh*4+2], hr[hh*4+3]);
    rb[2+2*hh] = pk(hr[16+hh*4+0], hr[16+hh*4+1]);
    rb[3+2*hh] = pk(hr[16+hh*4+2], hr[16+hh*4+3]);
  }
  f32x4 e0 = {edv[0], edv[1], edv[2], edv[3]};
  f32x4 e1 = {edv[4], edv[5], edv[6], edv[7]};
  *(f32x4*)(ed + n*8)     = e0;
  *(f32x4*)(ed + n*8 + 4) = e1;
}

__global__ void __launch_bounds__(TPB) k_B2(
    const float* __restrict__ W2, const float* __restrict__ a2s, const float* __restrict__ a2d,
    const float* __restrict__ X,
    unsigned* __restrict__ rec2, float* __restrict__ ed, int N)
{
  __shared__ float sW[512], sas[16], sad[16];
  for (int i = threadIdx.x; i < 512; i += TPB) sW[i] = W2[i];
  if (threadIdx.x < 16) { sas[threadIdx.x] = a2s[threadIdx.x]; sad[threadIdx.x] = a2d[threadIdx.x]; }
  __syncthreads();
  int n = blockIdx.x * TPB + threadIdx.x;
  if (n >= N) return;
  float Xr[32];
#pragma unroll
  for (int i = 0; i < 8; i++) {
    f32x4 t = __builtin_nontemporal_load((const f32x4*)(X + n*32) + i);
    Xr[i*4+0] = t.x; Xr[i*4+1] = t.y; Xr[i*4+2] = t.z; Xr[i*4+3] = t.w;
  }
  float hr[16];
#pragma unroll
  for (int j = 0; j < 16; j++) {
    float s = 0.f;
#pragma unroll
    for (int f = 0; f < 32; f++) s += Xr[f] * sW[f*16 + j];
    hr[j] = s;
  }
  float esv[4], edv[4];
#pragma unroll
  for (int hh = 0; hh < 4; hh++) {
    float s = 0.f, d = 0.f;
#pragma unroll
    for (int c = 0; c < 4; c++) { s += hr[hh*4+c]*sas[hh*4+c]; d += hr[hh*4+c]*sad[hh*4+c]; }
    esv[hh] = s; edv[hh] = d;
  }
  unsigned* r = rec2 + (size_t)n*10;
  r[0] = pk(esv[0], esv[1]); r[1] = pk(esv[2], esv[3]);
#pragma unroll
  for (int hh = 0; hh < 4; hh++) {
    r[2+2*hh] = pk(hr[hh*4+0], hr[hh*4+1]);
    r[3+2*hh] = pk(hr[hh*4+2], hr[hh*4+3]);
  }
  f32x4 e0 = {edv[0], edv[1], edv[2], edv[3]};
  *(f32x4*)(ed + n*8) = e0;
}

__global__ void __launch_bounds__(TPB) k_B3(
    const float* __restrict__ W3, const float* __restrict__ a3s, const float* __restrict__ a3d,
    const float* __restrict__ X3,
    unsigned* __restrict__ rec3, float* __restrict__ ed, int N)
{
  __shared__ float sW[128], sas[8], sad[8];
  for (int i = threadIdx.x; i < 128; i += TPB) sW[i] = W3[i];
  if (threadIdx.x < 8) { sas[threadIdx.x] = a3s[threadIdx.x]; sad[threadIdx.x] = a3d[threadIdx.x]; }
  __syncthreads();
  int n = blockIdx.x * TPB + threadIdx.x;
  if (n >= N) return;
  float Xr[16];
#pragma unroll
  for (int i = 0; i < 4; i++) {
    f32x4 t = __builtin_nontemporal_load((const f32x4*)(X3 + n*16) + i);
    Xr[i*4+0] = t.x; Xr[i*4+1] = t.y; Xr[i*4+2] = t.z; Xr[i*4+3] = t.w;
  }
  float hr[8];
#pragma unroll
  for (int j = 0; j < 8; j++) {
    float s = 0.f;
#pragma unroll
    for (int f = 0; f < 16; f++) s += Xr[f] * sW[f*8 + j];
    hr[j] = s;
  }
  unsigned* r = rec3 + (size_t)n*8;   // 32 B record, 2 heads x 16 B
#pragma unroll
  for (int hh = 0; hh < 2; hh++) {
    float s = 0.f, d = 0.f;
#pragma unroll
    for (int c = 0; c < 4; c++) { s += hr[hh*4+c]*sas[hh*4+c]; d += hr[hh*4+c]*sad[hh*4+c]; }
    u32x4 q = { __float_as_uint(s),
                pk(hr[hh*4+0], hr[hh*4+1]), pk(hr[hh*4+2], hr[hh*4+3]), 0u };
    __builtin_nontemporal_store(q, (u32x4*)(r + hh*4));
    ed[n*8 + hh] = d;
  }
}

// ==================== wave-per-row gather passes ============================
// 4 heads x 16 slots over 40 B L2-resident records; lane hh loads es uint +
// h uint2. Self-loop at t==deg; butterfly over slot bits.
template<int OS, int HOFF>
__global__ void __launch_bounds__(TPB) k_gat4(
    const int* __restrict__ rowptr, const int* __restrict__ rowend, const int* __restrict__ col,
    const unsigned* __restrict__ rec, const float* __restrict__ ed,
    const float* __restrict__ bias, float* __restrict__ out, int N)
{
  int wave = (blockIdx.x * TPB + threadIdx.x) >> 6;
  if (wave >= N) return;
  int lane = threadIdx.x & 63;
  int hh = lane & 3, j = lane >> 2;
  int d = wave;
  int e0 = rowptr[d], deg = rowend[d] - e0;
  float edv = ed[d*8 + HOFF + hh];
  float z = 0.f;
  f32x4 acc = {0.f, 0.f, 0.f, 0.f};
  for (int t = j; t <= deg; t += 16) {
    int s = (t == deg) ? d : __builtin_nontemporal_load(col + e0 + t);
    const unsigned* rp = rec + (size_t)s*10;
    unsigned ew = rp[hh >> 1];
    uint2 hv = *(const uint2*)(rp + 2 + 2*hh);
    float esv = ubf((ew >> ((hh & 1) * 16)) & 0xFFFFu);
    float w = __expf(lrelu(esv + edv));
    z += w;
    acc.x += w * ubf(hv.x & 0xFFFFu); acc.y += w * ubf(hv.x >> 16);
    acc.z += w * ubf(hv.y & 0xFFFFu); acc.w += w * ubf(hv.y >> 16);
  }
#pragma unroll
  for (int m = 4; m < 64; m <<= 1) {
    z += __shfl_xor(z, m);
    acc.x += __shfl_xor(acc.x, m); acc.y += __shfl_xor(acc.y, m);
    acc.z += __shfl_xor(acc.z, m); acc.w += __shfl_xor(acc.w, m);
  }
  if (j == 0) {
    float inv = 1.f / z;
    const f32x4 bb = *(const f32x4*)(bias + (HOFF + hh)*4);
    f32x4 o = { acc.x*inv + bb.x, acc.y*inv + bb.y, acc.z*inv + bb.z, acc.w*inv + bb.w };
    __builtin_nontemporal_store(o, (f32x4*)(out + (size_t)d*OS + (HOFF + hh)*4));
  }
}

// Layer 3: 2 heads x 32 slots; 32 B records (3.2 MB, L2-resident), 1 uint4 load.
__global__ void __launch_bounds__(TPB) k_gat3(
    const int* __restrict__ rowptr, const int* __restrict__ rowend, const int* __restrict__ col,
    const unsigned* __restrict__ rec, const float* __restrict__ ed,
    const float* __restrict__ b3, float* __restrict__ x4, int N)
{
  int wave = (blockIdx.x * TPB + threadIdx.x) >> 6;
  if (wave >= N) return;
  int lane = threadIdx.x & 63;
  int hh = lane & 1, j = lane >> 1;
  int d = wave;
  int e0 = rowptr[d], deg = rowend[d] - e0;
  float edv = ed[d*8 + hh];
  float z = 0.f;
  f32x4 acc = {0.f, 0.f, 0.f, 0.f};
  for (int t = j; t <= deg; t += 32) {
    int s = (t == deg) ? d : __builtin_nontemporal_load(col + e0 + t);
    u32x4 q = *(const u32x4*)(rec + (size_t)s*8 + hh*4);
    float w = __expf(lrelu(__uint_as_float(q.x) + edv));
    z += w;
    acc.x += w * ubf(q.y & 0xFFFFu); acc.y += w * ubf(q.y >> 16);
    acc.z += w * ubf(q.z & 0xFFFFu); acc.w += w * ubf(q.z >> 16);
  }
#pragma unroll
  for (int m = 2; m < 64; m <<= 1) {
    z += __shfl_xor(z, m);
    acc.x += __shfl_xor(acc.x, m); acc.y += __shfl_xor(acc.y, m);
    acc.z += __shfl_xor(acc.z, m); acc.w += __shfl_xor(acc.w, m);
  }
  if (j == 0) {
    float inv = 1.f / z;
    const f32x4 bb = *(const f32x4*)(b3 + hh*4);
    f32x4 o = { acc.x*inv + bb.x, acc.y*inv + bb.y, acc.z*inv + bb.z, acc.w*inv + bb.w };
    __builtin_nontemporal_store(o, (f32x4*)(x4 + d*8 + hh*4));
  }
}

__global__ void __launch_bounds__(TPB) k_adj_final(
    const int* __restrict__ rowptr, const int* __restrict__ rowend, const int* __restrict__ col,
    const float* __restrict__ x4, const float* __restrict__ Wl2,
    float* __restrict__ out, int N)
{
  __shared__ float sW[8];
  if (threadIdx.x < 8) sW[threadIdx.x] = Wl2[threadIdx.x];
  __syncthreads();
  int wave = (blockIdx.x * TPB + threadIdx.x) >> 6;
  if (wave >= N) return;
  int lane = threadIdx.x & 63;
  int q = lane & 1, j = lane >> 1;
  int r = wave;
  int e0 = rowptr[N + r], deg = rowend[N + r] - e0;
  f32x4 acc = {0.f, 0.f, 0.f, 0.f};
  for (int t = j; t < deg; t += 32) {
    int c = __builtin_nontemporal_load(col + e0 + t);
    f32x4 xv = *(const f32x4*)(x4 + c*8 + q*4);
    acc.x += xv.x; acc.y += xv.y; acc.z += xv.z; acc.w += xv.w;
  }
#pragma unroll
  for (int m = 2; m < 64; m <<= 1) {
    acc.x += __shfl_xor(acc.x, m); acc.y += __shfl_xor(acc.y, m);
    acc.z += __shfl_xor(acc.z, m); acc.w += __shfl_xor(acc.w, m);
  }
  float part = 0.f;
  if (j == 0) {
    float inv = deg > 0 ? 1.f / (float)deg : 0.f;
    f32x4 R = { acc.x*inv, acc.y*inv, acc.z*inv, acc.w*inv };
    f32x4 xo = *(const f32x4*)(x4 + r*8 + q*4);
    part = xo.x*R.x + xo.y*R.y + xo.z*R.z + xo.w*R.w
         + R.x*sW[q*4+0] + R.y*sW[q*4+1] + R.z*sW[q*4+2] + R.w*sW[q*4+3];
  }
  part += __shfl_xor(part, 1);
  if (lane == 0) out[r] = part;
}

// ============================ launch ========================================
extern "C" void kernel_launch(void* const* d_in, const int* in_sizes, int n_in,
                              void* d_out, int out_size, void* d_ws, size_t ws_size,
                              hipStream_t stream)
{
  const float* x1  = (const float*)d_in[0];
  const float* x2  = (const float*)d_in[1];
  const int*   ei  = (const int*)d_in[2];
  const float* Wq  = (const float*)d_in[4];
  const float* bq  = (const float*)d_in[5];
  const float* Wk  = (const float*)d_in[6];
  const float* bk  = (const float*)d_in[7];
  const float* Wv  = (const float*)d_in[8];
  const float* bv  = (const float*)d_in[9];
  const float* W1  = (const float*)d_in[10];
  const float* a1s = (const float*)d_in[11];
  const float* a1d = (const float*)d_in[12];
  const float* b1  = (const float*)d_in[13];
  const float* W2  = (const float*)d_in[14];
  const float* a2s = (const float*)d_in[15];
  const float* a2d = (const float*)d_in[16];
  const float* b2  = (const float*)d_in[17];
  const float* W3  = (const float*)d_in[18];
  const float* a3s = (const float*)d_in[19];
  const float* a3d = (const float*)d_in[20];
  const float* b3  = (const float*)d_in[21];
  const float* Wl2 = (const float*)d_in[22];

  int N = in_sizes[0] / 8;
  int E = in_sizes[2] / 2;
  int n2 = 2 * N;
  int NB = (n2 + 255) >> 8;             // CSR buckets (782)
  int gB = (E + EPB - 1) / EPB;         // k_bucket blocks (782)

  // ---- workspace ----
  float* sumexp = (float*)d_ws;                          // 16 (1 used, zeroed)
  int* rowptr   = (int*)(sumexp + 16);                   // 2N
  int* rowend   = rowptr + (size_t)n2;                   // 2N
  unsigned* itemsCSR = (unsigned*)(rowend + (size_t)n2); // NB*CAP (28.8 MB)
  unsigned* regionA  = itemsCSR + (size_t)NB * CAP;
  // phase 1 (CSR build): items2 + ofs + ofsT live in regionA
  unsigned* items2 = regionA;                            // gB*8192 (25.6 MB)
  int* ofs  = (int*)(items2 + (size_t)gB * (2 * EPB));   // gB*OFSW
  int* ofsT = ofs + (size_t)gB * OFSW;                   // OFSW*GBPAD
  size_t raSize = (size_t)gB * (2 * EPB + OFSW) + (size_t)OFSW * GBPAD;
  // phase 2: recs/ed/escore alias regionA (items2/ofs dead). 10N*3+8N+8N+N = 47N < raSize ✓
  unsigned* rec1a = regionA;                             // 10N (4.0 MB, L2-resident)
  unsigned* rec1b = rec1a + 10ull*N;                     // 10N (aliased by x4 later)
  unsigned* rec2  = rec1b + 10ull*N;                     // 10N
  unsigned* rec3  = rec2 + 10ull*N;                      // 8N (3.2 MB)
  float* ed       = (float*)(rec3 + 8ull*N);             // 8N
  float* escore   = ed + 8ull*N;                         // N
  float* X        = (float*)(regionA + raSize);          // 32N (X3 aliases, stride 16)
  float* X3 = X;
  float* x4 = (float*)rec1b;                             // 8N (rec1b dead by then)

  int gN = (N + TPB - 1) / TPB;
  int g64 = (int)(((long long)N * 64 + TPB - 1) / TPB);  // wave-per-row grids

  (void)hipMemsetAsync(sumexp, 0, 16 * sizeof(float), stream);

  // CSR build
  k_bucket<<<gB, TPB, 0, stream>>>(ei, E, N, items2, ofs);
  dim3 gt((OFSW + 31) / 32, (gB + 31) / 32);
  k_t<<<gt, TPB, 0, stream>>>(ofs, ofsT, gB);
  k_csr2<<<NB, TPB, 0, stream>>>(ofsT, items2, gB, itemsCSR, rowptr, rowend, n2);
  int* colv = (int*)itemsCSR;

  // dense prologue
  k_score<<<gN, TPB, 0, stream>>>(x1, x2, Wq, bq, Wk, bk, escore, sumexp, N);
  k_A1<<<gN, TPB, 0, stream>>>(x1, x2, Wv, bv, W1, a1s, a1d, escore, sumexp, rec1a, rec1b, ed, N);

  // GAT layer 1 (two 4-head passes over L2-resident 4 MB records)
  k_gat4<32, 0><<<g64, TPB, 0, stream>>>(rowptr, rowend, colv, rec1a, ed, b1, X, N);
  k_gat4<32, 4><<<g64, TPB, 0, stream>>>(rowptr, rowend, colv, rec1b, ed, b1, X, N);
  // GAT layer 2
  k_B2<<<gN, TPB, 0, stream>>>(W2, a2s, a2d, X, rec2, ed, N);
  k_gat4<16, 0><<<g64, TPB, 0, stream>>>(rowptr, rowend, colv, rec2, ed, b2, X3, N);
  // GAT layer 3
  k_B3<<<gN, TPB, 0, stream>>>(W3, a3s, a3d, X3, rec3, ed, N);
  k_gat3<<<g64, TPB, 0, stream>>>(rowptr, rowend, colv, rec3, ed, b3, x4, N);

  // adjacency readout (src-CSR rows [N,2N))
  k_adj_final<<<g64, TPB, 0, stream>>>(rowptr, rowend, colv, x4, Wl2, (float*)d_out, N);
}